// Round 1
// baseline (1761.585 us; speedup 1.0000x reference)
//
#include <hip/hip_runtime.h>
#include <hip/hip_bf16.h>

// ---------------------------------------------------------------------------
// SE3Transformer block, restructured:
//   msg0[e,o] = Y0 * sum_k h2[e,k] * U[src[e],k,o],  U[n,k,o] = sum_i h[n,i]*W3[k,o*16+i]
// U precomputed per NODE (20K) instead of per EDGE (320K): 5.7x FLOP cut.
// Layer-0 degree-1 branch is dead (out1 overwritten by layer 1) -> skipped.
// U stored bf16 (halves gather bytes; well under the 2%-of-max threshold).
// ---------------------------------------------------------------------------

#define Y0C 0.28209479177387814f
#define C1C 0.4886025119029199f

static __device__ __forceinline__ float bf2f(unsigned short u) {
    return __uint_as_float(((unsigned)u) << 16);
}
static __device__ __forceinline__ unsigned short f2bf(float f) {
    unsigned u = __float_as_uint(f);
    u += 0x7fffu + ((u >> 16) & 1u);   // round-to-nearest-even
    return (unsigned short)(u >> 16);
}

struct RadialW { const float *W1, *b1, *g1, *gb1, *W2, *b2, *g2, *gb2; };

// radial MLP: (x0,x1,x2) -> 32 (LN,relu) -> 32 (LN,relu). out[32] set to 1
// so the rb3-derived 33rd U row is picked up by the contraction.
__device__ __forceinline__ void radial_net(float x0, float x1, float x2,
                                           RadialW rw, float* out /*[33]*/) {
    float h[32];
#pragma unroll
    for (int j = 0; j < 32; ++j)
        h[j] = rw.b1[j] + x0 * rw.W1[j] + x1 * rw.W1[32 + j] + x2 * rw.W1[64 + j];
    float mu = 0.f;
#pragma unroll
    for (int j = 0; j < 32; ++j) mu += h[j];
    mu *= 0.03125f;
    float var = 0.f;
#pragma unroll
    for (int j = 0; j < 32; ++j) { float d = h[j] - mu; var += d * d; }
    var *= 0.03125f;
    float rs = rsqrtf(var + 1e-5f);
#pragma unroll
    for (int j = 0; j < 32; ++j)
        h[j] = fmaxf((h[j] - mu) * rs * rw.g1[j] + rw.gb1[j], 0.f);

    float h2[32];
#pragma unroll
    for (int j = 0; j < 32; ++j) h2[j] = rw.b2[j];
#pragma unroll
    for (int k = 0; k < 32; ++k) {
        float hk = h[k];
        const float* __restrict__ w = rw.W2 + k * 32;   // contiguous row: scalar loads
#pragma unroll
        for (int j = 0; j < 32; ++j) h2[j] += hk * w[j];
    }
    mu = 0.f;
#pragma unroll
    for (int j = 0; j < 32; ++j) mu += h2[j];
    mu *= 0.03125f;
    var = 0.f;
#pragma unroll
    for (int j = 0; j < 32; ++j) { float d = h2[j] - mu; var += d * d; }
    var *= 0.03125f;
    rs = rsqrtf(var + 1e-5f);
#pragma unroll
    for (int j = 0; j < 32; ++j)
        out[j] = fmaxf((h2[j] - mu) * rs * rw.g2[j] + rw.gb2[j], 0.f);
    out[32] = 1.f;
}

// v[o] = sum_{k<33} hv[k] * U[k*16+o]   (U row gathered per edge, bf16)
__device__ __forceinline__ void contract_u(const float* hv,
                                           const uint4* __restrict__ Up,
                                           float* v /*[16]*/) {
#pragma unroll
    for (int o = 0; o < 16; ++o) v[o] = 0.f;
#pragma unroll
    for (int k = 0; k < 33; ++k) {
        float hk = hv[k];
        uint4 a = Up[2 * k];
        uint4 b = Up[2 * k + 1];
        v[0]  += hk * bf2f((unsigned short)(a.x));
        v[1]  += hk * bf2f((unsigned short)(a.x >> 16));
        v[2]  += hk * bf2f((unsigned short)(a.y));
        v[3]  += hk * bf2f((unsigned short)(a.y >> 16));
        v[4]  += hk * bf2f((unsigned short)(a.z));
        v[5]  += hk * bf2f((unsigned short)(a.z >> 16));
        v[6]  += hk * bf2f((unsigned short)(a.w));
        v[7]  += hk * bf2f((unsigned short)(a.w >> 16));
        v[8]  += hk * bf2f((unsigned short)(b.x));
        v[9]  += hk * bf2f((unsigned short)(b.x >> 16));
        v[10] += hk * bf2f((unsigned short)(b.y));
        v[11] += hk * bf2f((unsigned short)(b.y >> 16));
        v[12] += hk * bf2f((unsigned short)(b.z));
        v[13] += hk * bf2f((unsigned short)(b.z >> 16));
        v[14] += hk * bf2f((unsigned short)(b.w));
        v[15] += hk * bf2f((unsigned short)(b.w >> 16));
    }
}

// ---- node embedding -------------------------------------------------------
__global__ void k_embed1(const float* __restrict__ nf, const float* __restrict__ W1,
                         const float* __restrict__ b1, float* __restrict__ t, int N) {
    int idx = blockIdx.x * blockDim.x + threadIdx.x;
    if (idx >= N * 67) return;
    int n = idx / 67, j = idx - n * 67;
    const float* __restrict__ x = nf + (size_t)n * 67;
    float s = b1[j];
    for (int i = 0; i < 67; ++i) s += x[i] * W1[i * 67 + j];
    t[idx] = (s > 0.f) ? s : expm1f(s);   // ELU(alpha=1)
}

__global__ void k_embed2(const float* __restrict__ t, const float* __restrict__ W2,
                         const float* __restrict__ b2, float* __restrict__ h0, int N) {
    int idx = blockIdx.x * blockDim.x + threadIdx.x;
    if (idx >= N * 16) return;
    int n = idx >> 4, c = idx & 15;
    const float* __restrict__ x = t + (size_t)n * 67;
    float s = b2[c];
    for (int i = 0; i < 67; ++i) s += x[i] * W2[i * 16 + c];
    h0[idx] = s;
}

// ---- geometry + degree ----------------------------------------------------
__global__ void k_geom(const float* __restrict__ pos, const float* __restrict__ ew,
                       const int* __restrict__ src, const int* __restrict__ dst,
                       float* __restrict__ feat, float* __restrict__ Y1,
                       float* __restrict__ deg, int E) {
    int e = blockIdx.x * blockDim.x + threadIdx.x;
    if (e >= E) return;
    int s = src[e], d = dst[e];
    float dx = pos[3 * d]     - pos[3 * s];
    float dy = pos[3 * d + 1] - pos[3 * s + 1];
    float dz = pos[3 * d + 2] - pos[3 * s + 2];
    float r = sqrtf(dx * dx + dy * dy + dz * dz);
    float im = 1.f / fmaxf(r, 1e-8f);
    Y1[3 * e]     = C1C * dy * im;   // (y, z, x) order
    Y1[3 * e + 1] = C1C * dz * im;
    Y1[3 * e + 2] = C1C * dx * im;
    feat[3 * e]     = ew[2 * e];
    feat[3 * e + 1] = ew[2 * e + 1];
    feat[3 * e + 2] = r;
    atomicAdd(deg + d, 1.f);
}

// ---- per-node U precompute: U[n,k,o], k<32 from W3, k==32 from rb3 --------
__global__ void k_u(const float* __restrict__ h, const float* __restrict__ W3,
                    const float* __restrict__ b3, unsigned short* __restrict__ U, int N) {
    int idx = blockIdx.x * blockDim.x + threadIdx.x;
    if (idx >= N * 528) return;
    int n = idx / 528, r = idx - n * 528;
    int k = r >> 4, o = r & 15;
    const float* __restrict__ w = (k < 32) ? (W3 + k * 256 + o * 16) : (b3 + o * 16);
    const float* __restrict__ hn = h + (size_t)n * 16;
    float s = 0.f;
#pragma unroll
    for (int i = 0; i < 16; ++i) s += hn[i] * w[i];
    U[idx] = f2bf(s);
}

// ---- edge kernels ---------------------------------------------------------
__global__ __launch_bounds__(256) void k_edge_l0(
    const float* __restrict__ feat, const int* __restrict__ src,
    const int* __restrict__ dst, RadialW ra,
    const unsigned short* __restrict__ Ua, float* __restrict__ acc0, int E) {
    int e = blockIdx.x * blockDim.x + threadIdx.x;
    if (e >= E) return;
    float f0 = feat[3 * e], f1 = feat[3 * e + 1], f2 = feat[3 * e + 2];
    int sn = src[e], dn = dst[e];
    float hv[33], v[16];
    radial_net(f0, f1, f2, ra, hv);
    contract_u(hv, (const uint4*)(Ua + (size_t)sn * 528), v);
    float* a0 = acc0 + (size_t)dn * 16;
#pragma unroll
    for (int o = 0; o < 16; ++o) atomicAdd(a0 + o, Y0C * v[o]);
}

__global__ __launch_bounds__(256) void k_edge_l1(
    const float* __restrict__ feat, const float* __restrict__ Y1,
    const int* __restrict__ src, const int* __restrict__ dst,
    RadialW ra, RadialW rb,
    const unsigned short* __restrict__ Ua, const unsigned short* __restrict__ Ub,
    float* __restrict__ acc0, float* __restrict__ acc1, int E) {
    int e = blockIdx.x * blockDim.x + threadIdx.x;
    if (e >= E) return;
    float f0 = feat[3 * e], f1 = feat[3 * e + 1], f2 = feat[3 * e + 2];
    int sn = src[e], dn = dst[e];
    float hv[33], v[16];

    radial_net(f0, f1, f2, ra, hv);
    contract_u(hv, (const uint4*)(Ua + (size_t)sn * 528), v);
    float* a0 = acc0 + (size_t)dn * 16;
#pragma unroll
    for (int o = 0; o < 16; ++o) atomicAdd(a0 + o, Y0C * v[o]);

    radial_net(f0, f1, f2, rb, hv);
    contract_u(hv, (const uint4*)(Ub + (size_t)sn * 528), v);
    float y0 = Y1[3 * e], y1 = Y1[3 * e + 1], y2 = Y1[3 * e + 2];
    float* a1 = acc1 + (size_t)dn * 48;
#pragma unroll
    for (int o = 0; o < 16; ++o) {
        atomicAdd(a1 + o * 3,     v[o] * y0);
        atomicAdd(a1 + o * 3 + 1, v[o] * y1);
        atomicAdd(a1 + o * 3 + 2, v[o] * y2);
    }
}

// ---- finalize: out = acc*inv_deg + has_in * (h @ Wself^T) -----------------
__global__ void k_fin(const float* __restrict__ acc0, const float* __restrict__ deg,
                      const float* __restrict__ h, const float* __restrict__ Wself,
                      float* __restrict__ out, int N) {
    int idx = blockIdx.x * blockDim.x + threadIdx.x;
    if (idx >= N * 16) return;
    int n = idx >> 4, o = idx & 15;
    float d = deg[n];
    float invd = (d > 0.f) ? 1.f / d : 0.f;
    float hi   = (d > 0.f) ? 1.f : 0.f;
    const float* __restrict__ hn = h + (size_t)n * 16;
    const float* __restrict__ w  = Wself + o * 16;
    float s = 0.f;
#pragma unroll
    for (int c = 0; c < 16; ++c) s += hn[c] * w[c];
    out[idx] = acc0[idx] * invd + hi * s;
}

__global__ void k_out1(const float* __restrict__ acc1, const float* __restrict__ deg,
                       float* __restrict__ out1, int N) {
    int idx = blockIdx.x * blockDim.x + threadIdx.x;
    if (idx >= N * 48) return;
    int n = idx / 48;
    float d = deg[n];
    float invd = (d > 0.f) ? 1.f / d : 0.f;
    out1[idx] = acc1[idx] * invd;
}

// ---------------------------------------------------------------------------
extern "C" void kernel_launch(void* const* d_in, const int* in_sizes, int n_in,
                              void* d_out, int out_size, void* d_ws, size_t ws_size,
                              hipStream_t stream) {
    (void)n_in; (void)out_size; (void)ws_size;
    const float* node_feats = (const float*)d_in[0];
    const float* pos    = (const float*)d_in[1];
    const float* edge_w = (const float*)d_in[2];
    const float* lin1_W = (const float*)d_in[3];
    const float* lin1_b = (const float*)d_in[4];
    const float* lin2_W = (const float*)d_in[5];
    const float* lin2_b = (const float*)d_in[6];
    const float* rW1    = (const float*)d_in[7];
    const float* rb1    = (const float*)d_in[8];
    const float* ln1_g  = (const float*)d_in[9];
    const float* ln1_b  = (const float*)d_in[10];
    const float* rW2    = (const float*)d_in[11];
    const float* rb2    = (const float*)d_in[12];
    const float* ln2_g  = (const float*)d_in[13];
    const float* ln2_b  = (const float*)d_in[14];
    const float* rW3    = (const float*)d_in[15];
    const float* rb3    = (const float*)d_in[16];
    const float* Wself  = (const float*)d_in[17];
    const int*   src    = (const int*)d_in[18];
    const int*   dst    = (const int*)d_in[19];

    const int N = in_sizes[1] / 3;     // pos is [N,3]
    const int E = in_sizes[18];        // src is [E]

    // workspace carve-up (256B aligned)
    char* ws = (char*)d_ws;
    size_t off = 0;
    auto carve = [&](size_t bytes) -> char* {
        char* p = ws + off;
        off = (off + bytes + 255) & ~(size_t)255;
        return p;
    };
    float* deg  = (float*)carve((size_t)N * 4);
    float* h0   = (float*)carve((size_t)N * 16 * 4);
    float* h1   = (float*)carve((size_t)N * 16 * 4);
    float* tmb  = (float*)carve((size_t)N * 67 * 4);
    float* feat = (float*)carve((size_t)E * 3 * 4);
    float* Y1w  = (float*)carve((size_t)E * 3 * 4);
    float* acc0 = (float*)carve((size_t)N * 16 * 4);
    float* acc1 = (float*)carve((size_t)N * 48 * 4);
    unsigned short* Ua = (unsigned short*)carve((size_t)N * 528 * 2);
    unsigned short* Ub = (unsigned short*)carve((size_t)N * 528 * 2);

    auto nb = [](int n) { return (n + 255) / 256; };

    hipMemsetAsync(deg,  0, (size_t)N * 4,       stream);
    hipMemsetAsync(acc0, 0, (size_t)N * 16 * 4,  stream);
    hipMemsetAsync(acc1, 0, (size_t)N * 48 * 4,  stream);

    k_embed1<<<nb(N * 67), 256, 0, stream>>>(node_feats, lin1_W, lin1_b, tmb, N);
    k_embed2<<<nb(N * 16), 256, 0, stream>>>(tmb, lin2_W, lin2_b, h0, N);
    k_geom<<<nb(E), 256, 0, stream>>>(pos, edge_w, src, dst, feat, Y1w, deg, E);

    auto rnet = [&](int net) -> RadialW {
        RadialW r;
        r.W1 = rW1 + net * 96;   r.b1 = rb1 + net * 32;
        r.g1 = ln1_g + net * 32; r.gb1 = ln1_b + net * 32;
        r.W2 = rW2 + net * 1024; r.b2 = rb2 + net * 32;
        r.g2 = ln2_g + net * 32; r.gb2 = ln2_b + net * 32;
        return r;
    };

    // ---- layer 0 (degree-1 branch dead: only net 0) ----
    k_u<<<nb(N * 528), 256, 0, stream>>>(h0, rW3 + 0 * 8192, rb3 + 0 * 256, Ua, N);
    k_edge_l0<<<nb(E), 256, 0, stream>>>(feat, src, dst, rnet(0), Ua, acc0, E);
    k_fin<<<nb(N * 16), 256, 0, stream>>>(acc0, deg, h0, Wself + 0 * 256, h1, N);

    // ---- layer 1 (nets 2,3) ----
    hipMemsetAsync(acc0, 0, (size_t)N * 16 * 4, stream);
    k_u<<<nb(N * 528), 256, 0, stream>>>(h1, rW3 + 2 * 8192, rb3 + 2 * 256, Ua, N);
    k_u<<<nb(N * 528), 256, 0, stream>>>(h1, rW3 + 3 * 8192, rb3 + 3 * 256, Ub, N);
    k_edge_l1<<<nb(E), 256, 0, stream>>>(feat, Y1w, src, dst, rnet(2), rnet(3),
                                         Ua, Ub, acc0, acc1, E);
    float* out0 = (float*)d_out;
    float* out1 = (float*)d_out + (size_t)N * 16;
    k_fin<<<nb(N * 16), 256, 0, stream>>>(acc0, deg, h1, Wself + 1 * 256, out0, N);
    k_out1<<<nb(N * 48), 256, 0, stream>>>(acc1, deg, out1, N);
}

// Round 2
// 645.519 us; speedup vs baseline: 2.7289x; 2.7289x over previous
//
#include <hip/hip_runtime.h>
#include <hip/hip_bf16.h>

// ---------------------------------------------------------------------------
// SE3Transformer block. Round 2: eliminate all scatter atomics.
//   - counting-sort edges by dst (cnt -> scan -> perm)
//   - edge kernels write per-edge bf16 rows to dst-sorted scratch (coalesced)
//   - segment-reduce kernels fuse invd, Y0, self-interaction, Y1 weighting
// U[n,k,o] per-node precompute (bf16) as before; layer-0 degree-1 branch dead.
// ---------------------------------------------------------------------------

#define Y0C 0.28209479177387814f
#define C1C 0.4886025119029199f

static __device__ __forceinline__ float bf2f(unsigned short u) {
    return __uint_as_float(((unsigned)u) << 16);
}
static __device__ __forceinline__ unsigned short f2bf(float f) {
    unsigned u = __float_as_uint(f);
    u += 0x7fffu + ((u >> 16) & 1u);   // round-to-nearest-even
    return (unsigned short)(u >> 16);
}
static __device__ __forceinline__ unsigned pack2(float a, float b) {
    return (unsigned)f2bf(a) | ((unsigned)f2bf(b) << 16);
}

struct RadialW { const float *W1, *b1, *g1, *gb1, *W2, *b2, *g2, *gb2; };

// radial MLP: (x0,x1,x2) -> 32 (LN,relu) -> 32 (LN,relu); out[32]=1 (rb3 row).
__device__ __forceinline__ void radial_net(float x0, float x1, float x2,
                                           RadialW rw, float* out /*[33]*/) {
    float h[32];
#pragma unroll
    for (int j = 0; j < 32; ++j)
        h[j] = rw.b1[j] + x0 * rw.W1[j] + x1 * rw.W1[32 + j] + x2 * rw.W1[64 + j];
    float mu = 0.f;
#pragma unroll
    for (int j = 0; j < 32; ++j) mu += h[j];
    mu *= 0.03125f;
    float var = 0.f;
#pragma unroll
    for (int j = 0; j < 32; ++j) { float d = h[j] - mu; var += d * d; }
    var *= 0.03125f;
    float rs = rsqrtf(var + 1e-5f);
#pragma unroll
    for (int j = 0; j < 32; ++j)
        h[j] = fmaxf((h[j] - mu) * rs * rw.g1[j] + rw.gb1[j], 0.f);

    float h2[32];
#pragma unroll
    for (int j = 0; j < 32; ++j) h2[j] = rw.b2[j];
#pragma unroll
    for (int k = 0; k < 32; ++k) {
        float hk = h[k];
        const float* __restrict__ w = rw.W2 + k * 32;
#pragma unroll
        for (int j = 0; j < 32; ++j) h2[j] += hk * w[j];
    }
    mu = 0.f;
#pragma unroll
    for (int j = 0; j < 32; ++j) mu += h2[j];
    mu *= 0.03125f;
    var = 0.f;
#pragma unroll
    for (int j = 0; j < 32; ++j) { float d = h2[j] - mu; var += d * d; }
    var *= 0.03125f;
    rs = rsqrtf(var + 1e-5f);
#pragma unroll
    for (int j = 0; j < 32; ++j)
        out[j] = fmaxf((h2[j] - mu) * rs * rw.g2[j] + rw.gb2[j], 0.f);
    out[32] = 1.f;
}

// v[o] = sum_{k<33} hv[k] * U[k*16+o]   (U row gathered, bf16)
__device__ __forceinline__ void contract_u(const float* hv,
                                           const uint4* __restrict__ Up,
                                           float* v /*[16]*/) {
#pragma unroll
    for (int o = 0; o < 16; ++o) v[o] = 0.f;
#pragma unroll
    for (int k = 0; k < 33; ++k) {
        float hk = hv[k];
        uint4 a = Up[2 * k];
        uint4 b = Up[2 * k + 1];
        v[0]  += hk * bf2f((unsigned short)(a.x));
        v[1]  += hk * bf2f((unsigned short)(a.x >> 16));
        v[2]  += hk * bf2f((unsigned short)(a.y));
        v[3]  += hk * bf2f((unsigned short)(a.y >> 16));
        v[4]  += hk * bf2f((unsigned short)(a.z));
        v[5]  += hk * bf2f((unsigned short)(a.z >> 16));
        v[6]  += hk * bf2f((unsigned short)(a.w));
        v[7]  += hk * bf2f((unsigned short)(a.w >> 16));
        v[8]  += hk * bf2f((unsigned short)(b.x));
        v[9]  += hk * bf2f((unsigned short)(b.x >> 16));
        v[10] += hk * bf2f((unsigned short)(b.y));
        v[11] += hk * bf2f((unsigned short)(b.y >> 16));
        v[12] += hk * bf2f((unsigned short)(b.z));
        v[13] += hk * bf2f((unsigned short)(b.z >> 16));
        v[14] += hk * bf2f((unsigned short)(b.w));
        v[15] += hk * bf2f((unsigned short)(b.w >> 16));
    }
}

// ---- node embedding -------------------------------------------------------
__global__ void k_embed1(const float* __restrict__ nf, const float* __restrict__ W1,
                         const float* __restrict__ b1, float* __restrict__ t, int N) {
    int idx = blockIdx.x * blockDim.x + threadIdx.x;
    if (idx >= N * 67) return;
    int n = idx / 67, j = idx - n * 67;
    const float* __restrict__ x = nf + (size_t)n * 67;
    float s = b1[j];
    for (int i = 0; i < 67; ++i) s += x[i] * W1[i * 67 + j];
    t[idx] = (s > 0.f) ? s : expm1f(s);   // ELU(alpha=1)
}

__global__ void k_embed2(const float* __restrict__ t, const float* __restrict__ W2,
                         const float* __restrict__ b2, float* __restrict__ h0, int N) {
    int idx = blockIdx.x * blockDim.x + threadIdx.x;
    if (idx >= N * 16) return;
    int n = idx >> 4, c = idx & 15;
    const float* __restrict__ x = t + (size_t)n * 67;
    float s = b2[c];
    for (int i = 0; i < 67; ++i) s += x[i] * W2[i * 16 + c];
    h0[idx] = s;
}

// ---- geometry -------------------------------------------------------------
__global__ void k_geom(const float* __restrict__ pos, const float* __restrict__ ew,
                       const int* __restrict__ src, const int* __restrict__ dst,
                       float* __restrict__ feat, float* __restrict__ Y1, int E) {
    int e = blockIdx.x * blockDim.x + threadIdx.x;
    if (e >= E) return;
    int s = src[e], d = dst[e];
    float dx = pos[3 * d]     - pos[3 * s];
    float dy = pos[3 * d + 1] - pos[3 * s + 1];
    float dz = pos[3 * d + 2] - pos[3 * s + 2];
    float r = sqrtf(dx * dx + dy * dy + dz * dz);
    float im = 1.f / fmaxf(r, 1e-8f);
    Y1[3 * e]     = C1C * dy * im;   // (y, z, x) order
    Y1[3 * e + 1] = C1C * dz * im;
    Y1[3 * e + 2] = C1C * dx * im;
    feat[3 * e]     = ew[2 * e];
    feat[3 * e + 1] = ew[2 * e + 1];
    feat[3 * e + 2] = r;
}

// ---- counting sort by dst -------------------------------------------------
__global__ void k_count(const int* __restrict__ dst, int* __restrict__ cnt,
                        int* __restrict__ pos, int E) {
    int e = blockIdx.x * blockDim.x + threadIdx.x;
    if (e >= E) return;
    pos[e] = atomicAdd(cnt + dst[e], 1);
}

__global__ __launch_bounds__(1024) void k_scan(const int* __restrict__ cnt,
                                               int* __restrict__ rowstart, int N) {
    __shared__ int buf[1024];
    __shared__ int carry;
    if (threadIdx.x == 0) { carry = 0; rowstart[0] = 0; }
    __syncthreads();
    for (int base = 0; base < N; base += 1024) {
        int i = base + (int)threadIdx.x;
        int v = (i < N) ? cnt[i] : 0;
        buf[threadIdx.x] = v;
        __syncthreads();
        for (int off = 1; off < 1024; off <<= 1) {
            int t = (threadIdx.x >= (unsigned)off) ? buf[threadIdx.x - off] : 0;
            __syncthreads();
            buf[threadIdx.x] += t;
            __syncthreads();
        }
        if (i < N) rowstart[i + 1] = carry + buf[threadIdx.x];
        __syncthreads();
        if (threadIdx.x == 1023) carry += buf[1023];
        __syncthreads();
    }
}

__global__ void k_scatter(const int* __restrict__ dst, const int* __restrict__ rowstart,
                          const int* __restrict__ pos, int* __restrict__ perm, int E) {
    int e = blockIdx.x * blockDim.x + threadIdx.x;
    if (e >= E) return;
    perm[rowstart[dst[e]] + pos[e]] = e;
}

// ---- per-node U precompute: U[n,k,o], k<32 from W3, k==32 from rb3 --------
__global__ void k_u(const float* __restrict__ h, const float* __restrict__ W3,
                    const float* __restrict__ b3, unsigned short* __restrict__ U, int N) {
    int idx = blockIdx.x * blockDim.x + threadIdx.x;
    if (idx >= N * 528) return;
    int n = idx / 528, r = idx - n * 528;
    int k = r >> 4, o = r & 15;
    const float* __restrict__ w = (k < 32) ? (W3 + k * 256 + o * 16) : (b3 + o * 16);
    const float* __restrict__ hn = h + (size_t)n * 16;
    float s = 0.f;
#pragma unroll
    for (int i = 0; i < 16; ++i) s += hn[i] * w[i];
    U[idx] = f2bf(s);
}

// ---- edge kernels (dst-sorted, no atomics) --------------------------------
__global__ __launch_bounds__(256) void k_edge0(
    const float* __restrict__ feat, const int* __restrict__ src,
    const int* __restrict__ perm, RadialW ra,
    const unsigned short* __restrict__ Ua, unsigned short* __restrict__ msg, int E) {
    int t = blockIdx.x * blockDim.x + threadIdx.x;
    if (t >= E) return;
    int e = perm[t];
    float f0 = feat[3 * e], f1 = feat[3 * e + 1], f2 = feat[3 * e + 2];
    int sn = src[e];
    float hv[33], v[16];
    radial_net(f0, f1, f2, ra, hv);
    contract_u(hv, (const uint4*)(Ua + (size_t)sn * 528), v);
    uint4* m = (uint4*)(msg + (size_t)t * 16);
    m[0] = make_uint4(pack2(v[0], v[1]), pack2(v[2], v[3]),
                      pack2(v[4], v[5]), pack2(v[6], v[7]));
    m[1] = make_uint4(pack2(v[8], v[9]), pack2(v[10], v[11]),
                      pack2(v[12], v[13]), pack2(v[14], v[15]));
}

__global__ __launch_bounds__(256) void k_edge1(
    const float* __restrict__ feat, const float* __restrict__ Y1,
    const int* __restrict__ src, const int* __restrict__ perm,
    RadialW ra, RadialW rb,
    const unsigned short* __restrict__ Ua, const unsigned short* __restrict__ Ub,
    unsigned short* __restrict__ msg, int E) {   // stride 40 shorts (80 B)
    int t = blockIdx.x * blockDim.x + threadIdx.x;
    if (t >= E) return;
    int e = perm[t];
    float f0 = feat[3 * e], f1 = feat[3 * e + 1], f2 = feat[3 * e + 2];
    int sn = src[e];
    float hv[33], va[16], vb[16];
    radial_net(f0, f1, f2, ra, hv);
    contract_u(hv, (const uint4*)(Ua + (size_t)sn * 528), va);
    radial_net(f0, f1, f2, rb, hv);
    contract_u(hv, (const uint4*)(Ub + (size_t)sn * 528), vb);
    float y0 = Y1[3 * e], y1 = Y1[3 * e + 1], y2 = Y1[3 * e + 2];
    unsigned short* row = msg + (size_t)t * 40;
    uint4* m = (uint4*)row;
    m[0] = make_uint4(pack2(va[0], va[1]), pack2(va[2], va[3]),
                      pack2(va[4], va[5]), pack2(va[6], va[7]));
    m[1] = make_uint4(pack2(va[8], va[9]), pack2(va[10], va[11]),
                      pack2(va[12], va[13]), pack2(va[14], va[15]));
    m[2] = make_uint4(pack2(vb[0], vb[1]), pack2(vb[2], vb[3]),
                      pack2(vb[4], vb[5]), pack2(vb[6], vb[7]));
    m[3] = make_uint4(pack2(vb[8], vb[9]), pack2(vb[10], vb[11]),
                      pack2(vb[12], vb[13]), pack2(vb[14], vb[15]));
    ((uint2*)row)[8] = make_uint2(pack2(y0, y1), pack2(y2, 0.f));
}

// ---- segment reduces ------------------------------------------------------
__global__ void k_reduce0(const unsigned short* __restrict__ msg,
                          const int* __restrict__ rowstart,
                          const float* __restrict__ h, const float* __restrict__ Wself,
                          float* __restrict__ out, int N) {
    int idx = blockIdx.x * blockDim.x + threadIdx.x;
    if (idx >= N * 16) return;
    int n = idx >> 4, o = idx & 15;
    int s = rowstart[n], t1 = rowstart[n + 1];
    float acc = 0.f;
    for (int t = s; t < t1; ++t) acc += bf2f(msg[(size_t)t * 16 + o]);
    int d = t1 - s;
    float invd = (d > 0) ? 1.f / (float)d : 0.f;
    float hi   = (d > 0) ? 1.f : 0.f;
    const float* __restrict__ hn = h + (size_t)n * 16;
    const float* __restrict__ w  = Wself + o * 16;
    float self = 0.f;
#pragma unroll
    for (int c = 0; c < 16; ++c) self += hn[c] * w[c];
    out[idx] = Y0C * acc * invd + hi * self;
}

__global__ void k_reduce1(const unsigned short* __restrict__ msg,  // stride 40
                          const int* __restrict__ rowstart,
                          const float* __restrict__ h, const float* __restrict__ Wself,
                          float* __restrict__ out0, float* __restrict__ out1, int N) {
    int idx = blockIdx.x * blockDim.x + threadIdx.x;
    if (idx >= N * 16) return;
    int n = idx >> 4, o = idx & 15;
    int s = rowstart[n], t1 = rowstart[n + 1];
    float a0 = 0.f, ax = 0.f, ay = 0.f, az = 0.f;
    for (int t = s; t < t1; ++t) {
        const unsigned short* row = msg + (size_t)t * 40;
        a0 += bf2f(row[o]);
        float b = bf2f(row[16 + o]);
        ax += b * bf2f(row[32]);
        ay += b * bf2f(row[33]);
        az += b * bf2f(row[34]);
    }
    int d = t1 - s;
    float invd = (d > 0) ? 1.f / (float)d : 0.f;
    float hi   = (d > 0) ? 1.f : 0.f;
    const float* __restrict__ hn = h + (size_t)n * 16;
    const float* __restrict__ w  = Wself + o * 16;
    float self = 0.f;
#pragma unroll
    for (int c = 0; c < 16; ++c) self += hn[c] * w[c];
    out0[idx] = Y0C * a0 * invd + hi * self;
    out1[(size_t)idx * 3]     = ax * invd;
    out1[(size_t)idx * 3 + 1] = ay * invd;
    out1[(size_t)idx * 3 + 2] = az * invd;
}

// ---------------------------------------------------------------------------
extern "C" void kernel_launch(void* const* d_in, const int* in_sizes, int n_in,
                              void* d_out, int out_size, void* d_ws, size_t ws_size,
                              hipStream_t stream) {
    (void)n_in; (void)out_size; (void)ws_size;
    const float* node_feats = (const float*)d_in[0];
    const float* pos    = (const float*)d_in[1];
    const float* edge_w = (const float*)d_in[2];
    const float* lin1_W = (const float*)d_in[3];
    const float* lin1_b = (const float*)d_in[4];
    const float* lin2_W = (const float*)d_in[5];
    const float* lin2_b = (const float*)d_in[6];
    const float* rW1    = (const float*)d_in[7];
    const float* rb1    = (const float*)d_in[8];
    const float* ln1_g  = (const float*)d_in[9];
    const float* ln1_b  = (const float*)d_in[10];
    const float* rW2    = (const float*)d_in[11];
    const float* rb2    = (const float*)d_in[12];
    const float* ln2_g  = (const float*)d_in[13];
    const float* ln2_b  = (const float*)d_in[14];
    const float* rW3    = (const float*)d_in[15];
    const float* rb3    = (const float*)d_in[16];
    const float* Wself  = (const float*)d_in[17];
    const int*   src    = (const int*)d_in[18];
    const int*   dst    = (const int*)d_in[19];

    const int N = in_sizes[1] / 3;     // pos is [N,3]
    const int E = in_sizes[18];        // src is [E]

    char* ws = (char*)d_ws;
    size_t off = 0;
    auto carve = [&](size_t bytes) -> char* {
        char* p = ws + off;
        off = (off + bytes + 255) & ~(size_t)255;
        return p;
    };
    float* h0   = (float*)carve((size_t)N * 16 * 4);
    float* h1   = (float*)carve((size_t)N * 16 * 4);
    float* feat = (float*)carve((size_t)E * 3 * 4);
    float* Y1w  = (float*)carve((size_t)E * 3 * 4);
    int*   cnt  = (int*)carve((size_t)N * 4);
    int*   rowstart = (int*)carve((size_t)(N + 1) * 4);
    int*   epos = (int*)carve((size_t)E * 4);
    int*   perm = (int*)carve((size_t)E * 4);
    unsigned short* Ua = (unsigned short*)carve((size_t)N * 528 * 2);
    unsigned short* Ub = (unsigned short*)carve((size_t)N * 528 * 2);
    unsigned short* msg = (unsigned short*)carve((size_t)E * 40 * 2);  // layer0 uses stride16 prefix
    float* tmb = (float*)msg;  // [N,67] embed temp overlaps msg (disjoint lifetime)

    auto nb = [](int n) { return (n + 255) / 256; };

    hipMemsetAsync(cnt, 0, (size_t)N * 4, stream);

    k_embed1<<<nb(N * 67), 256, 0, stream>>>(node_feats, lin1_W, lin1_b, tmb, N);
    k_embed2<<<nb(N * 16), 256, 0, stream>>>(tmb, lin2_W, lin2_b, h0, N);
    k_geom<<<nb(E), 256, 0, stream>>>(pos, edge_w, src, dst, feat, Y1w, E);

    k_count<<<nb(E), 256, 0, stream>>>(dst, cnt, epos, E);
    k_scan<<<1, 1024, 0, stream>>>(cnt, rowstart, N);
    k_scatter<<<nb(E), 256, 0, stream>>>(dst, rowstart, epos, perm, E);

    auto rnet = [&](int net) -> RadialW {
        RadialW r;
        r.W1 = rW1 + net * 96;   r.b1 = rb1 + net * 32;
        r.g1 = ln1_g + net * 32; r.gb1 = ln1_b + net * 32;
        r.W2 = rW2 + net * 1024; r.b2 = rb2 + net * 32;
        r.g2 = ln2_g + net * 32; r.gb2 = ln2_b + net * 32;
        return r;
    };

    // ---- layer 0 (degree-1 branch dead: only net 0) ----
    k_u<<<nb(N * 528), 256, 0, stream>>>(h0, rW3 + 0 * 8192, rb3 + 0 * 256, Ua, N);
    k_edge0<<<nb(E), 256, 0, stream>>>(feat, src, perm, rnet(0), Ua, msg, E);
    k_reduce0<<<nb(N * 16), 256, 0, stream>>>(msg, rowstart, h0, Wself + 0 * 256, h1, N);

    // ---- layer 1 (nets 2,3) ----
    k_u<<<nb(N * 528), 256, 0, stream>>>(h1, rW3 + 2 * 8192, rb3 + 2 * 256, Ua, N);
    k_u<<<nb(N * 528), 256, 0, stream>>>(h1, rW3 + 3 * 8192, rb3 + 3 * 256, Ub, N);
    k_edge1<<<nb(E), 256, 0, stream>>>(feat, Y1w, src, perm, rnet(2), rnet(3),
                                       Ua, Ub, msg, E);
    float* out0 = (float*)d_out;
    float* out1 = (float*)d_out + (size_t)N * 16;
    k_reduce1<<<nb(N * 16), 256, 0, stream>>>(msg, rowstart, h1, Wself + 1 * 256,
                                              out0, out1, N);
}

// Round 3
// 523.969 us; speedup vs baseline: 3.3620x; 1.2320x over previous
//
#include <hip/hip_runtime.h>
#include <hip/hip_bf16.h>

// ---------------------------------------------------------------------------
// SE3Transformer block. Round 3: src-locality for the U gather.
//   - TWO counting sorts: by dst (for reduce) and by src (for edge traversal)
//   - k_prep writes edge records (feat, Y1, src) into src-sorted layout
//   - edge kernels: streaming reads, U[src] gathers hit L1/L2 (out-deg ~16
//     reuse within a wave), scatter-WRITE msg rows to dst-sorted slots
//   - reduces read msg contiguously (dst-sorted), fuse invd/Y0/self/Y1
// U[n,k,o] per-node precompute (bf16); layer-0 degree-1 branch is dead.
// ---------------------------------------------------------------------------

#define Y0C 0.28209479177387814f
#define C1C 0.4886025119029199f

static __device__ __forceinline__ float bf2f(unsigned short u) {
    return __uint_as_float(((unsigned)u) << 16);
}
static __device__ __forceinline__ unsigned short f2bf(float f) {
    unsigned u = __float_as_uint(f);
    u += 0x7fffu + ((u >> 16) & 1u);   // round-to-nearest-even
    return (unsigned short)(u >> 16);
}
static __device__ __forceinline__ unsigned pack2(float a, float b) {
    return (unsigned)f2bf(a) | ((unsigned)f2bf(b) << 16);
}

struct RadialW { const float *W1, *b1, *g1, *gb1, *W2, *b2, *g2, *gb2; };

// radial MLP: (x0,x1,x2) -> 32 (LN,relu) -> 32 (LN,relu); out[32]=1 (rb3 row).
__device__ __forceinline__ void radial_net(float x0, float x1, float x2,
                                           RadialW rw, float* out /*[33]*/) {
    float h[32];
#pragma unroll
    for (int j = 0; j < 32; ++j)
        h[j] = rw.b1[j] + x0 * rw.W1[j] + x1 * rw.W1[32 + j] + x2 * rw.W1[64 + j];
    float mu = 0.f;
#pragma unroll
    for (int j = 0; j < 32; ++j) mu += h[j];
    mu *= 0.03125f;
    float var = 0.f;
#pragma unroll
    for (int j = 0; j < 32; ++j) { float d = h[j] - mu; var += d * d; }
    var *= 0.03125f;
    float rs = rsqrtf(var + 1e-5f);
#pragma unroll
    for (int j = 0; j < 32; ++j)
        h[j] = fmaxf((h[j] - mu) * rs * rw.g1[j] + rw.gb1[j], 0.f);

    float h2[32];
#pragma unroll
    for (int j = 0; j < 32; ++j) h2[j] = rw.b2[j];
#pragma unroll
    for (int k = 0; k < 32; ++k) {
        float hk = h[k];
        const float* __restrict__ w = rw.W2 + k * 32;
#pragma unroll
        for (int j = 0; j < 32; ++j) h2[j] += hk * w[j];
    }
    mu = 0.f;
#pragma unroll
    for (int j = 0; j < 32; ++j) mu += h2[j];
    mu *= 0.03125f;
    var = 0.f;
#pragma unroll
    for (int j = 0; j < 32; ++j) { float d = h2[j] - mu; var += d * d; }
    var *= 0.03125f;
    rs = rsqrtf(var + 1e-5f);
#pragma unroll
    for (int j = 0; j < 32; ++j)
        out[j] = fmaxf((h2[j] - mu) * rs * rw.g2[j] + rw.gb2[j], 0.f);
    out[32] = 1.f;
}

// v[o] = sum_{k<33} hv[k] * U[k*16+o]   (U row, bf16)
__device__ __forceinline__ void contract_u(const float* hv,
                                           const uint4* __restrict__ Up,
                                           float* v /*[16]*/) {
#pragma unroll
    for (int o = 0; o < 16; ++o) v[o] = 0.f;
#pragma unroll
    for (int k = 0; k < 33; ++k) {
        float hk = hv[k];
        uint4 a = Up[2 * k];
        uint4 b = Up[2 * k + 1];
        v[0]  += hk * bf2f((unsigned short)(a.x));
        v[1]  += hk * bf2f((unsigned short)(a.x >> 16));
        v[2]  += hk * bf2f((unsigned short)(a.y));
        v[3]  += hk * bf2f((unsigned short)(a.y >> 16));
        v[4]  += hk * bf2f((unsigned short)(a.z));
        v[5]  += hk * bf2f((unsigned short)(a.z >> 16));
        v[6]  += hk * bf2f((unsigned short)(a.w));
        v[7]  += hk * bf2f((unsigned short)(a.w >> 16));
        v[8]  += hk * bf2f((unsigned short)(b.x));
        v[9]  += hk * bf2f((unsigned short)(b.x >> 16));
        v[10] += hk * bf2f((unsigned short)(b.y));
        v[11] += hk * bf2f((unsigned short)(b.y >> 16));
        v[12] += hk * bf2f((unsigned short)(b.z));
        v[13] += hk * bf2f((unsigned short)(b.z >> 16));
        v[14] += hk * bf2f((unsigned short)(b.w));
        v[15] += hk * bf2f((unsigned short)(b.w >> 16));
    }
}

// ---- node embedding -------------------------------------------------------
__global__ void k_embed1(const float* __restrict__ nf, const float* __restrict__ W1,
                         const float* __restrict__ b1, float* __restrict__ t, int N) {
    int idx = blockIdx.x * blockDim.x + threadIdx.x;
    if (idx >= N * 67) return;
    int n = idx / 67, j = idx - n * 67;
    const float* __restrict__ x = nf + (size_t)n * 67;
    float s = b1[j];
    for (int i = 0; i < 67; ++i) s += x[i] * W1[i * 67 + j];
    t[idx] = (s > 0.f) ? s : expm1f(s);   // ELU(alpha=1)
}

__global__ void k_embed2(const float* __restrict__ t, const float* __restrict__ W2,
                         const float* __restrict__ b2, float* __restrict__ h0, int N) {
    int idx = blockIdx.x * blockDim.x + threadIdx.x;
    if (idx >= N * 16) return;
    int n = idx >> 4, c = idx & 15;
    const float* __restrict__ x = t + (size_t)n * 67;
    float s = b2[c];
    for (int i = 0; i < 67; ++i) s += x[i] * W2[i * 16 + c];
    h0[idx] = s;
}

// ---- counting sorts -------------------------------------------------------
__global__ void k_count2(const int* __restrict__ src, const int* __restrict__ dst,
                         int* __restrict__ cntd, int* __restrict__ cnts,
                         int* __restrict__ posd, int* __restrict__ poss, int E) {
    int e = blockIdx.x * blockDim.x + threadIdx.x;
    if (e >= E) return;
    posd[e] = atomicAdd(cntd + dst[e], 1);
    poss[e] = atomicAdd(cnts + src[e], 1);
}

// grid=2: block 0 scans cntd->rsd, block 1 scans cnts->rss
__global__ __launch_bounds__(1024) void k_scan2(const int* __restrict__ cntd,
                                                int* __restrict__ rsd,
                                                const int* __restrict__ cnts,
                                                int* __restrict__ rss, int N) {
    const int* __restrict__ c = (blockIdx.x == 0) ? cntd : cnts;
    int* __restrict__ rs      = (blockIdx.x == 0) ? rsd  : rss;
    int chunk = (N + 1023) >> 10;
    int lo = (int)threadIdx.x * chunk;
    int sum = 0;
    for (int j = 0; j < chunk; ++j) { int i = lo + j; sum += (i < N) ? c[i] : 0; }
    __shared__ int ps[1024];
    ps[threadIdx.x] = sum;
    __syncthreads();
    for (int off = 1; off < 1024; off <<= 1) {
        int t = (threadIdx.x >= (unsigned)off) ? ps[threadIdx.x - off] : 0;
        __syncthreads();
        ps[threadIdx.x] += t;
        __syncthreads();
    }
    int run = threadIdx.x ? ps[threadIdx.x - 1] : 0;
    if (threadIdx.x == 0) rs[0] = 0;
    for (int j = 0; j < chunk; ++j) {
        int i = lo + j;
        if (i < N) { run += c[i]; rs[i + 1] = run; }
    }
}

// ---- prep: geometry + edge record in src-sorted layout + s2d map ----------
__global__ void k_prep(const float* __restrict__ pos, const float* __restrict__ ew,
                       const int* __restrict__ src, const int* __restrict__ dst,
                       const int* __restrict__ rsd, const int* __restrict__ rss,
                       const int* __restrict__ posd, const int* __restrict__ poss,
                       float4* __restrict__ edgeS, int* __restrict__ s2d, int E) {
    int e = blockIdx.x * blockDim.x + threadIdx.x;
    if (e >= E) return;
    int s = src[e], d = dst[e];
    float dx = pos[3 * d]     - pos[3 * s];
    float dy = pos[3 * d + 1] - pos[3 * s + 1];
    float dz = pos[3 * d + 2] - pos[3 * s + 2];
    float r = sqrtf(dx * dx + dy * dy + dz * dz);
    float im = 1.f / fmaxf(r, 1e-8f);
    int ts = rss[s] + poss[e];
    int td = rsd[d] + posd[e];
    s2d[ts] = td;
    edgeS[2 * ts]     = make_float4(ew[2 * e], ew[2 * e + 1], r, __int_as_float(s));
    edgeS[2 * ts + 1] = make_float4(C1C * dy * im, C1C * dz * im, C1C * dx * im, 0.f);
}

// ---- per-node U precompute: U[n,k,o], k<32 from W3, k==32 from rb3 --------
__global__ void k_u(const float* __restrict__ h, const float* __restrict__ W3,
                    const float* __restrict__ b3, unsigned short* __restrict__ U, int N) {
    int idx = blockIdx.x * blockDim.x + threadIdx.x;
    if (idx >= N * 528) return;
    int n = idx / 528, r = idx - n * 528;
    int k = r >> 4, o = r & 15;
    const float* __restrict__ w = (k < 32) ? (W3 + k * 256 + o * 16) : (b3 + o * 16);
    const float* __restrict__ hn = h + (size_t)n * 16;
    float s = 0.f;
#pragma unroll
    for (int i = 0; i < 16; ++i) s += hn[i] * w[i];
    U[idx] = f2bf(s);
}

// ---- edge kernels (src-sorted traversal, scatter-write to dst slot) -------
__global__ __launch_bounds__(256) void k_edge0(
    const float4* __restrict__ edgeS, const int* __restrict__ s2d, RadialW ra,
    const unsigned short* __restrict__ Ua, unsigned short* __restrict__ msg, int E) {
    int t = blockIdx.x * blockDim.x + threadIdx.x;
    if (t >= E) return;
    float4 a = edgeS[2 * t];
    int sn = __float_as_int(a.w);
    float hv[33], v[16];
    radial_net(a.x, a.y, a.z, ra, hv);
    contract_u(hv, (const uint4*)(Ua + (size_t)sn * 528), v);
    int td = s2d[t];
    uint4* m = (uint4*)(msg + (size_t)td * 16);
    m[0] = make_uint4(pack2(v[0], v[1]), pack2(v[2], v[3]),
                      pack2(v[4], v[5]), pack2(v[6], v[7]));
    m[1] = make_uint4(pack2(v[8], v[9]), pack2(v[10], v[11]),
                      pack2(v[12], v[13]), pack2(v[14], v[15]));
}

__global__ __launch_bounds__(256) void k_edge1(
    const float4* __restrict__ edgeS, const int* __restrict__ s2d,
    RadialW ra, RadialW rb,
    const unsigned short* __restrict__ Ua, const unsigned short* __restrict__ Ub,
    unsigned short* __restrict__ msg, int E) {   // stride 40 shorts (80 B)
    int t = blockIdx.x * blockDim.x + threadIdx.x;
    if (t >= E) return;
    float4 a = edgeS[2 * t];
    float4 b = edgeS[2 * t + 1];
    int sn = __float_as_int(a.w);
    float hv[33], va[16], vb[16];
    radial_net(a.x, a.y, a.z, ra, hv);
    contract_u(hv, (const uint4*)(Ua + (size_t)sn * 528), va);
    radial_net(a.x, a.y, a.z, rb, hv);
    contract_u(hv, (const uint4*)(Ub + (size_t)sn * 528), vb);
    int td = s2d[t];
    unsigned short* row = msg + (size_t)td * 40;
    uint4* m = (uint4*)row;
    m[0] = make_uint4(pack2(va[0], va[1]), pack2(va[2], va[3]),
                      pack2(va[4], va[5]), pack2(va[6], va[7]));
    m[1] = make_uint4(pack2(va[8], va[9]), pack2(va[10], va[11]),
                      pack2(va[12], va[13]), pack2(va[14], va[15]));
    m[2] = make_uint4(pack2(vb[0], vb[1]), pack2(vb[2], vb[3]),
                      pack2(vb[4], vb[5]), pack2(vb[6], vb[7]));
    m[3] = make_uint4(pack2(vb[8], vb[9]), pack2(vb[10], vb[11]),
                      pack2(vb[12], vb[13]), pack2(vb[14], vb[15]));
    ((uint2*)row)[8] = make_uint2(pack2(b.x, b.y), pack2(b.z, 0.f));
}

// ---- segment reduces (contiguous, dst-sorted) -----------------------------
__global__ void k_reduce0(const unsigned short* __restrict__ msg,
                          const int* __restrict__ rowstart,
                          const float* __restrict__ h, const float* __restrict__ Wself,
                          float* __restrict__ out, int N) {
    int idx = blockIdx.x * blockDim.x + threadIdx.x;
    if (idx >= N * 16) return;
    int n = idx >> 4, o = idx & 15;
    int s = rowstart[n], t1 = rowstart[n + 1];
    float acc = 0.f;
    for (int t = s; t < t1; ++t) acc += bf2f(msg[(size_t)t * 16 + o]);
    int d = t1 - s;
    float invd = (d > 0) ? 1.f / (float)d : 0.f;
    float hi   = (d > 0) ? 1.f : 0.f;
    const float* __restrict__ hn = h + (size_t)n * 16;
    const float* __restrict__ w  = Wself + o * 16;
    float self = 0.f;
#pragma unroll
    for (int c = 0; c < 16; ++c) self += hn[c] * w[c];
    out[idx] = Y0C * acc * invd + hi * self;
}

__global__ void k_reduce1(const unsigned short* __restrict__ msg,  // stride 40
                          const int* __restrict__ rowstart,
                          const float* __restrict__ h, const float* __restrict__ Wself,
                          float* __restrict__ out0, float* __restrict__ out1, int N) {
    int idx = blockIdx.x * blockDim.x + threadIdx.x;
    if (idx >= N * 16) return;
    int n = idx >> 4, o = idx & 15;
    int s = rowstart[n], t1 = rowstart[n + 1];
    float a0 = 0.f, ax = 0.f, ay = 0.f, az = 0.f;
    for (int t = s; t < t1; ++t) {
        const unsigned short* row = msg + (size_t)t * 40;
        a0 += bf2f(row[o]);
        float b = bf2f(row[16 + o]);
        ax += b * bf2f(row[32]);
        ay += b * bf2f(row[33]);
        az += b * bf2f(row[34]);
    }
    int d = t1 - s;
    float invd = (d > 0) ? 1.f / (float)d : 0.f;
    float hi   = (d > 0) ? 1.f : 0.f;
    const float* __restrict__ hn = h + (size_t)n * 16;
    const float* __restrict__ w  = Wself + o * 16;
    float self = 0.f;
#pragma unroll
    for (int c = 0; c < 16; ++c) self += hn[c] * w[c];
    out0[idx] = Y0C * a0 * invd + hi * self;
    out1[(size_t)idx * 3]     = ax * invd;
    out1[(size_t)idx * 3 + 1] = ay * invd;
    out1[(size_t)idx * 3 + 2] = az * invd;
}

// ---------------------------------------------------------------------------
extern "C" void kernel_launch(void* const* d_in, const int* in_sizes, int n_in,
                              void* d_out, int out_size, void* d_ws, size_t ws_size,
                              hipStream_t stream) {
    (void)n_in; (void)out_size; (void)ws_size;
    const float* node_feats = (const float*)d_in[0];
    const float* pos    = (const float*)d_in[1];
    const float* edge_w = (const float*)d_in[2];
    const float* lin1_W = (const float*)d_in[3];
    const float* lin1_b = (const float*)d_in[4];
    const float* lin2_W = (const float*)d_in[5];
    const float* lin2_b = (const float*)d_in[6];
    const float* rW1    = (const float*)d_in[7];
    const float* rb1    = (const float*)d_in[8];
    const float* ln1_g  = (const float*)d_in[9];
    const float* ln1_b  = (const float*)d_in[10];
    const float* rW2    = (const float*)d_in[11];
    const float* rb2    = (const float*)d_in[12];
    const float* ln2_g  = (const float*)d_in[13];
    const float* ln2_b  = (const float*)d_in[14];
    const float* rW3    = (const float*)d_in[15];
    const float* rb3    = (const float*)d_in[16];
    const float* Wself  = (const float*)d_in[17];
    const int*   src    = (const int*)d_in[18];
    const int*   dst    = (const int*)d_in[19];

    const int N = in_sizes[1] / 3;     // pos is [N,3]
    const int E = in_sizes[18];        // src is [E]

    char* ws = (char*)d_ws;
    size_t off = 0;
    auto carve = [&](size_t bytes) -> char* {
        char* p = ws + off;
        off = (off + bytes + 255) & ~(size_t)255;
        return p;
    };
    float* h0   = (float*)carve((size_t)N * 16 * 4);
    float* h1   = (float*)carve((size_t)N * 16 * 4);
    int*   cntd = (int*)carve((size_t)N * 4);
    int*   cnts = (int*)carve((size_t)N * 4);
    int*   rsd  = (int*)carve((size_t)(N + 1) * 4);
    int*   rss  = (int*)carve((size_t)(N + 1) * 4);
    int*   s2d  = (int*)carve((size_t)E * 4);
    float4* edgeS = (float4*)carve((size_t)E * 32);
    unsigned short* Ua = (unsigned short*)carve((size_t)N * 528 * 2);
    unsigned short* Ub = (unsigned short*)carve((size_t)N * 528 * 2);
    unsigned short* msg = (unsigned short*)carve((size_t)E * 40 * 2);
    // disjoint-lifetime overlays inside msg (all dead before edge kernels run):
    float* tmb  = (float*)msg;                           // [N,67] embed temp
    int*   posd = (int*)((char*)msg + (8u << 20));       // [E]
    int*   poss = (int*)((char*)msg + (14u << 20));      // [E]

    auto nb = [](int n) { return (n + 255) / 256; };

    hipMemsetAsync(cntd, 0, (size_t)N * 4, stream);
    hipMemsetAsync(cnts, 0, (size_t)N * 4, stream);

    k_embed1<<<nb(N * 67), 256, 0, stream>>>(node_feats, lin1_W, lin1_b, tmb, N);
    k_embed2<<<nb(N * 16), 256, 0, stream>>>(tmb, lin2_W, lin2_b, h0, N);

    k_count2<<<nb(E), 256, 0, stream>>>(src, dst, cntd, cnts, posd, poss, E);
    k_scan2<<<2, 1024, 0, stream>>>(cntd, rsd, cnts, rss, N);
    k_prep<<<nb(E), 256, 0, stream>>>(pos, edge_w, src, dst, rsd, rss, posd, poss,
                                      edgeS, s2d, E);

    auto rnet = [&](int net) -> RadialW {
        RadialW r;
        r.W1 = rW1 + net * 96;   r.b1 = rb1 + net * 32;
        r.g1 = ln1_g + net * 32; r.gb1 = ln1_b + net * 32;
        r.W2 = rW2 + net * 1024; r.b2 = rb2 + net * 32;
        r.g2 = ln2_g + net * 32; r.gb2 = ln2_b + net * 32;
        return r;
    };

    // ---- layer 0 (degree-1 branch dead: only net 0) ----
    k_u<<<nb(N * 528), 256, 0, stream>>>(h0, rW3 + 0 * 8192, rb3 + 0 * 256, Ua, N);
    k_edge0<<<nb(E), 256, 0, stream>>>(edgeS, s2d, rnet(0), Ua, msg, E);
    k_reduce0<<<nb(N * 16), 256, 0, stream>>>(msg, rsd, h0, Wself + 0 * 256, h1, N);

    // ---- layer 1 (nets 2,3) ----
    k_u<<<nb(N * 528), 256, 0, stream>>>(h1, rW3 + 2 * 8192, rb3 + 2 * 256, Ua, N);
    k_u<<<nb(N * 528), 256, 0, stream>>>(h1, rW3 + 3 * 8192, rb3 + 3 * 256, Ub, N);
    k_edge1<<<nb(E), 256, 0, stream>>>(edgeS, s2d, rnet(2), rnet(3), Ua, Ub, msg, E);
    float* out0 = (float*)d_out;
    float* out1 = (float*)d_out + (size_t)N * 16;
    k_reduce1<<<nb(N * 16), 256, 0, stream>>>(msg, rsd, h1, Wself + 1 * 256,
                                              out0, out1, N);
}

// Round 4
// 472.059 us; speedup vs baseline: 3.7317x; 1.1100x over previous
//
#include <hip/hip_runtime.h>
#include <hip/hip_fp16.h>

// ---------------------------------------------------------------------------
// SE3Transformer block. Round 4:
//   - U stored as f16 k-PAIRS (+ f32 tail row): contraction uses v_pk_fma_f16
//     (2 MACs/instr, no unpack)  [radial MLP + LN stay f32 for precision]
//   - k_edgeL1 split per (edge, net): grid 2E, 2x latency hiding, lower VGPR
//   - Y1 written dst-sorted by k_prep (edge kernels never touch it)
//   - k_u restructured: thread=(n,o), h in registers -> ~30x less L1 traffic,
//     both layer-1 nets in one launch
// Structure from R3: dual counting sort (src for traversal, dst for reduce),
// edge kernels read streaming, scatter-write 32B msg half-rows to dst slots.
// ---------------------------------------------------------------------------

#define Y0C 0.28209479177387814f
#define C1C 0.4886025119029199f

static __device__ __forceinline__ unsigned h2u(__half2 h) {
    union { __half2 h; unsigned u; } x; x.h = h; return x.u;
}
static __device__ __forceinline__ __half2 u2h(unsigned u) {
    union { unsigned u; __half2 h; } x; x.u = u; return x.h;
}
static __device__ __forceinline__ float hbits2f(unsigned short s) {
    __half_raw r; r.x = s; return __half2float((__half)r);
}

struct RadialW { const float *W1, *b1, *g1, *gb1, *W2, *b2, *g2, *gb2; };

// radial MLP (f32): (x0,x1,x2) -> 32 (LN,relu) -> 32 (LN,relu) -> f16 k-pairs
__device__ __forceinline__ void radial_net_pk(float x0, float x1, float x2,
                                              RadialW rw, __half2* hvpk /*[16]*/) {
    float h[32];
#pragma unroll
    for (int j = 0; j < 32; ++j)
        h[j] = rw.b1[j] + x0 * rw.W1[j] + x1 * rw.W1[32 + j] + x2 * rw.W1[64 + j];
    float mu = 0.f;
#pragma unroll
    for (int j = 0; j < 32; ++j) mu += h[j];
    mu *= 0.03125f;
    float var = 0.f;
#pragma unroll
    for (int j = 0; j < 32; ++j) { float d = h[j] - mu; var += d * d; }
    var *= 0.03125f;
    float rs = rsqrtf(var + 1e-5f);
#pragma unroll
    for (int j = 0; j < 32; ++j)
        h[j] = fmaxf((h[j] - mu) * rs * rw.g1[j] + rw.gb1[j], 0.f);

    float h2[32];
#pragma unroll
    for (int j = 0; j < 32; ++j) h2[j] = rw.b2[j];
#pragma unroll
    for (int k = 0; k < 32; ++k) {
        float hk = h[k];
        const float* __restrict__ w = rw.W2 + k * 32;   // uniform -> s_load
#pragma unroll
        for (int j = 0; j < 32; ++j) h2[j] += hk * w[j];
    }
    mu = 0.f;
#pragma unroll
    for (int j = 0; j < 32; ++j) mu += h2[j];
    mu *= 0.03125f;
    var = 0.f;
#pragma unroll
    for (int j = 0; j < 32; ++j) { float d = h2[j] - mu; var += d * d; }
    var *= 0.03125f;
    rs = rsqrtf(var + 1e-5f);
    float y[32];
#pragma unroll
    for (int j = 0; j < 32; ++j)
        y[j] = fmaxf((h2[j] - mu) * rs * rw.g2[j] + rw.gb2[j], 0.f);
#pragma unroll
    for (int p = 0; p < 16; ++p)
        hvpk[p] = __floats2half2_rn(y[2 * p], y[2 * p + 1]);
}

// v[o] = tail[o] + sum_p hvpk[p] .* Um[o][p]   (f16 packed FMA, f32 finish)
__device__ __forceinline__ void contract_pk(const __half2* hvpk,
                                            const uint4* __restrict__ Um,
                                            const float* __restrict__ Ut,
                                            float* v /*[16]*/) {
    float4 t0 = ((const float4*)Ut)[0];
    float4 t1 = ((const float4*)Ut)[1];
    float4 t2 = ((const float4*)Ut)[2];
    float4 t3 = ((const float4*)Ut)[3];
    float tail[16] = {t0.x, t0.y, t0.z, t0.w, t1.x, t1.y, t1.z, t1.w,
                      t2.x, t2.y, t2.z, t2.w, t3.x, t3.y, t3.z, t3.w};
#pragma unroll
    for (int o = 0; o < 16; ++o) {
        uint4 q0 = Um[o * 4];
        uint4 q1 = Um[o * 4 + 1];
        uint4 q2 = Um[o * 4 + 2];
        uint4 q3 = Um[o * 4 + 3];
        __half2 acc = __hmul2(hvpk[0], u2h(q0.x));
        acc = __hfma2(hvpk[1],  u2h(q0.y), acc);
        acc = __hfma2(hvpk[2],  u2h(q0.z), acc);
        acc = __hfma2(hvpk[3],  u2h(q0.w), acc);
        acc = __hfma2(hvpk[4],  u2h(q1.x), acc);
        acc = __hfma2(hvpk[5],  u2h(q1.y), acc);
        acc = __hfma2(hvpk[6],  u2h(q1.z), acc);
        acc = __hfma2(hvpk[7],  u2h(q1.w), acc);
        acc = __hfma2(hvpk[8],  u2h(q2.x), acc);
        acc = __hfma2(hvpk[9],  u2h(q2.y), acc);
        acc = __hfma2(hvpk[10], u2h(q2.z), acc);
        acc = __hfma2(hvpk[11], u2h(q2.w), acc);
        acc = __hfma2(hvpk[12], u2h(q3.x), acc);
        acc = __hfma2(hvpk[13], u2h(q3.y), acc);
        acc = __hfma2(hvpk[14], u2h(q3.z), acc);
        acc = __hfma2(hvpk[15], u2h(q3.w), acc);
        v[o] = tail[o] + __low2float(acc) + __high2float(acc);
    }
}

// ---- node embedding -------------------------------------------------------
__global__ void k_embed1(const float* __restrict__ nf, const float* __restrict__ W1,
                         const float* __restrict__ b1, float* __restrict__ t, int N) {
    int idx = blockIdx.x * blockDim.x + threadIdx.x;
    if (idx >= N * 67) return;
    int n = idx / 67, j = idx - n * 67;
    const float* __restrict__ x = nf + (size_t)n * 67;
    float s = b1[j];
    for (int i = 0; i < 67; ++i) s += x[i] * W1[i * 67 + j];
    t[idx] = (s > 0.f) ? s : expm1f(s);   // ELU(alpha=1)
}

__global__ void k_embed2(const float* __restrict__ t, const float* __restrict__ W2,
                         const float* __restrict__ b2, float* __restrict__ h0, int N) {
    int idx = blockIdx.x * blockDim.x + threadIdx.x;
    if (idx >= N * 16) return;
    int n = idx >> 4, c = idx & 15;
    const float* __restrict__ x = t + (size_t)n * 67;
    float s = b2[c];
    for (int i = 0; i < 67; ++i) s += x[i] * W2[i * 16 + c];
    h0[idx] = s;
}

// ---- counting sorts -------------------------------------------------------
__global__ void k_count2(const int* __restrict__ src, const int* __restrict__ dst,
                         int* __restrict__ cntd, int* __restrict__ cnts,
                         int* __restrict__ posd, int* __restrict__ poss, int E) {
    int e = blockIdx.x * blockDim.x + threadIdx.x;
    if (e >= E) return;
    posd[e] = atomicAdd(cntd + dst[e], 1);
    poss[e] = atomicAdd(cnts + src[e], 1);
}

// grid=2: block 0 scans cntd->rsd, block 1 scans cnts->rss
__global__ __launch_bounds__(1024) void k_scan2(const int* __restrict__ cntd,
                                                int* __restrict__ rsd,
                                                const int* __restrict__ cnts,
                                                int* __restrict__ rss, int N) {
    const int* __restrict__ c = (blockIdx.x == 0) ? cntd : cnts;
    int* __restrict__ rs      = (blockIdx.x == 0) ? rsd  : rss;
    int chunk = (N + 1023) >> 10;
    int lo = (int)threadIdx.x * chunk;
    int sum = 0;
    for (int j = 0; j < chunk; ++j) { int i = lo + j; sum += (i < N) ? c[i] : 0; }
    __shared__ int ps[1024];
    ps[threadIdx.x] = sum;
    __syncthreads();
    for (int off = 1; off < 1024; off <<= 1) {
        int t = (threadIdx.x >= (unsigned)off) ? ps[threadIdx.x - off] : 0;
        __syncthreads();
        ps[threadIdx.x] += t;
        __syncthreads();
    }
    int run = threadIdx.x ? ps[threadIdx.x - 1] : 0;
    if (threadIdx.x == 0) rs[0] = 0;
    for (int j = 0; j < chunk; ++j) {
        int i = lo + j;
        if (i < N) { run += c[i]; rs[i + 1] = run; }
    }
}

// ---- prep: geometry; edgeS (src-sorted), y1d (dst-sorted, f16), s2d map ---
__global__ void k_prep(const float* __restrict__ pos, const float* __restrict__ ew,
                       const int* __restrict__ src, const int* __restrict__ dst,
                       const int* __restrict__ rsd, const int* __restrict__ rss,
                       const int* __restrict__ posd, const int* __restrict__ poss,
                       float4* __restrict__ edgeS, uint2* __restrict__ y1d,
                       int* __restrict__ s2d, int E) {
    int e = blockIdx.x * blockDim.x + threadIdx.x;
    if (e >= E) return;
    int s = src[e], d = dst[e];
    float dx = pos[3 * d]     - pos[3 * s];
    float dy = pos[3 * d + 1] - pos[3 * s + 1];
    float dz = pos[3 * d + 2] - pos[3 * s + 2];
    float r = sqrtf(dx * dx + dy * dy + dz * dz);
    float im = 1.f / fmaxf(r, 1e-8f);
    int ts = rss[s] + poss[e];
    int td = rsd[d] + posd[e];
    s2d[ts] = td;
    edgeS[ts] = make_float4(ew[2 * e], ew[2 * e + 1], r, __int_as_float(s));
    y1d[td] = make_uint2(h2u(__floats2half2_rn(C1C * dy * im, C1C * dz * im)),
                         h2u(__floats2half2_rn(C1C * dx * im, 0.f)));
}

// ---- U precompute: thread=(net,n,o); h in regs; f16 pairs + f32 tail ------
__global__ void k_u(const float* __restrict__ h, const float* __restrict__ W3,
                    const float* __restrict__ b3,
                    unsigned* __restrict__ Um0, float* __restrict__ Ut0,
                    unsigned* __restrict__ Um1, float* __restrict__ Ut1,
                    int N, int nets) {
    int idx = blockIdx.x * blockDim.x + threadIdx.x;
    if (idx >= nets * N * 16) return;
    int net = idx / (N * 16);
    int r = idx - net * (N * 16);
    int n = r >> 4, o = r & 15;
    const float* __restrict__ W3n = W3 + (size_t)net * 8192;
    const float* __restrict__ b3n = b3 + (size_t)net * 256;
    unsigned* __restrict__ Um = net ? Um1 : Um0;
    float*    __restrict__ Ut = net ? Ut1 : Ut0;

    const float4* hp = (const float4*)(h + (size_t)n * 16);
    float4 h0 = hp[0], h1 = hp[1], h2 = hp[2], h3 = hp[3];
    float hn[16] = {h0.x, h0.y, h0.z, h0.w, h1.x, h1.y, h1.z, h1.w,
                    h2.x, h2.y, h2.z, h2.w, h3.x, h3.y, h3.z, h3.w};

    float u[32];
#pragma unroll 4
    for (int k = 0; k < 32; ++k) {
        const float4* w = (const float4*)(W3n + k * 256 + o * 16);
        float4 w0 = w[0], w1 = w[1], w2 = w[2], w3 = w[3];
        float s = hn[0]*w0.x + hn[1]*w0.y + hn[2]*w0.z + hn[3]*w0.w
                + hn[4]*w1.x + hn[5]*w1.y + hn[6]*w1.z + hn[7]*w1.w
                + hn[8]*w2.x + hn[9]*w2.y + hn[10]*w2.z + hn[11]*w2.w
                + hn[12]*w3.x + hn[13]*w3.y + hn[14]*w3.z + hn[15]*w3.w;
        u[k] = s;
    }
    {
        const float4* w = (const float4*)(b3n + o * 16);
        float4 w0 = w[0], w1 = w[1], w2 = w[2], w3 = w[3];
        Ut[n * 16 + o] = hn[0]*w0.x + hn[1]*w0.y + hn[2]*w0.z + hn[3]*w0.w
                       + hn[4]*w1.x + hn[5]*w1.y + hn[6]*w1.z + hn[7]*w1.w
                       + hn[8]*w2.x + hn[9]*w2.y + hn[10]*w2.z + hn[11]*w2.w
                       + hn[12]*w3.x + hn[13]*w3.y + hn[14]*w3.z + hn[15]*w3.w;
    }
    uint4* du = (uint4*)(Um + ((size_t)(n * 16 + o)) * 16);
    du[0] = make_uint4(h2u(__floats2half2_rn(u[0], u[1])),
                       h2u(__floats2half2_rn(u[2], u[3])),
                       h2u(__floats2half2_rn(u[4], u[5])),
                       h2u(__floats2half2_rn(u[6], u[7])));
    du[1] = make_uint4(h2u(__floats2half2_rn(u[8], u[9])),
                       h2u(__floats2half2_rn(u[10], u[11])),
                       h2u(__floats2half2_rn(u[12], u[13])),
                       h2u(__floats2half2_rn(u[14], u[15])));
    du[2] = make_uint4(h2u(__floats2half2_rn(u[16], u[17])),
                       h2u(__floats2half2_rn(u[18], u[19])),
                       h2u(__floats2half2_rn(u[20], u[21])),
                       h2u(__floats2half2_rn(u[22], u[23])));
    du[3] = make_uint4(h2u(__floats2half2_rn(u[24], u[25])),
                       h2u(__floats2half2_rn(u[26], u[27])),
                       h2u(__floats2half2_rn(u[28], u[29])),
                       h2u(__floats2half2_rn(u[30], u[31])));
}

// ---- edge kernels (src-sorted traversal, scatter-write to dst slot) -------
__global__ __launch_bounds__(256) void k_edgeL0(
    const float4* __restrict__ edgeS, const int* __restrict__ s2d, RadialW ra,
    const uint4* __restrict__ UmA, const float* __restrict__ UtA,
    unsigned short* __restrict__ msg /*stride 16*/, int E) {
    int t = blockIdx.x * blockDim.x + threadIdx.x;
    if (t >= E) return;
    float4 a = edgeS[t];
    int sn = __float_as_int(a.w);
    __half2 hv[16];
    float v[16];
    radial_net_pk(a.x, a.y, a.z, ra, hv);
    contract_pk(hv, UmA + (size_t)sn * 64, UtA + (size_t)sn * 16, v);
    int td = s2d[t];
    uint4* m = (uint4*)(msg + (size_t)td * 16);
    m[0] = make_uint4(h2u(__floats2half2_rn(v[0], v[1])),
                      h2u(__floats2half2_rn(v[2], v[3])),
                      h2u(__floats2half2_rn(v[4], v[5])),
                      h2u(__floats2half2_rn(v[6], v[7])));
    m[1] = make_uint4(h2u(__floats2half2_rn(v[8], v[9])),
                      h2u(__floats2half2_rn(v[10], v[11])),
                      h2u(__floats2half2_rn(v[12], v[13])),
                      h2u(__floats2half2_rn(v[14], v[15])));
}

__global__ __launch_bounds__(256) void k_edgeL1(
    const float4* __restrict__ edgeS, const int* __restrict__ s2d,
    RadialW ra, RadialW rb,
    const uint4* __restrict__ UmA, const float* __restrict__ UtA,
    const uint4* __restrict__ UmB, const float* __restrict__ UtB,
    unsigned short* __restrict__ msg /*stride 32*/, int nbE, int E) {
    int half = (blockIdx.x >= (unsigned)nbE) ? 1 : 0;
    int t = (blockIdx.x - half * nbE) * blockDim.x + threadIdx.x;
    if (t >= E) return;
    float4 a = edgeS[t];
    int sn = __float_as_int(a.w);
    RadialW rw = half ? rb : ra;
    const uint4* __restrict__ Um = half ? UmB : UmA;
    const float* __restrict__ Ut = half ? UtB : UtA;
    __half2 hv[16];
    float v[16];
    radial_net_pk(a.x, a.y, a.z, rw, hv);
    contract_pk(hv, Um + (size_t)sn * 64, Ut + (size_t)sn * 16, v);
    int td = s2d[t];
    uint4* m = (uint4*)(msg + (size_t)td * 32 + half * 16);
    m[0] = make_uint4(h2u(__floats2half2_rn(v[0], v[1])),
                      h2u(__floats2half2_rn(v[2], v[3])),
                      h2u(__floats2half2_rn(v[4], v[5])),
                      h2u(__floats2half2_rn(v[6], v[7])));
    m[1] = make_uint4(h2u(__floats2half2_rn(v[8], v[9])),
                      h2u(__floats2half2_rn(v[10], v[11])),
                      h2u(__floats2half2_rn(v[12], v[13])),
                      h2u(__floats2half2_rn(v[14], v[15])));
}

// ---- segment reduces (contiguous, dst-sorted) -----------------------------
__global__ void k_reduce0(const unsigned short* __restrict__ msg,
                          const int* __restrict__ rowstart,
                          const float* __restrict__ h, const float* __restrict__ Wself,
                          float* __restrict__ out, int N) {
    int idx = blockIdx.x * blockDim.x + threadIdx.x;
    if (idx >= N * 16) return;
    int n = idx >> 4, o = idx & 15;
    int s = rowstart[n], t1 = rowstart[n + 1];
    float acc = 0.f;
    for (int t = s; t < t1; ++t) acc += hbits2f(msg[(size_t)t * 16 + o]);
    int d = t1 - s;
    float invd = (d > 0) ? 1.f / (float)d : 0.f;
    float hi   = (d > 0) ? 1.f : 0.f;
    const float* __restrict__ hn = h + (size_t)n * 16;
    const float* __restrict__ w  = Wself + o * 16;
    float self = 0.f;
#pragma unroll
    for (int c = 0; c < 16; ++c) self += hn[c] * w[c];
    out[idx] = Y0C * acc * invd + hi * self;
}

__global__ void k_reduce1(const unsigned short* __restrict__ msg,  // stride 32
                          const uint2* __restrict__ y1d,
                          const int* __restrict__ rowstart,
                          const float* __restrict__ h, const float* __restrict__ Wself,
                          float* __restrict__ out0, float* __restrict__ out1, int N) {
    int idx = blockIdx.x * blockDim.x + threadIdx.x;
    if (idx >= N * 16) return;
    int n = idx >> 4, o = idx & 15;
    int s = rowstart[n], t1 = rowstart[n + 1];
    float a0 = 0.f, ax = 0.f, ay = 0.f, az = 0.f;
    for (int t = s; t < t1; ++t) {
        const unsigned short* row = msg + (size_t)t * 32;
        a0 += hbits2f(row[o]);
        float b = hbits2f(row[16 + o]);
        uint2 yv = y1d[t];
        ax += b * hbits2f((unsigned short)yv.x);
        ay += b * hbits2f((unsigned short)(yv.x >> 16));
        az += b * hbits2f((unsigned short)yv.y);
    }
    int d = t1 - s;
    float invd = (d > 0) ? 1.f / (float)d : 0.f;
    float hi   = (d > 0) ? 1.f : 0.f;
    const float* __restrict__ hn = h + (size_t)n * 16;
    const float* __restrict__ w  = Wself + o * 16;
    float self = 0.f;
#pragma unroll
    for (int c = 0; c < 16; ++c) self += hn[c] * w[c];
    out0[idx] = Y0C * a0 * invd + hi * self;
    out1[(size_t)idx * 3]     = ax * invd;
    out1[(size_t)idx * 3 + 1] = ay * invd;
    out1[(size_t)idx * 3 + 2] = az * invd;
}

// ---------------------------------------------------------------------------
extern "C" void kernel_launch(void* const* d_in, const int* in_sizes, int n_in,
                              void* d_out, int out_size, void* d_ws, size_t ws_size,
                              hipStream_t stream) {
    (void)n_in; (void)out_size; (void)ws_size;
    const float* node_feats = (const float*)d_in[0];
    const float* pos    = (const float*)d_in[1];
    const float* edge_w = (const float*)d_in[2];
    const float* lin1_W = (const float*)d_in[3];
    const float* lin1_b = (const float*)d_in[4];
    const float* lin2_W = (const float*)d_in[5];
    const float* lin2_b = (const float*)d_in[6];
    const float* rW1    = (const float*)d_in[7];
    const float* rb1    = (const float*)d_in[8];
    const float* ln1_g  = (const float*)d_in[9];
    const float* ln1_b  = (const float*)d_in[10];
    const float* rW2    = (const float*)d_in[11];
    const float* rb2    = (const float*)d_in[12];
    const float* ln2_g  = (const float*)d_in[13];
    const float* ln2_b  = (const float*)d_in[14];
    const float* rW3    = (const float*)d_in[15];
    const float* rb3    = (const float*)d_in[16];
    const float* Wself  = (const float*)d_in[17];
    const int*   src    = (const int*)d_in[18];
    const int*   dst    = (const int*)d_in[19];

    const int N = in_sizes[1] / 3;     // pos is [N,3]
    const int E = in_sizes[18];        // src is [E]

    char* ws = (char*)d_ws;
    size_t off = 0;
    auto carve = [&](size_t bytes) -> char* {
        char* p = ws + off;
        off = (off + bytes + 255) & ~(size_t)255;
        return p;
    };
    float* h0   = (float*)carve((size_t)N * 16 * 4);
    float* h1   = (float*)carve((size_t)N * 16 * 4);
    int*   cntd = (int*)carve((size_t)N * 4);
    int*   cnts = (int*)carve((size_t)N * 4);
    int*   rsd  = (int*)carve((size_t)(N + 1) * 4);
    int*   rss  = (int*)carve((size_t)(N + 1) * 4);
    int*   s2d  = (int*)carve((size_t)E * 4);
    float4* edgeS = (float4*)carve((size_t)E * 16);
    uint2*  y1d   = (uint2*)carve((size_t)E * 8);
    unsigned* UaM = (unsigned*)carve((size_t)N * 16 * 64);
    float*    UaT = (float*)carve((size_t)N * 16 * 4);
    unsigned* UbM = (unsigned*)carve((size_t)N * 16 * 64);
    float*    UbT = (float*)carve((size_t)N * 16 * 4);
    unsigned short* msg = (unsigned short*)carve((size_t)E * 32 * 2);
    // disjoint-lifetime overlays inside msg (dead before edge kernels run):
    float* tmb  = (float*)msg;                           // [N,67] embed temp
    int*   posd = (int*)((char*)msg + (8u << 20));       // [E]
    int*   poss = (int*)((char*)msg + (14u << 20));      // [E]

    auto nb = [](int n) { return (n + 255) / 256; };
    const int nbE = nb(E);

    hipMemsetAsync(cntd, 0, (size_t)N * 4, stream);
    hipMemsetAsync(cnts, 0, (size_t)N * 4, stream);

    k_embed1<<<nb(N * 67), 256, 0, stream>>>(node_feats, lin1_W, lin1_b, tmb, N);
    k_embed2<<<nb(N * 16), 256, 0, stream>>>(tmb, lin2_W, lin2_b, h0, N);

    k_count2<<<nbE, 256, 0, stream>>>(src, dst, cntd, cnts, posd, poss, E);
    k_scan2<<<2, 1024, 0, stream>>>(cntd, rsd, cnts, rss, N);
    k_prep<<<nbE, 256, 0, stream>>>(pos, edge_w, src, dst, rsd, rss, posd, poss,
                                    edgeS, y1d, s2d, E);

    auto rnet = [&](int net) -> RadialW {
        RadialW r;
        r.W1 = rW1 + net * 96;   r.b1 = rb1 + net * 32;
        r.g1 = ln1_g + net * 32; r.gb1 = ln1_b + net * 32;
        r.W2 = rW2 + net * 1024; r.b2 = rb2 + net * 32;
        r.g2 = ln2_g + net * 32; r.gb2 = ln2_b + net * 32;
        return r;
    };

    // ---- layer 0 (degree-1 branch dead: only net 0) ----
    k_u<<<nb(N * 16), 256, 0, stream>>>(h0, rW3, rb3, UaM, UaT, UbM, UbT, N, 1);
    k_edgeL0<<<nbE, 256, 0, stream>>>(edgeS, s2d, rnet(0), (const uint4*)UaM, UaT,
                                      msg, E);
    k_reduce0<<<nb(N * 16), 256, 0, stream>>>(msg, rsd, h0, Wself, h1, N);

    // ---- layer 1 (nets 2,3) ----
    k_u<<<nb(2 * N * 16), 256, 0, stream>>>(h1, rW3 + 2 * 8192, rb3 + 2 * 256,
                                            UaM, UaT, UbM, UbT, N, 2);
    k_edgeL1<<<2 * nbE, 256, 0, stream>>>(edgeS, s2d, rnet(2), rnet(3),
                                          (const uint4*)UaM, UaT,
                                          (const uint4*)UbM, UbT, msg, nbE, E);
    float* out0 = (float*)d_out;
    float* out1 = (float*)d_out + (size_t)N * 16;
    k_reduce1<<<nb(N * 16), 256, 0, stream>>>(msg, y1d, rsd, h1, Wself + 256,
                                              out0, out1, N);
}

// Round 5
// 399.946 us; speedup vs baseline: 4.4046x; 1.1803x over previous
//
#include <hip/hip_runtime.h>
#include <hip/hip_fp16.h>

// ---------------------------------------------------------------------------
// SE3Transformer block. Round 5:
//   - k_u rebuilt: W3 pre-packed (k-pair half2) into Wp[i][o][kp] stride-18
//     (conflict-free ds_read_b64), LDS-staged once per block (18 KB),
//     2 nodes/thread -> weight reads amortized; pk_fma accumulation.
//     (R4's k_u re-read 2 KB of W3 per thread -> 133 us latency-bound)
//   - everything else unchanged from R4 (dual counting sort, f16-pk edge
//     kernels split per (edge,net), dst-sorted msg scatter, fused reduces)
// ---------------------------------------------------------------------------

#define Y0C 0.28209479177387814f
#define C1C 0.4886025119029199f

static __device__ __forceinline__ unsigned h2u(__half2 h) {
    union { __half2 h; unsigned u; } x; x.h = h; return x.u;
}
static __device__ __forceinline__ __half2 u2h(unsigned u) {
    union { unsigned u; __half2 h; } x; x.u = u; return x.h;
}
static __device__ __forceinline__ float hbits2f(unsigned short s) {
    __half_raw r; r.x = s; return __half2float((__half)r);
}

struct RadialW { const float *W1, *b1, *g1, *gb1, *W2, *b2, *g2, *gb2; };

// radial MLP (f32): (x0,x1,x2) -> 32 (LN,relu) -> 32 (LN,relu) -> f16 k-pairs
__device__ __forceinline__ void radial_net_pk(float x0, float x1, float x2,
                                              RadialW rw, __half2* hvpk /*[16]*/) {
    float h[32];
#pragma unroll
    for (int j = 0; j < 32; ++j)
        h[j] = rw.b1[j] + x0 * rw.W1[j] + x1 * rw.W1[32 + j] + x2 * rw.W1[64 + j];
    float mu = 0.f;
#pragma unroll
    for (int j = 0; j < 32; ++j) mu += h[j];
    mu *= 0.03125f;
    float var = 0.f;
#pragma unroll
    for (int j = 0; j < 32; ++j) { float d = h[j] - mu; var += d * d; }
    var *= 0.03125f;
    float rs = rsqrtf(var + 1e-5f);
#pragma unroll
    for (int j = 0; j < 32; ++j)
        h[j] = fmaxf((h[j] - mu) * rs * rw.g1[j] + rw.gb1[j], 0.f);

    float h2[32];
#pragma unroll
    for (int j = 0; j < 32; ++j) h2[j] = rw.b2[j];
#pragma unroll
    for (int k = 0; k < 32; ++k) {
        float hk = h[k];
        const float* __restrict__ w = rw.W2 + k * 32;   // uniform -> s_load
#pragma unroll
        for (int j = 0; j < 32; ++j) h2[j] += hk * w[j];
    }
    mu = 0.f;
#pragma unroll
    for (int j = 0; j < 32; ++j) mu += h2[j];
    mu *= 0.03125f;
    var = 0.f;
#pragma unroll
    for (int j = 0; j < 32; ++j) { float d = h2[j] - mu; var += d * d; }
    var *= 0.03125f;
    rs = rsqrtf(var + 1e-5f);
    float y[32];
#pragma unroll
    for (int j = 0; j < 32; ++j)
        y[j] = fmaxf((h2[j] - mu) * rs * rw.g2[j] + rw.gb2[j], 0.f);
#pragma unroll
    for (int p = 0; p < 16; ++p)
        hvpk[p] = __floats2half2_rn(y[2 * p], y[2 * p + 1]);
}

// v[o] = tail[o] + sum_p hvpk[p] .* Um[o][p]   (f16 packed FMA, f32 finish)
__device__ __forceinline__ void contract_pk(const __half2* hvpk,
                                            const uint4* __restrict__ Um,
                                            const float* __restrict__ Ut,
                                            float* v /*[16]*/) {
    float4 t0 = ((const float4*)Ut)[0];
    float4 t1 = ((const float4*)Ut)[1];
    float4 t2 = ((const float4*)Ut)[2];
    float4 t3 = ((const float4*)Ut)[3];
    float tail[16] = {t0.x, t0.y, t0.z, t0.w, t1.x, t1.y, t1.z, t1.w,
                      t2.x, t2.y, t2.z, t2.w, t3.x, t3.y, t3.z, t3.w};
#pragma unroll
    for (int o = 0; o < 16; ++o) {
        uint4 q0 = Um[o * 4];
        uint4 q1 = Um[o * 4 + 1];
        uint4 q2 = Um[o * 4 + 2];
        uint4 q3 = Um[o * 4 + 3];
        __half2 acc = __hmul2(hvpk[0], u2h(q0.x));
        acc = __hfma2(hvpk[1],  u2h(q0.y), acc);
        acc = __hfma2(hvpk[2],  u2h(q0.z), acc);
        acc = __hfma2(hvpk[3],  u2h(q0.w), acc);
        acc = __hfma2(hvpk[4],  u2h(q1.x), acc);
        acc = __hfma2(hvpk[5],  u2h(q1.y), acc);
        acc = __hfma2(hvpk[6],  u2h(q1.z), acc);
        acc = __hfma2(hvpk[7],  u2h(q1.w), acc);
        acc = __hfma2(hvpk[8],  u2h(q2.x), acc);
        acc = __hfma2(hvpk[9],  u2h(q2.y), acc);
        acc = __hfma2(hvpk[10], u2h(q2.z), acc);
        acc = __hfma2(hvpk[11], u2h(q2.w), acc);
        acc = __hfma2(hvpk[12], u2h(q3.x), acc);
        acc = __hfma2(hvpk[13], u2h(q3.y), acc);
        acc = __hfma2(hvpk[14], u2h(q3.z), acc);
        acc = __hfma2(hvpk[15], u2h(q3.w), acc);
        v[o] = tail[o] + __low2float(acc) + __high2float(acc);
    }
}

// ---- node embedding -------------------------------------------------------
__global__ void k_embed1(const float* __restrict__ nf, const float* __restrict__ W1,
                         const float* __restrict__ b1, float* __restrict__ t, int N) {
    int idx = blockIdx.x * blockDim.x + threadIdx.x;
    if (idx >= N * 67) return;
    int n = idx / 67, j = idx - n * 67;
    const float* __restrict__ x = nf + (size_t)n * 67;
    float s = b1[j];
    for (int i = 0; i < 67; ++i) s += x[i] * W1[i * 67 + j];
    t[idx] = (s > 0.f) ? s : expm1f(s);   // ELU(alpha=1)
}

__global__ void k_embed2(const float* __restrict__ t, const float* __restrict__ W2,
                         const float* __restrict__ b2, float* __restrict__ h0, int N) {
    int idx = blockIdx.x * blockDim.x + threadIdx.x;
    if (idx >= N * 16) return;
    int n = idx >> 4, c = idx & 15;
    const float* __restrict__ x = t + (size_t)n * 67;
    float s = b2[c];
    for (int i = 0; i < 67; ++i) s += x[i] * W2[i * 16 + c];
    h0[idx] = s;
}

// ---- counting sorts -------------------------------------------------------
__global__ void k_count2(const int* __restrict__ src, const int* __restrict__ dst,
                         int* __restrict__ cntd, int* __restrict__ cnts,
                         int* __restrict__ posd, int* __restrict__ poss, int E) {
    int e = blockIdx.x * blockDim.x + threadIdx.x;
    if (e >= E) return;
    posd[e] = atomicAdd(cntd + dst[e], 1);
    poss[e] = atomicAdd(cnts + src[e], 1);
}

// grid=2: block 0 scans cntd->rsd, block 1 scans cnts->rss
__global__ __launch_bounds__(1024) void k_scan2(const int* __restrict__ cntd,
                                                int* __restrict__ rsd,
                                                const int* __restrict__ cnts,
                                                int* __restrict__ rss, int N) {
    const int* __restrict__ c = (blockIdx.x == 0) ? cntd : cnts;
    int* __restrict__ rs      = (blockIdx.x == 0) ? rsd  : rss;
    int chunk = (N + 1023) >> 10;
    int lo = (int)threadIdx.x * chunk;
    int sum = 0;
    for (int j = 0; j < chunk; ++j) { int i = lo + j; sum += (i < N) ? c[i] : 0; }
    __shared__ int ps[1024];
    ps[threadIdx.x] = sum;
    __syncthreads();
    for (int off = 1; off < 1024; off <<= 1) {
        int t = (threadIdx.x >= (unsigned)off) ? ps[threadIdx.x - off] : 0;
        __syncthreads();
        ps[threadIdx.x] += t;
        __syncthreads();
    }
    int run = threadIdx.x ? ps[threadIdx.x - 1] : 0;
    if (threadIdx.x == 0) rs[0] = 0;
    for (int j = 0; j < chunk; ++j) {
        int i = lo + j;
        if (i < N) { run += c[i]; rs[i + 1] = run; }
    }
}

// ---- prep: geometry; edgeS (src-sorted), y1d (dst-sorted, f16), s2d map ---
__global__ void k_prep(const float* __restrict__ pos, const float* __restrict__ ew,
                       const int* __restrict__ src, const int* __restrict__ dst,
                       const int* __restrict__ rsd, const int* __restrict__ rss,
                       const int* __restrict__ posd, const int* __restrict__ poss,
                       float4* __restrict__ edgeS, uint2* __restrict__ y1d,
                       int* __restrict__ s2d, int E) {
    int e = blockIdx.x * blockDim.x + threadIdx.x;
    if (e >= E) return;
    int s = src[e], d = dst[e];
    float dx = pos[3 * d]     - pos[3 * s];
    float dy = pos[3 * d + 1] - pos[3 * s + 1];
    float dz = pos[3 * d + 2] - pos[3 * s + 2];
    float r = sqrtf(dx * dx + dy * dy + dz * dz);
    float im = 1.f / fmaxf(r, 1e-8f);
    int ts = rss[s] + poss[e];
    int td = rsd[d] + posd[e];
    s2d[ts] = td;
    edgeS[ts] = make_float4(ew[2 * e], ew[2 * e + 1], r, __int_as_float(s));
    y1d[td] = make_uint2(h2u(__floats2half2_rn(C1C * dy * im, C1C * dz * im)),
                         h2u(__floats2half2_rn(C1C * dx * im, 0.f)));
}

// ---- W3 pre-pack: Wp[ni][(i*16+o)*18 + kp] = half2(W3[2kp,o16+i], W3[2kp+1,o16+i])
// ni 0,1,2 -> nets 0,2,3. Stride 18 -> conflict-free ds_read_b64 in k_u2.
__global__ void k_w3pack(const float* __restrict__ rW3, unsigned* __restrict__ Wp) {
    int t = blockIdx.x * blockDim.x + threadIdx.x;
    if (t >= 3 * 256) return;
    int ni = t >> 8;
    int net = (ni == 0) ? 0 : ni + 1;
    int r = t & 255;
    int i = r >> 4, o = r & 15;
    const float* __restrict__ W3n = rW3 + (size_t)net * 8192;
    unsigned* __restrict__ dp = Wp + (size_t)ni * 4608 + (size_t)(i * 16 + o) * 18;
#pragma unroll
    for (int kp = 0; kp < 16; ++kp) {
        float a = W3n[(2 * kp) * 256 + o * 16 + i];
        float b = W3n[(2 * kp + 1) * 256 + o * 16 + i];
        dp[kp] = h2u(__floats2half2_rn(a, b));
    }
}

// ---- U precompute v2: LDS-staged packed weights, 2 nodes/thread -----------
// block = 256 threads = 16 node-pairs x 16 o; 32 nodes/block.
// Um[(n*16+o)*16 + kp] = half2(U[n,2kp,o], U[n,2kp+1,o]); Ut[n*16+o] f32 tail.
__global__ __launch_bounds__(256) void k_u2(
    const float* __restrict__ h, const unsigned* __restrict__ Wp,
    const float* __restrict__ b3A, const float* __restrict__ b3B,
    unsigned* __restrict__ Um0, float* __restrict__ Ut0,
    unsigned* __restrict__ Um1, float* __restrict__ Ut1,
    int wpA, int nbPerNet, int N) {
    __shared__ unsigned WL[4608];
    int netSel = blockIdx.x / nbPerNet;
    int nbase = (blockIdx.x - netSel * nbPerNet) * 32;
    const unsigned* __restrict__ g = Wp + (size_t)(wpA + netSel) * 4608;
    for (int j = threadIdx.x; j < 4608; j += 256) WL[j] = g[j];
    __syncthreads();

    const float* __restrict__ b3 = netSel ? b3B : b3A;
    unsigned* __restrict__ Um = netSel ? Um1 : Um0;
    float*    __restrict__ Ut = netSel ? Ut1 : Ut0;

    int o = threadIdx.x & 15;
    int pr = threadIdx.x >> 4;
    int n0 = nbase + pr * 2;
    int n1 = n0 + 1;
    bool ok0 = n0 < N, ok1 = n1 < N;
    int m0 = ok0 ? n0 : 0, m1 = ok1 ? n1 : 0;

    // load h rows; compute f32 tail immediately; pack to broadcast-half2
    const float* __restrict__ bo = b3 + o * 16;
    float tA = 0.f, tB = 0.f;
    __half2 hhA[16], hhB[16];
    {
        const float4* hp = (const float4*)(h + (size_t)m0 * 16);
#pragma unroll
        for (int q = 0; q < 4; ++q) {
            float4 hv = hp[q];
            tA += hv.x * bo[4 * q] + hv.y * bo[4 * q + 1]
                + hv.z * bo[4 * q + 2] + hv.w * bo[4 * q + 3];
            hhA[4 * q]     = __floats2half2_rn(hv.x, hv.x);
            hhA[4 * q + 1] = __floats2half2_rn(hv.y, hv.y);
            hhA[4 * q + 2] = __floats2half2_rn(hv.z, hv.z);
            hhA[4 * q + 3] = __floats2half2_rn(hv.w, hv.w);
        }
    }
    {
        const float4* hp = (const float4*)(h + (size_t)m1 * 16);
#pragma unroll
        for (int q = 0; q < 4; ++q) {
            float4 hv = hp[q];
            tB += hv.x * bo[4 * q] + hv.y * bo[4 * q + 1]
                + hv.z * bo[4 * q + 2] + hv.w * bo[4 * q + 3];
            hhB[4 * q]     = __floats2half2_rn(hv.x, hv.x);
            hhB[4 * q + 1] = __floats2half2_rn(hv.y, hv.y);
            hhB[4 * q + 2] = __floats2half2_rn(hv.z, hv.z);
            hhB[4 * q + 3] = __floats2half2_rn(hv.w, hv.w);
        }
    }

    __half2 accA[16], accB[16];
#pragma unroll
    for (int p = 0; p < 16; ++p) {
        accA[p] = __floats2half2_rn(0.f, 0.f);
        accB[p] = __floats2half2_rn(0.f, 0.f);
    }

#pragma unroll
    for (int i = 0; i < 16; ++i) {
        const uint2* __restrict__ row = (const uint2*)(WL + i * 288 + o * 18);
        __half2 ha = hhA[i], hb = hhB[i];
#pragma unroll
        for (int q = 0; q < 8; ++q) {
            uint2 w = row[q];
            accA[2 * q]     = __hfma2(ha, u2h(w.x), accA[2 * q]);
            accA[2 * q + 1] = __hfma2(ha, u2h(w.y), accA[2 * q + 1]);
            accB[2 * q]     = __hfma2(hb, u2h(w.x), accB[2 * q]);
            accB[2 * q + 1] = __hfma2(hb, u2h(w.y), accB[2 * q + 1]);
        }
    }

    if (ok0) {
        uint4* du = (uint4*)(Um + ((size_t)(n0 * 16 + o)) * 16);
#pragma unroll
        for (int q = 0; q < 4; ++q)
            du[q] = make_uint4(h2u(accA[4 * q]), h2u(accA[4 * q + 1]),
                               h2u(accA[4 * q + 2]), h2u(accA[4 * q + 3]));
        Ut[n0 * 16 + o] = tA;
    }
    if (ok1) {
        uint4* du = (uint4*)(Um + ((size_t)(n1 * 16 + o)) * 16);
#pragma unroll
        for (int q = 0; q < 4; ++q)
            du[q] = make_uint4(h2u(accB[4 * q]), h2u(accB[4 * q + 1]),
                               h2u(accB[4 * q + 2]), h2u(accB[4 * q + 3]));
        Ut[n1 * 16 + o] = tB;
    }
}

// ---- edge kernels (src-sorted traversal, scatter-write to dst slot) -------
__global__ __launch_bounds__(256) void k_edgeL0(
    const float4* __restrict__ edgeS, const int* __restrict__ s2d, RadialW ra,
    const uint4* __restrict__ UmA, const float* __restrict__ UtA,
    unsigned short* __restrict__ msg /*stride 16*/, int E) {
    int t = blockIdx.x * blockDim.x + threadIdx.x;
    if (t >= E) return;
    float4 a = edgeS[t];
    int sn = __float_as_int(a.w);
    __half2 hv[16];
    float v[16];
    radial_net_pk(a.x, a.y, a.z, ra, hv);
    contract_pk(hv, UmA + (size_t)sn * 64, UtA + (size_t)sn * 16, v);
    int td = s2d[t];
    uint4* m = (uint4*)(msg + (size_t)td * 16);
    m[0] = make_uint4(h2u(__floats2half2_rn(v[0], v[1])),
                      h2u(__floats2half2_rn(v[2], v[3])),
                      h2u(__floats2half2_rn(v[4], v[5])),
                      h2u(__floats2half2_rn(v[6], v[7])));
    m[1] = make_uint4(h2u(__floats2half2_rn(v[8], v[9])),
                      h2u(__floats2half2_rn(v[10], v[11])),
                      h2u(__floats2half2_rn(v[12], v[13])),
                      h2u(__floats2half2_rn(v[14], v[15])));
}

__global__ __launch_bounds__(256) void k_edgeL1(
    const float4* __restrict__ edgeS, const int* __restrict__ s2d,
    RadialW ra, RadialW rb,
    const uint4* __restrict__ UmA, const float* __restrict__ UtA,
    const uint4* __restrict__ UmB, const float* __restrict__ UtB,
    unsigned short* __restrict__ msg /*stride 32*/, int nbE, int E) {
    int half = (blockIdx.x >= (unsigned)nbE) ? 1 : 0;
    int t = (blockIdx.x - half * nbE) * blockDim.x + threadIdx.x;
    if (t >= E) return;
    float4 a = edgeS[t];
    int sn = __float_as_int(a.w);
    RadialW rw = half ? rb : ra;
    const uint4* __restrict__ Um = half ? UmB : UmA;
    const float* __restrict__ Ut = half ? UtB : UtA;
    __half2 hv[16];
    float v[16];
    radial_net_pk(a.x, a.y, a.z, rw, hv);
    contract_pk(hv, Um + (size_t)sn * 64, Ut + (size_t)sn * 16, v);
    int td = s2d[t];
    uint4* m = (uint4*)(msg + (size_t)td * 32 + half * 16);
    m[0] = make_uint4(h2u(__floats2half2_rn(v[0], v[1])),
                      h2u(__floats2half2_rn(v[2], v[3])),
                      h2u(__floats2half2_rn(v[4], v[5])),
                      h2u(__floats2half2_rn(v[6], v[7])));
    m[1] = make_uint4(h2u(__floats2half2_rn(v[8], v[9])),
                      h2u(__floats2half2_rn(v[10], v[11])),
                      h2u(__floats2half2_rn(v[12], v[13])),
                      h2u(__floats2half2_rn(v[14], v[15])));
}

// ---- segment reduces (contiguous, dst-sorted) -----------------------------
__global__ void k_reduce0(const unsigned short* __restrict__ msg,
                          const int* __restrict__ rowstart,
                          const float* __restrict__ h, const float* __restrict__ Wself,
                          float* __restrict__ out, int N) {
    int idx = blockIdx.x * blockDim.x + threadIdx.x;
    if (idx >= N * 16) return;
    int n = idx >> 4, o = idx & 15;
    int s = rowstart[n], t1 = rowstart[n + 1];
    float acc = 0.f;
    for (int t = s; t < t1; ++t) acc += hbits2f(msg[(size_t)t * 16 + o]);
    int d = t1 - s;
    float invd = (d > 0) ? 1.f / (float)d : 0.f;
    float hi   = (d > 0) ? 1.f : 0.f;
    const float* __restrict__ hn = h + (size_t)n * 16;
    const float* __restrict__ w  = Wself + o * 16;
    float self = 0.f;
#pragma unroll
    for (int c = 0; c < 16; ++c) self += hn[c] * w[c];
    out[idx] = Y0C * acc * invd + hi * self;
}

__global__ void k_reduce1(const unsigned short* __restrict__ msg,  // stride 32
                          const uint2* __restrict__ y1d,
                          const int* __restrict__ rowstart,
                          const float* __restrict__ h, const float* __restrict__ Wself,
                          float* __restrict__ out0, float* __restrict__ out1, int N) {
    int idx = blockIdx.x * blockDim.x + threadIdx.x;
    if (idx >= N * 16) return;
    int n = idx >> 4, o = idx & 15;
    int s = rowstart[n], t1 = rowstart[n + 1];
    float a0 = 0.f, ax = 0.f, ay = 0.f, az = 0.f;
    for (int t = s; t < t1; ++t) {
        const unsigned short* row = msg + (size_t)t * 32;
        a0 += hbits2f(row[o]);
        float b = hbits2f(row[16 + o]);
        uint2 yv = y1d[t];
        ax += b * hbits2f((unsigned short)yv.x);
        ay += b * hbits2f((unsigned short)(yv.x >> 16));
        az += b * hbits2f((unsigned short)yv.y);
    }
    int d = t1 - s;
    float invd = (d > 0) ? 1.f / (float)d : 0.f;
    float hi   = (d > 0) ? 1.f : 0.f;
    const float* __restrict__ hn = h + (size_t)n * 16;
    const float* __restrict__ w  = Wself + o * 16;
    float self = 0.f;
#pragma unroll
    for (int c = 0; c < 16; ++c) self += hn[c] * w[c];
    out0[idx] = Y0C * a0 * invd + hi * self;
    out1[(size_t)idx * 3]     = ax * invd;
    out1[(size_t)idx * 3 + 1] = ay * invd;
    out1[(size_t)idx * 3 + 2] = az * invd;
}

// ---------------------------------------------------------------------------
extern "C" void kernel_launch(void* const* d_in, const int* in_sizes, int n_in,
                              void* d_out, int out_size, void* d_ws, size_t ws_size,
                              hipStream_t stream) {
    (void)n_in; (void)out_size; (void)ws_size;
    const float* node_feats = (const float*)d_in[0];
    const float* pos    = (const float*)d_in[1];
    const float* edge_w = (const float*)d_in[2];
    const float* lin1_W = (const float*)d_in[3];
    const float* lin1_b = (const float*)d_in[4];
    const float* lin2_W = (const float*)d_in[5];
    const float* lin2_b = (const float*)d_in[6];
    const float* rW1    = (const float*)d_in[7];
    const float* rb1    = (const float*)d_in[8];
    const float* ln1_g  = (const float*)d_in[9];
    const float* ln1_b  = (const float*)d_in[10];
    const float* rW2    = (const float*)d_in[11];
    const float* rb2    = (const float*)d_in[12];
    const float* ln2_g  = (const float*)d_in[13];
    const float* ln2_b  = (const float*)d_in[14];
    const float* rW3    = (const float*)d_in[15];
    const float* rb3    = (const float*)d_in[16];
    const float* Wself  = (const float*)d_in[17];
    const int*   src    = (const int*)d_in[18];
    const int*   dst    = (const int*)d_in[19];

    const int N = in_sizes[1] / 3;     // pos is [N,3]
    const int E = in_sizes[18];        // src is [E]

    char* ws = (char*)d_ws;
    size_t off = 0;
    auto carve = [&](size_t bytes) -> char* {
        char* p = ws + off;
        off = (off + bytes + 255) & ~(size_t)255;
        return p;
    };
    float* h0   = (float*)carve((size_t)N * 16 * 4);
    float* h1   = (float*)carve((size_t)N * 16 * 4);
    int*   cntd = (int*)carve((size_t)N * 4);
    int*   cnts = (int*)carve((size_t)N * 4);
    int*   rsd  = (int*)carve((size_t)(N + 1) * 4);
    int*   rss  = (int*)carve((size_t)(N + 1) * 4);
    int*   s2d  = (int*)carve((size_t)E * 4);
    float4* edgeS = (float4*)carve((size_t)E * 16);
    uint2*  y1d   = (uint2*)carve((size_t)E * 8);
    unsigned* UaM = (unsigned*)carve((size_t)N * 16 * 64);
    float*    UaT = (float*)carve((size_t)N * 16 * 4);
    unsigned* UbM = (unsigned*)carve((size_t)N * 16 * 64);
    float*    UbT = (float*)carve((size_t)N * 16 * 4);
    unsigned* Wp  = (unsigned*)carve((size_t)3 * 4608 * 4);
    unsigned short* msg = (unsigned short*)carve((size_t)E * 32 * 2);
    // disjoint-lifetime overlays inside msg (dead before edge kernels run):
    float* tmb  = (float*)msg;                           // [N,67] embed temp
    int*   posd = (int*)((char*)msg + (8u << 20));       // [E]
    int*   poss = (int*)((char*)msg + (14u << 20));      // [E]

    auto nb = [](int n) { return (n + 255) / 256; };
    const int nbE = nb(E);
    const int nbU = (N + 31) / 32;

    hipMemsetAsync(cntd, 0, (size_t)N * 4, stream);
    hipMemsetAsync(cnts, 0, (size_t)N * 4, stream);

    k_w3pack<<<3, 256, 0, stream>>>(rW3, Wp);
    k_embed1<<<nb(N * 67), 256, 0, stream>>>(node_feats, lin1_W, lin1_b, tmb, N);
    k_embed2<<<nb(N * 16), 256, 0, stream>>>(tmb, lin2_W, lin2_b, h0, N);

    k_count2<<<nbE, 256, 0, stream>>>(src, dst, cntd, cnts, posd, poss, E);
    k_scan2<<<2, 1024, 0, stream>>>(cntd, rsd, cnts, rss, N);
    k_prep<<<nbE, 256, 0, stream>>>(pos, edge_w, src, dst, rsd, rss, posd, poss,
                                    edgeS, y1d, s2d, E);

    auto rnet = [&](int net) -> RadialW {
        RadialW r;
        r.W1 = rW1 + net * 96;   r.b1 = rb1 + net * 32;
        r.g1 = ln1_g + net * 32; r.gb1 = ln1_b + net * 32;
        r.W2 = rW2 + net * 1024; r.b2 = rb2 + net * 32;
        r.g2 = ln2_g + net * 32; r.gb2 = ln2_b + net * 32;
        return r;
    };

    // ---- layer 0 (degree-1 branch dead: only net 0) ----
    k_u2<<<nbU, 256, 0, stream>>>(h0, Wp, rb3, rb3, UaM, UaT, UbM, UbT,
                                  /*wpA=*/0, nbU, N);
    k_edgeL0<<<nbE, 256, 0, stream>>>(edgeS, s2d, rnet(0), (const uint4*)UaM, UaT,
                                      msg, E);
    k_reduce0<<<nb(N * 16), 256, 0, stream>>>(msg, rsd, h0, Wself, h1, N);

    // ---- layer 1 (nets 2,3) ----
    k_u2<<<2 * nbU, 256, 0, stream>>>(h1, Wp, rb3 + 2 * 256, rb3 + 3 * 256,
                                      UaM, UaT, UbM, UbT, /*wpA=*/1, nbU, N);
    k_edgeL1<<<2 * nbE, 256, 0, stream>>>(edgeS, s2d, rnet(2), rnet(3),
                                          (const uint4*)UaM, UaT,
                                          (const uint4*)UbM, UbT, msg, nbE, E);
    float* out0 = (float*)d_out;
    float* out1 = (float*)d_out + (size_t)N * 16;
    k_reduce1<<<nb(N * 16), 256, 0, stream>>>(msg, y1d, rsd, h1, Wself + 256,
                                              out0, out1, N);
}

// Round 6
// 360.674 us; speedup vs baseline: 4.8841x; 1.1089x over previous
//
#include <hip/hip_runtime.h>
#include <hip/hip_fp16.h>

// ---------------------------------------------------------------------------
// SE3Transformer block. Round 6:
//   - layer-2 radial GEMM via v_dot2_f32_f16 (fdot2): W2 pre-packed as
//     k-pair half2 [j][kp]; 512 fdot2 (f32 acc) replaces 1024 v_fma_f32
//   - contraction switched to fdot2 (f32 accumulate; same inst count,
//     better precision than f16 pk_fma accumulate)
//   - single fused memset for both count arrays
// Structure from R5: dual counting sort, LDS-staged k_u2, dst-sorted msg
// scatter from src-sorted edge traversal, fused segment reduces.
// ---------------------------------------------------------------------------

#define Y0C 0.28209479177387814f
#define C1C 0.4886025119029199f

typedef _Float16 hv2 __attribute__((ext_vector_type(2)));

#if defined(__has_builtin)
#if __has_builtin(__builtin_amdgcn_fdot2)
#define FDOT2(a, b, c) __builtin_amdgcn_fdot2((a), (b), (c), false)
#endif
#endif
#ifndef FDOT2
#define FDOT2(a, b, c) ((c) + (float)(a).x * (float)(b).x + (float)(a).y * (float)(b).y)
#endif

static __device__ __forceinline__ unsigned h2u(__half2 h) {
    union { __half2 h; unsigned u; } x; x.h = h; return x.u;
}
static __device__ __forceinline__ __half2 u2h(unsigned u) {
    union { unsigned u; __half2 h; } x; x.u = u; return x.h;
}
static __device__ __forceinline__ hv2 u2hv(unsigned u) {
    union { unsigned u; hv2 h; } x; x.u = u; return x.h;
}
static __device__ __forceinline__ unsigned hv2u(hv2 h) {
    union { hv2 h; unsigned u; } x; x.h = h; return x.u;
}
static __device__ __forceinline__ hv2 f2hv(float a, float b) {
    hv2 r; r.x = (_Float16)a; r.y = (_Float16)b; return r;
}
static __device__ __forceinline__ float hbits2f(unsigned short s) {
    __half_raw r; r.x = s; return __half2float((__half)r);
}

struct RadialW {
    const float *W1, *b1, *g1, *gb1, *b2, *g2, *gb2;
    const unsigned* W2q;   // packed [j*16+kp] = half2(W2[2kp][j], W2[2kp+1][j])
};

// radial MLP: (x0,x1,x2) -> 32 (LN,relu) -> [fdot2 GEMM] -> 32 (LN,relu)
// output packed as 16 natural k-pair half2 for the fdot2 contraction.
__device__ __forceinline__ void radial_net_pk(float x0, float x1, float x2,
                                              RadialW rw, hv2* hvpk /*[16]*/) {
    float h[32];
#pragma unroll
    for (int j = 0; j < 32; ++j)
        h[j] = rw.b1[j] + x0 * rw.W1[j] + x1 * rw.W1[32 + j] + x2 * rw.W1[64 + j];
    float mu = 0.f;
#pragma unroll
    for (int j = 0; j < 32; ++j) mu += h[j];
    mu *= 0.03125f;
    float var = 0.f;
#pragma unroll
    for (int j = 0; j < 32; ++j) { float d = h[j] - mu; var += d * d; }
    var *= 0.03125f;
    float rs = rsqrtf(var + 1e-5f);
#pragma unroll
    for (int j = 0; j < 32; ++j)
        h[j] = fmaxf((h[j] - mu) * rs * rw.g1[j] + rw.gb1[j], 0.f);

    hv2 hp[16];
#pragma unroll
    for (int p = 0; p < 16; ++p) hp[p] = f2hv(h[2 * p], h[2 * p + 1]);

    float h2[32];
#pragma unroll
    for (int j = 0; j < 32; ++j) {
        float acc = rw.b2[j];
        const unsigned* __restrict__ wj = rw.W2q + j * 16;   // uniform -> s_load
#pragma unroll
        for (int kp = 0; kp < 16; ++kp)
            acc = FDOT2(hp[kp], u2hv(wj[kp]), acc);
        h2[j] = acc;
    }
    mu = 0.f;
#pragma unroll
    for (int j = 0; j < 32; ++j) mu += h2[j];
    mu *= 0.03125f;
    var = 0.f;
#pragma unroll
    for (int j = 0; j < 32; ++j) { float d = h2[j] - mu; var += d * d; }
    var *= 0.03125f;
    rs = rsqrtf(var + 1e-5f);
    float y[32];
#pragma unroll
    for (int j = 0; j < 32; ++j)
        y[j] = fmaxf((h2[j] - mu) * rs * rw.g2[j] + rw.gb2[j], 0.f);
#pragma unroll
    for (int p = 0; p < 16; ++p) hvpk[p] = f2hv(y[2 * p], y[2 * p + 1]);
}

// v[o] = Ut[o] + sum_p dot2(hvpk[p], Um[o][p])   (fdot2, f32 accumulate)
__device__ __forceinline__ void contract_dot(const hv2* hvpk,
                                             const uint4* __restrict__ Um,
                                             const float* __restrict__ Ut,
                                             float* v /*[16]*/) {
    float4 t0 = ((const float4*)Ut)[0];
    float4 t1 = ((const float4*)Ut)[1];
    float4 t2 = ((const float4*)Ut)[2];
    float4 t3 = ((const float4*)Ut)[3];
    float tail[16] = {t0.x, t0.y, t0.z, t0.w, t1.x, t1.y, t1.z, t1.w,
                      t2.x, t2.y, t2.z, t2.w, t3.x, t3.y, t3.z, t3.w};
#pragma unroll
    for (int o = 0; o < 16; ++o) {
        uint4 q0 = Um[o * 4];
        uint4 q1 = Um[o * 4 + 1];
        uint4 q2 = Um[o * 4 + 2];
        uint4 q3 = Um[o * 4 + 3];
        float acc = tail[o];
        acc = FDOT2(hvpk[0],  u2hv(q0.x), acc);
        acc = FDOT2(hvpk[1],  u2hv(q0.y), acc);
        acc = FDOT2(hvpk[2],  u2hv(q0.z), acc);
        acc = FDOT2(hvpk[3],  u2hv(q0.w), acc);
        acc = FDOT2(hvpk[4],  u2hv(q1.x), acc);
        acc = FDOT2(hvpk[5],  u2hv(q1.y), acc);
        acc = FDOT2(hvpk[6],  u2hv(q1.z), acc);
        acc = FDOT2(hvpk[7],  u2hv(q1.w), acc);
        acc = FDOT2(hvpk[8],  u2hv(q2.x), acc);
        acc = FDOT2(hvpk[9],  u2hv(q2.y), acc);
        acc = FDOT2(hvpk[10], u2hv(q2.z), acc);
        acc = FDOT2(hvpk[11], u2hv(q2.w), acc);
        acc = FDOT2(hvpk[12], u2hv(q3.x), acc);
        acc = FDOT2(hvpk[13], u2hv(q3.y), acc);
        acc = FDOT2(hvpk[14], u2hv(q3.z), acc);
        acc = FDOT2(hvpk[15], u2hv(q3.w), acc);
        v[o] = acc;
    }
}

// ---- node embedding -------------------------------------------------------
__global__ void k_embed1(const float* __restrict__ nf, const float* __restrict__ W1,
                         const float* __restrict__ b1, float* __restrict__ t, int N) {
    int idx = blockIdx.x * blockDim.x + threadIdx.x;
    if (idx >= N * 67) return;
    int n = idx / 67, j = idx - n * 67;
    const float* __restrict__ x = nf + (size_t)n * 67;
    float s = b1[j];
    for (int i = 0; i < 67; ++i) s += x[i] * W1[i * 67 + j];
    t[idx] = (s > 0.f) ? s : expm1f(s);   // ELU(alpha=1)
}

__global__ void k_embed2(const float* __restrict__ t, const float* __restrict__ W2,
                         const float* __restrict__ b2, float* __restrict__ h0, int N) {
    int idx = blockIdx.x * blockDim.x + threadIdx.x;
    if (idx >= N * 16) return;
    int n = idx >> 4, c = idx & 15;
    const float* __restrict__ x = t + (size_t)n * 67;
    float s = b2[c];
    for (int i = 0; i < 67; ++i) s += x[i] * W2[i * 16 + c];
    h0[idx] = s;
}

// ---- counting sorts -------------------------------------------------------
__global__ void k_count2(const int* __restrict__ src, const int* __restrict__ dst,
                         int* __restrict__ cntd, int* __restrict__ cnts,
                         int* __restrict__ posd, int* __restrict__ poss, int E) {
    int e = blockIdx.x * blockDim.x + threadIdx.x;
    if (e >= E) return;
    posd[e] = atomicAdd(cntd + dst[e], 1);
    poss[e] = atomicAdd(cnts + src[e], 1);
}

// grid=2: block 0 scans cntd->rsd, block 1 scans cnts->rss
__global__ __launch_bounds__(1024) void k_scan2(const int* __restrict__ cntd,
                                                int* __restrict__ rsd,
                                                const int* __restrict__ cnts,
                                                int* __restrict__ rss, int N) {
    const int* __restrict__ c = (blockIdx.x == 0) ? cntd : cnts;
    int* __restrict__ rs      = (blockIdx.x == 0) ? rsd  : rss;
    int chunk = (N + 1023) >> 10;
    int lo = (int)threadIdx.x * chunk;
    int sum = 0;
    for (int j = 0; j < chunk; ++j) { int i = lo + j; sum += (i < N) ? c[i] : 0; }
    __shared__ int ps[1024];
    ps[threadIdx.x] = sum;
    __syncthreads();
    for (int off = 1; off < 1024; off <<= 1) {
        int t = (threadIdx.x >= (unsigned)off) ? ps[threadIdx.x - off] : 0;
        __syncthreads();
        ps[threadIdx.x] += t;
        __syncthreads();
    }
    int run = threadIdx.x ? ps[threadIdx.x - 1] : 0;
    if (threadIdx.x == 0) rs[0] = 0;
    for (int j = 0; j < chunk; ++j) {
        int i = lo + j;
        if (i < N) { run += c[i]; rs[i + 1] = run; }
    }
}

// ---- prep: geometry; edgeS (src-sorted), y1d (dst-sorted, f16), s2d map ---
__global__ void k_prep(const float* __restrict__ pos, const float* __restrict__ ew,
                       const int* __restrict__ src, const int* __restrict__ dst,
                       const int* __restrict__ rsd, const int* __restrict__ rss,
                       const int* __restrict__ posd, const int* __restrict__ poss,
                       float4* __restrict__ edgeS, uint2* __restrict__ y1d,
                       int* __restrict__ s2d, int E) {
    int e = blockIdx.x * blockDim.x + threadIdx.x;
    if (e >= E) return;
    int s = src[e], d = dst[e];
    float dx = pos[3 * d]     - pos[3 * s];
    float dy = pos[3 * d + 1] - pos[3 * s + 1];
    float dz = pos[3 * d + 2] - pos[3 * s + 2];
    float r = sqrtf(dx * dx + dy * dy + dz * dz);
    float im = 1.f / fmaxf(r, 1e-8f);
    int ts = rss[s] + poss[e];
    int td = rsd[d] + posd[e];
    s2d[ts] = td;
    edgeS[ts] = make_float4(ew[2 * e], ew[2 * e + 1], r, __int_as_float(s));
    y1d[td] = make_uint2(h2u(__floats2half2_rn(C1C * dy * im, C1C * dz * im)),
                         h2u(__floats2half2_rn(C1C * dx * im, 0.f)));
}

// ---- weight pre-pack ------------------------------------------------------
// W3: Wp[ni][(i*16+o)*18 + kp] = half2(W3[2kp][o*16+i], W3[2kp+1][o*16+i])
// W2: Wq[ni][j*16+kp]          = half2(W2[2kp][j],     W2[2kp+1][j])
// ni 0,1,2 -> nets 0,2,3.
__global__ void k_pack(const float* __restrict__ rW3, const float* __restrict__ rW2,
                       unsigned* __restrict__ Wp, unsigned* __restrict__ Wq) {
    int t = blockIdx.x * blockDim.x + threadIdx.x;
    if (t < 3 * 256) {
        int ni = t >> 8;
        int net = (ni == 0) ? 0 : ni + 1;
        int r = t & 255;
        int i = r >> 4, o = r & 15;
        const float* __restrict__ W3n = rW3 + (size_t)net * 8192;
        unsigned* __restrict__ dp = Wp + (size_t)ni * 4608 + (size_t)(i * 16 + o) * 18;
#pragma unroll
        for (int kp = 0; kp < 16; ++kp) {
            float a = W3n[(2 * kp) * 256 + o * 16 + i];
            float b = W3n[(2 * kp + 1) * 256 + o * 16 + i];
            dp[kp] = h2u(__floats2half2_rn(a, b));
        }
    } else if (t < 3 * 256 + 3 * 512) {
        int r = t - 3 * 256;
        int ni = r / 512;
        int net = (ni == 0) ? 0 : ni + 1;
        int jk = r - ni * 512;
        int j = jk >> 4, kp = jk & 15;
        const float* __restrict__ W2n = rW2 + (size_t)net * 1024;
        Wq[ni * 512 + j * 16 + kp] =
            h2u(__floats2half2_rn(W2n[(2 * kp) * 32 + j], W2n[(2 * kp + 1) * 32 + j]));
    }
}

// ---- U precompute: LDS-staged packed weights, 2 nodes/thread --------------
__global__ __launch_bounds__(256) void k_u2(
    const float* __restrict__ h, const unsigned* __restrict__ Wp,
    const float* __restrict__ b3A, const float* __restrict__ b3B,
    unsigned* __restrict__ Um0, float* __restrict__ Ut0,
    unsigned* __restrict__ Um1, float* __restrict__ Ut1,
    int wpA, int nbPerNet, int N) {
    __shared__ unsigned WL[4608];
    int netSel = blockIdx.x / nbPerNet;
    int nbase = (blockIdx.x - netSel * nbPerNet) * 32;
    const unsigned* __restrict__ g = Wp + (size_t)(wpA + netSel) * 4608;
    for (int j = threadIdx.x; j < 4608; j += 256) WL[j] = g[j];
    __syncthreads();

    const float* __restrict__ b3 = netSel ? b3B : b3A;
    unsigned* __restrict__ Um = netSel ? Um1 : Um0;
    float*    __restrict__ Ut = netSel ? Ut1 : Ut0;

    int o = threadIdx.x & 15;
    int pr = threadIdx.x >> 4;
    int n0 = nbase + pr * 2;
    int n1 = n0 + 1;
    bool ok0 = n0 < N, ok1 = n1 < N;
    int m0 = ok0 ? n0 : 0, m1 = ok1 ? n1 : 0;

    const float* __restrict__ bo = b3 + o * 16;
    float tA = 0.f, tB = 0.f;
    __half2 hhA[16], hhB[16];
    {
        const float4* hp = (const float4*)(h + (size_t)m0 * 16);
#pragma unroll
        for (int q = 0; q < 4; ++q) {
            float4 hv = hp[q];
            tA += hv.x * bo[4 * q] + hv.y * bo[4 * q + 1]
                + hv.z * bo[4 * q + 2] + hv.w * bo[4 * q + 3];
            hhA[4 * q]     = __floats2half2_rn(hv.x, hv.x);
            hhA[4 * q + 1] = __floats2half2_rn(hv.y, hv.y);
            hhA[4 * q + 2] = __floats2half2_rn(hv.z, hv.z);
            hhA[4 * q + 3] = __floats2half2_rn(hv.w, hv.w);
        }
    }
    {
        const float4* hp = (const float4*)(h + (size_t)m1 * 16);
#pragma unroll
        for (int q = 0; q < 4; ++q) {
            float4 hv = hp[q];
            tB += hv.x * bo[4 * q] + hv.y * bo[4 * q + 1]
                + hv.z * bo[4 * q + 2] + hv.w * bo[4 * q + 3];
            hhB[4 * q]     = __floats2half2_rn(hv.x, hv.x);
            hhB[4 * q + 1] = __floats2half2_rn(hv.y, hv.y);
            hhB[4 * q + 2] = __floats2half2_rn(hv.z, hv.z);
            hhB[4 * q + 3] = __floats2half2_rn(hv.w, hv.w);
        }
    }

    __half2 accA[16], accB[16];
#pragma unroll
    for (int p = 0; p < 16; ++p) {
        accA[p] = __floats2half2_rn(0.f, 0.f);
        accB[p] = __floats2half2_rn(0.f, 0.f);
    }

#pragma unroll
    for (int i = 0; i < 16; ++i) {
        const uint2* __restrict__ row = (const uint2*)(WL + i * 288 + o * 18);
        __half2 ha = hhA[i], hb = hhB[i];
#pragma unroll
        for (int q = 0; q < 8; ++q) {
            uint2 w = row[q];
            accA[2 * q]     = __hfma2(ha, u2h(w.x), accA[2 * q]);
            accA[2 * q + 1] = __hfma2(ha, u2h(w.y), accA[2 * q + 1]);
            accB[2 * q]     = __hfma2(hb, u2h(w.x), accB[2 * q]);
            accB[2 * q + 1] = __hfma2(hb, u2h(w.y), accB[2 * q + 1]);
        }
    }

    if (ok0) {
        uint4* du = (uint4*)(Um + ((size_t)(n0 * 16 + o)) * 16);
#pragma unroll
        for (int q = 0; q < 4; ++q)
            du[q] = make_uint4(h2u(accA[4 * q]), h2u(accA[4 * q + 1]),
                               h2u(accA[4 * q + 2]), h2u(accA[4 * q + 3]));
        Ut[n0 * 16 + o] = tA;
    }
    if (ok1) {
        uint4* du = (uint4*)(Um + ((size_t)(n1 * 16 + o)) * 16);
#pragma unroll
        for (int q = 0; q < 4; ++q)
            du[q] = make_uint4(h2u(accB[4 * q]), h2u(accB[4 * q + 1]),
                               h2u(accB[4 * q + 2]), h2u(accB[4 * q + 3]));
        Ut[n1 * 16 + o] = tB;
    }
}

// ---- edge kernels (src-sorted traversal, scatter-write to dst slot) -------
__global__ __launch_bounds__(256) void k_edgeL0(
    const float4* __restrict__ edgeS, const int* __restrict__ s2d, RadialW ra,
    const uint4* __restrict__ UmA, const float* __restrict__ UtA,
    unsigned short* __restrict__ msg /*stride 16*/, int E) {
    int t = blockIdx.x * blockDim.x + threadIdx.x;
    if (t >= E) return;
    float4 a = edgeS[t];
    int sn = __float_as_int(a.w);
    hv2 hv[16];
    float v[16];
    radial_net_pk(a.x, a.y, a.z, ra, hv);
    contract_dot(hv, UmA + (size_t)sn * 64, UtA + (size_t)sn * 16, v);
    int td = s2d[t];
    uint4* m = (uint4*)(msg + (size_t)td * 16);
    m[0] = make_uint4(hv2u(f2hv(v[0], v[1])),  hv2u(f2hv(v[2], v[3])),
                      hv2u(f2hv(v[4], v[5])),  hv2u(f2hv(v[6], v[7])));
    m[1] = make_uint4(hv2u(f2hv(v[8], v[9])),  hv2u(f2hv(v[10], v[11])),
                      hv2u(f2hv(v[12], v[13])), hv2u(f2hv(v[14], v[15])));
}

__global__ __launch_bounds__(256) void k_edgeL1(
    const float4* __restrict__ edgeS, const int* __restrict__ s2d,
    RadialW ra, RadialW rb,
    const uint4* __restrict__ UmA, const float* __restrict__ UtA,
    const uint4* __restrict__ UmB, const float* __restrict__ UtB,
    unsigned short* __restrict__ msg /*stride 32*/, int nbE, int E) {
    int half = (blockIdx.x >= (unsigned)nbE) ? 1 : 0;
    int t = (blockIdx.x - half * nbE) * blockDim.x + threadIdx.x;
    if (t >= E) return;
    float4 a = edgeS[t];
    int sn = __float_as_int(a.w);
    RadialW rw = half ? rb : ra;
    const uint4* __restrict__ Um = half ? UmB : UmA;
    const float* __restrict__ Ut = half ? UtB : UtA;
    hv2 hv[16];
    float v[16];
    radial_net_pk(a.x, a.y, a.z, rw, hv);
    contract_dot(hv, Um + (size_t)sn * 64, Ut + (size_t)sn * 16, v);
    int td = s2d[t];
    uint4* m = (uint4*)(msg + (size_t)td * 32 + half * 16);
    m[0] = make_uint4(hv2u(f2hv(v[0], v[1])),  hv2u(f2hv(v[2], v[3])),
                      hv2u(f2hv(v[4], v[5])),  hv2u(f2hv(v[6], v[7])));
    m[1] = make_uint4(hv2u(f2hv(v[8], v[9])),  hv2u(f2hv(v[10], v[11])),
                      hv2u(f2hv(v[12], v[13])), hv2u(f2hv(v[14], v[15])));
}

// ---- segment reduces (contiguous, dst-sorted) -----------------------------
__global__ void k_reduce0(const unsigned short* __restrict__ msg,
                          const int* __restrict__ rowstart,
                          const float* __restrict__ h, const float* __restrict__ Wself,
                          float* __restrict__ out, int N) {
    int idx = blockIdx.x * blockDim.x + threadIdx.x;
    if (idx >= N * 16) return;
    int n = idx >> 4, o = idx & 15;
    int s = rowstart[n], t1 = rowstart[n + 1];
    float acc = 0.f;
    for (int t = s; t < t1; ++t) acc += hbits2f(msg[(size_t)t * 16 + o]);
    int d = t1 - s;
    float invd = (d > 0) ? 1.f / (float)d : 0.f;
    float hi   = (d > 0) ? 1.f : 0.f;
    const float* __restrict__ hn = h + (size_t)n * 16;
    const float* __restrict__ w  = Wself + o * 16;
    float self = 0.f;
#pragma unroll
    for (int c = 0; c < 16; ++c) self += hn[c] * w[c];
    out[idx] = Y0C * acc * invd + hi * self;
}

__global__ void k_reduce1(const unsigned short* __restrict__ msg,  // stride 32
                          const uint2* __restrict__ y1d,
                          const int* __restrict__ rowstart,
                          const float* __restrict__ h, const float* __restrict__ Wself,
                          float* __restrict__ out0, float* __restrict__ out1, int N) {
    int idx = blockIdx.x * blockDim.x + threadIdx.x;
    if (idx >= N * 16) return;
    int n = idx >> 4, o = idx & 15;
    int s = rowstart[n], t1 = rowstart[n + 1];
    float a0 = 0.f, ax = 0.f, ay = 0.f, az = 0.f;
    for (int t = s; t < t1; ++t) {
        const unsigned short* row = msg + (size_t)t * 32;
        a0 += hbits2f(row[o]);
        float b = hbits2f(row[16 + o]);
        uint2 yv = y1d[t];
        ax += b * hbits2f((unsigned short)yv.x);
        ay += b * hbits2f((unsigned short)(yv.x >> 16));
        az += b * hbits2f((unsigned short)yv.y);
    }
    int d = t1 - s;
    float invd = (d > 0) ? 1.f / (float)d : 0.f;
    float hi   = (d > 0) ? 1.f : 0.f;
    const float* __restrict__ hn = h + (size_t)n * 16;
    const float* __restrict__ w  = Wself + o * 16;
    float self = 0.f;
#pragma unroll
    for (int c = 0; c < 16; ++c) self += hn[c] * w[c];
    out0[idx] = Y0C * a0 * invd + hi * self;
    out1[(size_t)idx * 3]     = ax * invd;
    out1[(size_t)idx * 3 + 1] = ay * invd;
    out1[(size_t)idx * 3 + 2] = az * invd;
}

// ---------------------------------------------------------------------------
extern "C" void kernel_launch(void* const* d_in, const int* in_sizes, int n_in,
                              void* d_out, int out_size, void* d_ws, size_t ws_size,
                              hipStream_t stream) {
    (void)n_in; (void)out_size; (void)ws_size;
    const float* node_feats = (const float*)d_in[0];
    const float* pos    = (const float*)d_in[1];
    const float* edge_w = (const float*)d_in[2];
    const float* lin1_W = (const float*)d_in[3];
    const float* lin1_b = (const float*)d_in[4];
    const float* lin2_W = (const float*)d_in[5];
    const float* lin2_b = (const float*)d_in[6];
    const float* rW1    = (const float*)d_in[7];
    const float* rb1    = (const float*)d_in[8];
    const float* ln1_g  = (const float*)d_in[9];
    const float* ln1_b  = (const float*)d_in[10];
    const float* rW2    = (const float*)d_in[11];
    const float* rb2    = (const float*)d_in[12];
    const float* ln2_g  = (const float*)d_in[13];
    const float* ln2_b  = (const float*)d_in[14];
    const float* rW3    = (const float*)d_in[15];
    const float* rb3    = (const float*)d_in[16];
    const float* Wself  = (const float*)d_in[17];
    const int*   src    = (const int*)d_in[18];
    const int*   dst    = (const int*)d_in[19];

    const int N = in_sizes[1] / 3;     // pos is [N,3]
    const int E = in_sizes[18];        // src is [E]

    char* ws = (char*)d_ws;
    size_t off = 0;
    auto carve = [&](size_t bytes) -> char* {
        char* p = ws + off;
        off = (off + bytes + 255) & ~(size_t)255;
        return p;
    };
    float* h0   = (float*)carve((size_t)N * 16 * 4);
    float* h1   = (float*)carve((size_t)N * 16 * 4);
    int*   cntd = (int*)carve((size_t)N * 4);
    int*   cnts = (int*)carve((size_t)N * 4);
    int*   rsd  = (int*)carve((size_t)(N + 1) * 4);
    int*   rss  = (int*)carve((size_t)(N + 1) * 4);
    int*   s2d  = (int*)carve((size_t)E * 4);
    float4* edgeS = (float4*)carve((size_t)E * 16);
    uint2*  y1d   = (uint2*)carve((size_t)E * 8);
    unsigned* UaM = (unsigned*)carve((size_t)N * 16 * 64);
    float*    UaT = (float*)carve((size_t)N * 16 * 4);
    unsigned* UbM = (unsigned*)carve((size_t)N * 16 * 64);
    float*    UbT = (float*)carve((size_t)N * 16 * 4);
    unsigned* Wp  = (unsigned*)carve((size_t)3 * 4608 * 4);
    unsigned* Wq  = (unsigned*)carve((size_t)3 * 512 * 4);
    unsigned short* msg = (unsigned short*)carve((size_t)E * 32 * 2);
    // disjoint-lifetime overlays inside msg (dead before edge kernels run):
    float* tmb  = (float*)msg;                           // [N,67] embed temp
    int*   posd = (int*)((char*)msg + (8u << 20));       // [E]
    int*   poss = (int*)((char*)msg + (14u << 20));      // [E]

    auto nb = [](int n) { return (n + 255) / 256; };
    const int nbE = nb(E);
    const int nbU = (N + 31) / 32;

    // single fused memset (cntd and cnts are adjacent carves)
    hipMemsetAsync(cntd, 0, (size_t)((char*)cnts - (char*)cntd) + (size_t)N * 4, stream);

    k_pack<<<nb(3 * 256 + 3 * 512), 256, 0, stream>>>(rW3, rW2, Wp, Wq);
    k_embed1<<<nb(N * 67), 256, 0, stream>>>(node_feats, lin1_W, lin1_b, tmb, N);
    k_embed2<<<nb(N * 16), 256, 0, stream>>>(tmb, lin2_W, lin2_b, h0, N);

    k_count2<<<nbE, 256, 0, stream>>>(src, dst, cntd, cnts, posd, poss, E);
    k_scan2<<<2, 1024, 0, stream>>>(cntd, rsd, cnts, rss, N);
    k_prep<<<nbE, 256, 0, stream>>>(pos, edge_w, src, dst, rsd, rss, posd, poss,
                                    edgeS, y1d, s2d, E);

    auto rnet = [&](int net, int ni) -> RadialW {
        RadialW r;
        r.W1 = rW1 + net * 96;   r.b1 = rb1 + net * 32;
        r.g1 = ln1_g + net * 32; r.gb1 = ln1_b + net * 32;
        r.b2 = rb2 + net * 32;
        r.g2 = ln2_g + net * 32; r.gb2 = ln2_b + net * 32;
        r.W2q = Wq + ni * 512;
        return r;
    };

    // ---- layer 0 (degree-1 branch dead: only net 0) ----
    k_u2<<<nbU, 256, 0, stream>>>(h0, Wp, rb3, rb3, UaM, UaT, UbM, UbT,
                                  /*wpA=*/0, nbU, N);
    k_edgeL0<<<nbE, 256, 0, stream>>>(edgeS, s2d, rnet(0, 0), (const uint4*)UaM, UaT,
                                      msg, E);
    k_reduce0<<<nb(N * 16), 256, 0, stream>>>(msg, rsd, h0, Wself, h1, N);

    // ---- layer 1 (nets 2,3) ----
    k_u2<<<2 * nbU, 256, 0, stream>>>(h1, Wp, rb3 + 2 * 256, rb3 + 3 * 256,
                                      UaM, UaT, UbM, UbT, /*wpA=*/1, nbU, N);
    k_edgeL1<<<2 * nbE, 256, 0, stream>>>(edgeS, s2d, rnet(2, 1), rnet(3, 2),
                                          (const uint4*)UaM, UaT,
                                          (const uint4*)UbM, UbT, msg, nbE, E);
    float* out0 = (float*)d_out;
    float* out1 = (float*)d_out + (size_t)N * 16;
    k_reduce1<<<nb(N * 16), 256, 0, stream>>>(msg, y1d, rsd, h1, Wself + 256,
                                              out0, out1, N);
}

// Round 7
// 355.551 us; speedup vs baseline: 4.9545x; 1.0144x over previous
//
#include <hip/hip_runtime.h>
#include <hip/hip_fp16.h>

// ---------------------------------------------------------------------------
// SE3Transformer block. Round 7:
//   - LN mean/var sums tree-reduced (4 partials) in radial net: removes the
//     only 32-deep serial dependency chains in the edge kernels
//   - embed fused into one wave-per-node kernel (LDS handoff, no tmb HBM
//     round-trip); weight pre-pack folded into the same launch (role-split)
//   - segment reduces unrolled x2 with dual accumulator sets
// Structure from R6: dual counting sort, LDS-staged k_u2, fdot2 GEMM +
// contraction, src-sorted edge traversal scatter-writing dst-sorted msg.
// ---------------------------------------------------------------------------

#define Y0C 0.28209479177387814f
#define C1C 0.4886025119029199f

typedef _Float16 hv2 __attribute__((ext_vector_type(2)));

#if defined(__has_builtin)
#if __has_builtin(__builtin_amdgcn_fdot2)
#define FDOT2(a, b, c) __builtin_amdgcn_fdot2((a), (b), (c), false)
#endif
#endif
#ifndef FDOT2
#define FDOT2(a, b, c) ((c) + (float)(a).x * (float)(b).x + (float)(a).y * (float)(b).y)
#endif

static __device__ __forceinline__ unsigned h2u(__half2 h) {
    union { __half2 h; unsigned u; } x; x.h = h; return x.u;
}
static __device__ __forceinline__ __half2 u2h(unsigned u) {
    union { unsigned u; __half2 h; } x; x.u = u; return x.h;
}
static __device__ __forceinline__ hv2 u2hv(unsigned u) {
    union { unsigned u; hv2 h; } x; x.u = u; return x.h;
}
static __device__ __forceinline__ unsigned hv2u(hv2 h) {
    union { hv2 h; unsigned u; } x; x.h = h; return x.u;
}
static __device__ __forceinline__ hv2 f2hv(float a, float b) {
    hv2 r; r.x = (_Float16)a; r.y = (_Float16)b; return r;
}
static __device__ __forceinline__ float hbits2f(unsigned short s) {
    __half_raw r; r.x = s; return __half2float((__half)r);
}

struct RadialW {
    const float *W1, *b1, *g1, *gb1, *b2, *g2, *gb2;
    const unsigned* W2q;   // packed [j*16+kp] = half2(W2[2kp][j], W2[2kp+1][j])
};

// radial MLP: (x0,x1,x2) -> 32 (LN,relu) -> [fdot2 GEMM] -> 32 (LN,relu)
// LN mean/var via 4-way partial sums (short dep chains).
__device__ __forceinline__ void radial_net_pk(float x0, float x1, float x2,
                                              RadialW rw, hv2* hvpk /*[16]*/) {
    float h[32];
#pragma unroll
    for (int j = 0; j < 32; ++j)
        h[j] = rw.b1[j] + x0 * rw.W1[j] + x1 * rw.W1[32 + j] + x2 * rw.W1[64 + j];
    float s0 = 0.f, s1 = 0.f, s2 = 0.f, s3 = 0.f;
#pragma unroll
    for (int p = 0; p < 8; ++p) {
        s0 += h[4 * p]; s1 += h[4 * p + 1]; s2 += h[4 * p + 2]; s3 += h[4 * p + 3];
    }
    float mu = ((s0 + s1) + (s2 + s3)) * 0.03125f;
    float v0 = 0.f, v1 = 0.f, v2 = 0.f, v3 = 0.f;
#pragma unroll
    for (int p = 0; p < 8; ++p) {
        float d0 = h[4 * p] - mu, d1 = h[4 * p + 1] - mu;
        float d2 = h[4 * p + 2] - mu, d3 = h[4 * p + 3] - mu;
        v0 = fmaf(d0, d0, v0); v1 = fmaf(d1, d1, v1);
        v2 = fmaf(d2, d2, v2); v3 = fmaf(d3, d3, v3);
    }
    float var = ((v0 + v1) + (v2 + v3)) * 0.03125f;
    float rs = rsqrtf(var + 1e-5f);
#pragma unroll
    for (int j = 0; j < 32; ++j)
        h[j] = fmaxf((h[j] - mu) * rs * rw.g1[j] + rw.gb1[j], 0.f);

    hv2 hp[16];
#pragma unroll
    for (int p = 0; p < 16; ++p) hp[p] = f2hv(h[2 * p], h[2 * p + 1]);

    float h2[32];
#pragma unroll
    for (int j = 0; j < 32; ++j) {
        float acc = rw.b2[j];
        const unsigned* __restrict__ wj = rw.W2q + j * 16;   // uniform -> s_load
#pragma unroll
        for (int kp = 0; kp < 16; ++kp)
            acc = FDOT2(hp[kp], u2hv(wj[kp]), acc);
        h2[j] = acc;
    }
    s0 = s1 = s2 = s3 = 0.f;
#pragma unroll
    for (int p = 0; p < 8; ++p) {
        s0 += h2[4 * p]; s1 += h2[4 * p + 1]; s2 += h2[4 * p + 2]; s3 += h2[4 * p + 3];
    }
    mu = ((s0 + s1) + (s2 + s3)) * 0.03125f;
    v0 = v1 = v2 = v3 = 0.f;
#pragma unroll
    for (int p = 0; p < 8; ++p) {
        float d0 = h2[4 * p] - mu, d1 = h2[4 * p + 1] - mu;
        float d2 = h2[4 * p + 2] - mu, d3 = h2[4 * p + 3] - mu;
        v0 = fmaf(d0, d0, v0); v1 = fmaf(d1, d1, v1);
        v2 = fmaf(d2, d2, v2); v3 = fmaf(d3, d3, v3);
    }
    var = ((v0 + v1) + (v2 + v3)) * 0.03125f;
    rs = rsqrtf(var + 1e-5f);
    float y[32];
#pragma unroll
    for (int j = 0; j < 32; ++j)
        y[j] = fmaxf((h2[j] - mu) * rs * rw.g2[j] + rw.gb2[j], 0.f);
#pragma unroll
    for (int p = 0; p < 16; ++p) hvpk[p] = f2hv(y[2 * p], y[2 * p + 1]);
}

// v[o] = Ut[o] + sum_p dot2(hvpk[p], Um[o][p])   (fdot2, f32 accumulate)
__device__ __forceinline__ void contract_dot(const hv2* hvpk,
                                             const uint4* __restrict__ Um,
                                             const float* __restrict__ Ut,
                                             float* v /*[16]*/) {
    float4 t0 = ((const float4*)Ut)[0];
    float4 t1 = ((const float4*)Ut)[1];
    float4 t2 = ((const float4*)Ut)[2];
    float4 t3 = ((const float4*)Ut)[3];
    float tail[16] = {t0.x, t0.y, t0.z, t0.w, t1.x, t1.y, t1.z, t1.w,
                      t2.x, t2.y, t2.z, t2.w, t3.x, t3.y, t3.z, t3.w};
#pragma unroll
    for (int o = 0; o < 16; ++o) {
        uint4 q0 = Um[o * 4];
        uint4 q1 = Um[o * 4 + 1];
        uint4 q2 = Um[o * 4 + 2];
        uint4 q3 = Um[o * 4 + 3];
        float acc = tail[o];
        acc = FDOT2(hvpk[0],  u2hv(q0.x), acc);
        acc = FDOT2(hvpk[1],  u2hv(q0.y), acc);
        acc = FDOT2(hvpk[2],  u2hv(q0.z), acc);
        acc = FDOT2(hvpk[3],  u2hv(q0.w), acc);
        acc = FDOT2(hvpk[4],  u2hv(q1.x), acc);
        acc = FDOT2(hvpk[5],  u2hv(q1.y), acc);
        acc = FDOT2(hvpk[6],  u2hv(q1.z), acc);
        acc = FDOT2(hvpk[7],  u2hv(q1.w), acc);
        acc = FDOT2(hvpk[8],  u2hv(q2.x), acc);
        acc = FDOT2(hvpk[9],  u2hv(q2.y), acc);
        acc = FDOT2(hvpk[10], u2hv(q2.z), acc);
        acc = FDOT2(hvpk[11], u2hv(q2.w), acc);
        acc = FDOT2(hvpk[12], u2hv(q3.x), acc);
        acc = FDOT2(hvpk[13], u2hv(q3.y), acc);
        acc = FDOT2(hvpk[14], u2hv(q3.z), acc);
        acc = FDOT2(hvpk[15], u2hv(q3.w), acc);
        v[o] = acc;
    }
}

// ---- fused embed (wave-per-node) + weight pre-pack (role-split blocks) ----
// embed: t = ELU(x@W1+b1); h0 = t@W2+b2. x,t staged in LDS per wave.
// pack (blocks >= nbEmb):
//   W3: Wp[ni][(i*16+o)*18+kp] = half2(W3[2kp][o*16+i], W3[2kp+1][o*16+i])
//   W2: Wq[ni][j*16+kp]        = half2(W2[2kp][j],      W2[2kp+1][j])
__global__ __launch_bounds__(256) void k_embed_pack(
    const float* __restrict__ nf, const float* __restrict__ W1,
    const float* __restrict__ b1, const float* __restrict__ W2,
    const float* __restrict__ b2, float* __restrict__ h0, int N, int nbEmb,
    const float* __restrict__ rW3, const float* __restrict__ rW2,
    unsigned* __restrict__ Wp, unsigned* __restrict__ Wq) {
    if (blockIdx.x >= (unsigned)nbEmb) {
        int t = (blockIdx.x - nbEmb) * 256 + threadIdx.x;
        if (t < 3 * 256) {
            int ni = t >> 8;
            int net = (ni == 0) ? 0 : ni + 1;
            int r = t & 255;
            int i = r >> 4, o = r & 15;
            const float* __restrict__ W3n = rW3 + (size_t)net * 8192;
            unsigned* __restrict__ dp = Wp + (size_t)ni * 4608 + (size_t)(i * 16 + o) * 18;
#pragma unroll
            for (int kp = 0; kp < 16; ++kp) {
                float a = W3n[(2 * kp) * 256 + o * 16 + i];
                float b = W3n[(2 * kp + 1) * 256 + o * 16 + i];
                dp[kp] = h2u(__floats2half2_rn(a, b));
            }
        } else if (t < 3 * 256 + 3 * 512) {
            int r = t - 3 * 256;
            int ni = r / 512;
            int net = (ni == 0) ? 0 : ni + 1;
            int jk = r - ni * 512;
            int j = jk >> 4, kp = jk & 15;
            const float* __restrict__ W2n = rW2 + (size_t)net * 1024;
            Wq[ni * 512 + j * 16 + kp] =
                h2u(__floats2half2_rn(W2n[(2 * kp) * 32 + j],
                                      W2n[(2 * kp + 1) * 32 + j]));
        }
        return;
    }
    __shared__ float xs[4][68];
    __shared__ float ts[4][68];
    int w = threadIdx.x >> 6, lane = threadIdx.x & 63;
    int n = blockIdx.x * 4 + w;
    bool ok = n < N;
    int nn = ok ? n : (N - 1);
    const float* __restrict__ x = nf + (size_t)nn * 67;
    xs[w][lane] = x[lane];
    if (lane < 3) xs[w][64 + lane] = x[64 + lane];
    __syncthreads();
    // phase A: outputs j = lane, plus j = 64+lane for lanes 0..2
    int j2 = 64 + lane; int j2c = (j2 < 67) ? j2 : 66;
    float a0 = b1[lane], a1 = b1[j2c];
    for (int i = 0; i < 67; ++i) {
        float xi = xs[w][i];
        a0 = fmaf(xi, W1[i * 67 + lane], a0);
        a1 = fmaf(xi, W1[i * 67 + j2c], a1);
    }
    ts[w][lane] = (a0 > 0.f) ? a0 : expm1f(a0);
    if (lane < 3) ts[w][64 + lane] = (a1 > 0.f) ? a1 : expm1f(a1);
    __syncthreads();
    // phase B: 4-way split dot over i, combine
    int c = lane & 15, q = lane >> 4;
    int i0 = q * 17, i1 = (i0 + 17 < 67) ? (i0 + 17) : 67;
    float s = (q == 0) ? b2[c] : 0.f;
    for (int i = i0; i < i1; ++i) s = fmaf(ts[w][i], W2[i * 16 + c], s);
    __syncthreads();            // reuse xs as scratch after all reads done
    xs[w][lane] = s;
    __syncthreads();
    if (ok && lane < 16)
        h0[(size_t)n * 16 + lane] =
            (xs[w][lane] + xs[w][lane + 16]) + (xs[w][lane + 32] + xs[w][lane + 48]);
}

// ---- counting sorts -------------------------------------------------------
__global__ void k_count2(const int* __restrict__ src, const int* __restrict__ dst,
                         int* __restrict__ cntd, int* __restrict__ cnts,
                         int* __restrict__ posd, int* __restrict__ poss, int E) {
    int e = blockIdx.x * blockDim.x + threadIdx.x;
    if (e >= E) return;
    posd[e] = atomicAdd(cntd + dst[e], 1);
    poss[e] = atomicAdd(cnts + src[e], 1);
}

// grid=2: block 0 scans cntd->rsd, block 1 scans cnts->rss
__global__ __launch_bounds__(1024) void k_scan2(const int* __restrict__ cntd,
                                                int* __restrict__ rsd,
                                                const int* __restrict__ cnts,
                                                int* __restrict__ rss, int N) {
    const int* __restrict__ c = (blockIdx.x == 0) ? cntd : cnts;
    int* __restrict__ rs      = (blockIdx.x == 0) ? rsd  : rss;
    int chunk = (N + 1023) >> 10;
    int lo = (int)threadIdx.x * chunk;
    int sum = 0;
    for (int j = 0; j < chunk; ++j) { int i = lo + j; sum += (i < N) ? c[i] : 0; }
    __shared__ int ps[1024];
    ps[threadIdx.x] = sum;
    __syncthreads();
    for (int off = 1; off < 1024; off <<= 1) {
        int t = (threadIdx.x >= (unsigned)off) ? ps[threadIdx.x - off] : 0;
        __syncthreads();
        ps[threadIdx.x] += t;
        __syncthreads();
    }
    int run = threadIdx.x ? ps[threadIdx.x - 1] : 0;
    if (threadIdx.x == 0) rs[0] = 0;
    for (int j = 0; j < chunk; ++j) {
        int i = lo + j;
        if (i < N) { run += c[i]; rs[i + 1] = run; }
    }
}

// ---- prep: geometry; edgeS (src-sorted), y1d (dst-sorted, f16), s2d map ---
__global__ void k_prep(const float* __restrict__ pos, const float* __restrict__ ew,
                       const int* __restrict__ src, const int* __restrict__ dst,
                       const int* __restrict__ rsd, const int* __restrict__ rss,
                       const int* __restrict__ posd, const int* __restrict__ poss,
                       float4* __restrict__ edgeS, uint2* __restrict__ y1d,
                       int* __restrict__ s2d, int E) {
    int e = blockIdx.x * blockDim.x + threadIdx.x;
    if (e >= E) return;
    int s = src[e], d = dst[e];
    float dx = pos[3 * d]     - pos[3 * s];
    float dy = pos[3 * d + 1] - pos[3 * s + 1];
    float dz = pos[3 * d + 2] - pos[3 * s + 2];
    float r = sqrtf(dx * dx + dy * dy + dz * dz);
    float im = 1.f / fmaxf(r, 1e-8f);
    int ts = rss[s] + poss[e];
    int td = rsd[d] + posd[e];
    s2d[ts] = td;
    edgeS[ts] = make_float4(ew[2 * e], ew[2 * e + 1], r, __int_as_float(s));
    y1d[td] = make_uint2(h2u(__floats2half2_rn(C1C * dy * im, C1C * dz * im)),
                         h2u(__floats2half2_rn(C1C * dx * im, 0.f)));
}

// ---- U precompute: LDS-staged packed weights, 2 nodes/thread --------------
__global__ __launch_bounds__(256) void k_u2(
    const float* __restrict__ h, const unsigned* __restrict__ Wp,
    const float* __restrict__ b3A, const float* __restrict__ b3B,
    unsigned* __restrict__ Um0, float* __restrict__ Ut0,
    unsigned* __restrict__ Um1, float* __restrict__ Ut1,
    int wpA, int nbPerNet, int N) {
    __shared__ unsigned WL[4608];
    int netSel = blockIdx.x / nbPerNet;
    int nbase = (blockIdx.x - netSel * nbPerNet) * 32;
    const unsigned* __restrict__ g = Wp + (size_t)(wpA + netSel) * 4608;
    for (int j = threadIdx.x; j < 4608; j += 256) WL[j] = g[j];
    __syncthreads();

    const float* __restrict__ b3 = netSel ? b3B : b3A;
    unsigned* __restrict__ Um = netSel ? Um1 : Um0;
    float*    __restrict__ Ut = netSel ? Ut1 : Ut0;

    int o = threadIdx.x & 15;
    int pr = threadIdx.x >> 4;
    int n0 = nbase + pr * 2;
    int n1 = n0 + 1;
    bool ok0 = n0 < N, ok1 = n1 < N;
    int m0 = ok0 ? n0 : 0, m1 = ok1 ? n1 : 0;

    const float* __restrict__ bo = b3 + o * 16;
    float tA = 0.f, tB = 0.f;
    __half2 hhA[16], hhB[16];
    {
        const float4* hp = (const float4*)(h + (size_t)m0 * 16);
#pragma unroll
        for (int q = 0; q < 4; ++q) {
            float4 hv = hp[q];
            tA += hv.x * bo[4 * q] + hv.y * bo[4 * q + 1]
                + hv.z * bo[4 * q + 2] + hv.w * bo[4 * q + 3];
            hhA[4 * q]     = __floats2half2_rn(hv.x, hv.x);
            hhA[4 * q + 1] = __floats2half2_rn(hv.y, hv.y);
            hhA[4 * q + 2] = __floats2half2_rn(hv.z, hv.z);
            hhA[4 * q + 3] = __floats2half2_rn(hv.w, hv.w);
        }
    }
    {
        const float4* hp = (const float4*)(h + (size_t)m1 * 16);
#pragma unroll
        for (int q = 0; q < 4; ++q) {
            float4 hv = hp[q];
            tB += hv.x * bo[4 * q] + hv.y * bo[4 * q + 1]
                + hv.z * bo[4 * q + 2] + hv.w * bo[4 * q + 3];
            hhB[4 * q]     = __floats2half2_rn(hv.x, hv.x);
            hhB[4 * q + 1] = __floats2half2_rn(hv.y, hv.y);
            hhB[4 * q + 2] = __floats2half2_rn(hv.z, hv.z);
            hhB[4 * q + 3] = __floats2half2_rn(hv.w, hv.w);
        }
    }

    __half2 accA[16], accB[16];
#pragma unroll
    for (int p = 0; p < 16; ++p) {
        accA[p] = __floats2half2_rn(0.f, 0.f);
        accB[p] = __floats2half2_rn(0.f, 0.f);
    }

#pragma unroll
    for (int i = 0; i < 16; ++i) {
        const uint2* __restrict__ row = (const uint2*)(WL + i * 288 + o * 18);
        __half2 ha = hhA[i], hb = hhB[i];
#pragma unroll
        for (int q = 0; q < 8; ++q) {
            uint2 w = row[q];
            accA[2 * q]     = __hfma2(ha, u2h(w.x), accA[2 * q]);
            accA[2 * q + 1] = __hfma2(ha, u2h(w.y), accA[2 * q + 1]);
            accB[2 * q]     = __hfma2(hb, u2h(w.x), accB[2 * q]);
            accB[2 * q + 1] = __hfma2(hb, u2h(w.y), accB[2 * q + 1]);
        }
    }

    if (ok0) {
        uint4* du = (uint4*)(Um + ((size_t)(n0 * 16 + o)) * 16);
#pragma unroll
        for (int q = 0; q < 4; ++q)
            du[q] = make_uint4(h2u(accA[4 * q]), h2u(accA[4 * q + 1]),
                               h2u(accA[4 * q + 2]), h2u(accA[4 * q + 3]));
        Ut[n0 * 16 + o] = tA;
    }
    if (ok1) {
        uint4* du = (uint4*)(Um + ((size_t)(n1 * 16 + o)) * 16);
#pragma unroll
        for (int q = 0; q < 4; ++q)
            du[q] = make_uint4(h2u(accB[4 * q]), h2u(accB[4 * q + 1]),
                               h2u(accB[4 * q + 2]), h2u(accB[4 * q + 3]));
        Ut[n1 * 16 + o] = tB;
    }
}

// ---- edge kernels (src-sorted traversal, scatter-write to dst slot) -------
__global__ __launch_bounds__(256) void k_edgeL0(
    const float4* __restrict__ edgeS, const int* __restrict__ s2d, RadialW ra,
    const uint4* __restrict__ UmA, const float* __restrict__ UtA,
    unsigned short* __restrict__ msg /*stride 16*/, int E) {
    int t = blockIdx.x * blockDim.x + threadIdx.x;
    if (t >= E) return;
    float4 a = edgeS[t];
    int sn = __float_as_int(a.w);
    hv2 hv[16];
    float v[16];
    radial_net_pk(a.x, a.y, a.z, ra, hv);
    contract_dot(hv, UmA + (size_t)sn * 64, UtA + (size_t)sn * 16, v);
    int td = s2d[t];
    uint4* m = (uint4*)(msg + (size_t)td * 16);
    m[0] = make_uint4(hv2u(f2hv(v[0], v[1])),  hv2u(f2hv(v[2], v[3])),
                      hv2u(f2hv(v[4], v[5])),  hv2u(f2hv(v[6], v[7])));
    m[1] = make_uint4(hv2u(f2hv(v[8], v[9])),  hv2u(f2hv(v[10], v[11])),
                      hv2u(f2hv(v[12], v[13])), hv2u(f2hv(v[14], v[15])));
}

__global__ __launch_bounds__(256) void k_edgeL1(
    const float4* __restrict__ edgeS, const int* __restrict__ s2d,
    RadialW ra, RadialW rb,
    const uint4* __restrict__ UmA, const float* __restrict__ UtA,
    const uint4* __restrict__ UmB, const float* __restrict__ UtB,
    unsigned short* __restrict__ msg /*stride 32*/, int nbE, int E) {
    int half = (blockIdx.x >= (unsigned)nbE) ? 1 : 0;
    int t = (blockIdx.x - half * nbE) * blockDim.x + threadIdx.x;
    if (t >= E) return;
    float4 a = edgeS[t];
    int sn = __float_as_int(a.w);
    RadialW rw = half ? rb : ra;
    const uint4* __restrict__ Um = half ? UmB : UmA;
    const float* __restrict__ Ut = half ? UtB : UtA;
    hv2 hv[16];
    float v[16];
    radial_net_pk(a.x, a.y, a.z, rw, hv);
    contract_dot(hv, Um + (size_t)sn * 64, Ut + (size_t)sn * 16, v);
    int td = s2d[t];
    uint4* m = (uint4*)(msg + (size_t)td * 32 + half * 16);
    m[0] = make_uint4(hv2u(f2hv(v[0], v[1])),  hv2u(f2hv(v[2], v[3])),
                      hv2u(f2hv(v[4], v[5])),  hv2u(f2hv(v[6], v[7])));
    m[1] = make_uint4(hv2u(f2hv(v[8], v[9])),  hv2u(f2hv(v[10], v[11])),
                      hv2u(f2hv(v[12], v[13])), hv2u(f2hv(v[14], v[15])));
}

// ---- segment reduces (contiguous, dst-sorted; x2 unrolled) ----------------
__global__ void k_reduce0(const unsigned short* __restrict__ msg,
                          const int* __restrict__ rowstart,
                          const float* __restrict__ h, const float* __restrict__ Wself,
                          float* __restrict__ out, int N) {
    int idx = blockIdx.x * blockDim.x + threadIdx.x;
    if (idx >= N * 16) return;
    int n = idx >> 4, o = idx & 15;
    int s = rowstart[n], t1 = rowstart[n + 1];
    float acc0 = 0.f, acc1 = 0.f;
    int t = s;
    for (; t + 1 < t1; t += 2) {
        acc0 += hbits2f(msg[(size_t)t * 16 + o]);
        acc1 += hbits2f(msg[(size_t)(t + 1) * 16 + o]);
    }
    if (t < t1) acc0 += hbits2f(msg[(size_t)t * 16 + o]);
    float acc = acc0 + acc1;
    int d = t1 - s;
    float invd = (d > 0) ? 1.f / (float)d : 0.f;
    float hi   = (d > 0) ? 1.f : 0.f;
    const float* __restrict__ hn = h + (size_t)n * 16;
    const float* __restrict__ w  = Wself + o * 16;
    float self = 0.f;
#pragma unroll
    for (int c = 0; c < 16; ++c) self += hn[c] * w[c];
    out[idx] = Y0C * acc * invd + hi * self;
}

__global__ void k_reduce1(const unsigned short* __restrict__ msg,  // stride 32
                          const uint2* __restrict__ y1d,
                          const int* __restrict__ rowstart,
                          const float* __restrict__ h, const float* __restrict__ Wself,
                          float* __restrict__ out0, float* __restrict__ out1, int N) {
    int idx = blockIdx.x * blockDim.x + threadIdx.x;
    if (idx >= N * 16) return;
    int n = idx >> 4, o = idx & 15;
    int s = rowstart[n], t1 = rowstart[n + 1];
    float a0 = 0.f, ax = 0.f, ay = 0.f, az = 0.f;
    float b0 = 0.f, bx = 0.f, by = 0.f, bz = 0.f;
    int t = s;
    for (; t + 1 < t1; t += 2) {
        const unsigned short* rowA = msg + (size_t)t * 32;
        const unsigned short* rowB = msg + (size_t)(t + 1) * 32;
        uint2 yva = y1d[t];
        uint2 yvb = y1d[t + 1];
        a0 += hbits2f(rowA[o]);
        b0 += hbits2f(rowB[o]);
        float pa = hbits2f(rowA[16 + o]);
        float pb = hbits2f(rowB[16 + o]);
        ax = fmaf(pa, hbits2f((unsigned short)yva.x), ax);
        ay = fmaf(pa, hbits2f((unsigned short)(yva.x >> 16)), ay);
        az = fmaf(pa, hbits2f((unsigned short)yva.y), az);
        bx = fmaf(pb, hbits2f((unsigned short)yvb.x), bx);
        by = fmaf(pb, hbits2f((unsigned short)(yvb.x >> 16)), by);
        bz = fmaf(pb, hbits2f((unsigned short)yvb.y), bz);
    }
    if (t < t1) {
        const unsigned short* rowA = msg + (size_t)t * 32;
        uint2 yva = y1d[t];
        a0 += hbits2f(rowA[o]);
        float pa = hbits2f(rowA[16 + o]);
        ax = fmaf(pa, hbits2f((unsigned short)yva.x), ax);
        ay = fmaf(pa, hbits2f((unsigned short)(yva.x >> 16)), ay);
        az = fmaf(pa, hbits2f((unsigned short)yva.y), az);
    }
    a0 += b0; ax += bx; ay += by; az += bz;
    int d = t1 - s;
    float invd = (d > 0) ? 1.f / (float)d : 0.f;
    float hi   = (d > 0) ? 1.f : 0.f;
    const float* __restrict__ hn = h + (size_t)n * 16;
    const float* __restrict__ w  = Wself + o * 16;
    float self = 0.f;
#pragma unroll
    for (int c = 0; c < 16; ++c) self += hn[c] * w[c];
    out0[idx] = Y0C * a0 * invd + hi * self;
    out1[(size_t)idx * 3]     = ax * invd;
    out1[(size_t)idx * 3 + 1] = ay * invd;
    out1[(size_t)idx * 3 + 2] = az * invd;
}

// ---------------------------------------------------------------------------
extern "C" void kernel_launch(void* const* d_in, const int* in_sizes, int n_in,
                              void* d_out, int out_size, void* d_ws, size_t ws_size,
                              hipStream_t stream) {
    (void)n_in; (void)out_size; (void)ws_size;
    const float* node_feats = (const float*)d_in[0];
    const float* pos    = (const float*)d_in[1];
    const float* edge_w = (const float*)d_in[2];
    const float* lin1_W = (const float*)d_in[3];
    const float* lin1_b = (const float*)d_in[4];
    const float* lin2_W = (const float*)d_in[5];
    const float* lin2_b = (const float*)d_in[6];
    const float* rW1    = (const float*)d_in[7];
    const float* rb1    = (const float*)d_in[8];
    const float* ln1_g  = (const float*)d_in[9];
    const float* ln1_b  = (const float*)d_in[10];
    const float* rW2    = (const float*)d_in[11];
    const float* rb2    = (const float*)d_in[12];
    const float* ln2_g  = (const float*)d_in[13];
    const float* ln2_b  = (const float*)d_in[14];
    const float* rW3    = (const float*)d_in[15];
    const float* rb3    = (const float*)d_in[16];
    const float* Wself  = (const float*)d_in[17];
    const int*   src    = (const int*)d_in[18];
    const int*   dst    = (const int*)d_in[19];

    const int N = in_sizes[1] / 3;     // pos is [N,3]
    const int E = in_sizes[18];        // src is [E]

    char* ws = (char*)d_ws;
    size_t off = 0;
    auto carve = [&](size_t bytes) -> char* {
        char* p = ws + off;
        off = (off + bytes + 255) & ~(size_t)255;
        return p;
    };
    float* h0   = (float*)carve((size_t)N * 16 * 4);
    float* h1   = (float*)carve((size_t)N * 16 * 4);
    int*   cntd = (int*)carve((size_t)N * 4);
    int*   cnts = (int*)carve((size_t)N * 4);
    int*   rsd  = (int*)carve((size_t)(N + 1) * 4);
    int*   rss  = (int*)carve((size_t)(N + 1) * 4);
    int*   s2d  = (int*)carve((size_t)E * 4);
    float4* edgeS = (float4*)carve((size_t)E * 16);
    uint2*  y1d   = (uint2*)carve((size_t)E * 8);
    unsigned* UaM = (unsigned*)carve((size_t)N * 16 * 64);
    float*    UaT = (float*)carve((size_t)N * 16 * 4);
    unsigned* UbM = (unsigned*)carve((size_t)N * 16 * 64);
    float*    UbT = (float*)carve((size_t)N * 16 * 4);
    unsigned* Wp  = (unsigned*)carve((size_t)3 * 4608 * 4);
    unsigned* Wq  = (unsigned*)carve((size_t)3 * 512 * 4);
    unsigned short* msg = (unsigned short*)carve((size_t)E * 32 * 2);
    // disjoint-lifetime overlays inside msg (dead before edge kernels run):
    int* posd = (int*)((char*)msg + (8u << 20));       // [E]
    int* poss = (int*)((char*)msg + (14u << 20));      // [E]

    auto nb = [](int n) { return (n + 255) / 256; };
    const int nbE = nb(E);
    const int nbU = (N + 31) / 32;
    const int nbEmb = (N + 3) / 4;

    // single fused memset (cntd and cnts are adjacent carves)
    hipMemsetAsync(cntd, 0, (size_t)((char*)cnts - (char*)cntd) + (size_t)N * 4, stream);

    k_embed_pack<<<nbEmb + 9, 256, 0, stream>>>(node_feats, lin1_W, lin1_b,
                                                lin2_W, lin2_b, h0, N, nbEmb,
                                                rW3, rW2, Wp, Wq);

    k_count2<<<nbE, 256, 0, stream>>>(src, dst, cntd, cnts, posd, poss, E);
    k_scan2<<<2, 1024, 0, stream>>>(cntd, rsd, cnts, rss, N);
    k_prep<<<nbE, 256, 0, stream>>>(pos, edge_w, src, dst, rsd, rss, posd, poss,
                                    edgeS, y1d, s2d, E);

    auto rnet = [&](int net, int ni) -> RadialW {
        RadialW r;
        r.W1 = rW1 + net * 96;   r.b1 = rb1 + net * 32;
        r.g1 = ln1_g + net * 32; r.gb1 = ln1_b + net * 32;
        r.b2 = rb2 + net * 32;
        r.g2 = ln2_g + net * 32; r.gb2 = ln2_b + net * 32;
        r.W2q = Wq + ni * 512;
        return r;
    };

    // ---- layer 0 (degree-1 branch dead: only net 0) ----
    k_u2<<<nbU, 256, 0, stream>>>(h0, Wp, rb3, rb3, UaM, UaT, UbM, UbT,
                                  /*wpA=*/0, nbU, N);
    k_edgeL0<<<nbE, 256, 0, stream>>>(edgeS, s2d, rnet(0, 0), (const uint4*)UaM, UaT,
                                      msg, E);
    k_reduce0<<<nb(N * 16), 256, 0, stream>>>(msg, rsd, h0, Wself, h1, N);

    // ---- layer 1 (nets 2,3) ----
    k_u2<<<2 * nbU, 256, 0, stream>>>(h1, Wp, rb3 + 2 * 256, rb3 + 3 * 256,
                                      UaM, UaT, UbM, UbT, /*wpA=*/1, nbU, N);
    k_edgeL1<<<2 * nbE, 256, 0, stream>>>(edgeS, s2d, rnet(2, 1), rnet(3, 2),
                                          (const uint4*)UaM, UaT,
                                          (const uint4*)UbM, UbT, msg, nbE, E);
    float* out0 = (float*)d_out;
    float* out1 = (float*)d_out + (size_t)N * 16;
    k_reduce1<<<nb(N * 16), 256, 0, stream>>>(msg, y1d, rsd, h1, Wself + 256,
                                              out0, out1, N);
}

// Round 8
// 352.829 us; speedup vs baseline: 4.9927x; 1.0077x over previous
//
#include <hip/hip_runtime.h>
#include <hip/hip_fp16.h>

// ---------------------------------------------------------------------------
// SE3Transformer block. Round 8:
//   - REVERT R7's wave-per-node fused embed (50us, latency-bound: serial
//     67-iter W1-load+FMA chain). Back to flat thread-per-output embed
//     kernels, now with 4-way partial accumulators + unroll (loads batch).
//   - weight pre-pack rides on k_embed1's grid (role-split blocks)
//   - keep R7 wins: LN tree-reduce in radial net, fdot2 GEMM+contraction,
//     dual counting sort, LDS-staged k_u2, x2-unrolled reduces
// ---------------------------------------------------------------------------

#define Y0C 0.28209479177387814f
#define C1C 0.4886025119029199f

typedef _Float16 hv2 __attribute__((ext_vector_type(2)));

#if defined(__has_builtin)
#if __has_builtin(__builtin_amdgcn_fdot2)
#define FDOT2(a, b, c) __builtin_amdgcn_fdot2((a), (b), (c), false)
#endif
#endif
#ifndef FDOT2
#define FDOT2(a, b, c) ((c) + (float)(a).x * (float)(b).x + (float)(a).y * (float)(b).y)
#endif

static __device__ __forceinline__ unsigned h2u(__half2 h) {
    union { __half2 h; unsigned u; } x; x.h = h; return x.u;
}
static __device__ __forceinline__ __half2 u2h(unsigned u) {
    union { unsigned u; __half2 h; } x; x.u = u; return x.h;
}
static __device__ __forceinline__ hv2 u2hv(unsigned u) {
    union { unsigned u; hv2 h; } x; x.u = u; return x.h;
}
static __device__ __forceinline__ unsigned hv2u(hv2 h) {
    union { hv2 h; unsigned u; } x; x.h = h; return x.u;
}
static __device__ __forceinline__ hv2 f2hv(float a, float b) {
    hv2 r; r.x = (_Float16)a; r.y = (_Float16)b; return r;
}
static __device__ __forceinline__ float hbits2f(unsigned short s) {
    __half_raw r; r.x = s; return __half2float((__half)r);
}

struct RadialW {
    const float *W1, *b1, *g1, *gb1, *b2, *g2, *gb2;
    const unsigned* W2q;   // packed [j*16+kp] = half2(W2[2kp][j], W2[2kp+1][j])
};

// radial MLP: (x0,x1,x2) -> 32 (LN,relu) -> [fdot2 GEMM] -> 32 (LN,relu)
// LN mean/var via 4-way partial sums (short dep chains).
__device__ __forceinline__ void radial_net_pk(float x0, float x1, float x2,
                                              RadialW rw, hv2* hvpk /*[16]*/) {
    float h[32];
#pragma unroll
    for (int j = 0; j < 32; ++j)
        h[j] = rw.b1[j] + x0 * rw.W1[j] + x1 * rw.W1[32 + j] + x2 * rw.W1[64 + j];
    float s0 = 0.f, s1 = 0.f, s2 = 0.f, s3 = 0.f;
#pragma unroll
    for (int p = 0; p < 8; ++p) {
        s0 += h[4 * p]; s1 += h[4 * p + 1]; s2 += h[4 * p + 2]; s3 += h[4 * p + 3];
    }
    float mu = ((s0 + s1) + (s2 + s3)) * 0.03125f;
    float v0 = 0.f, v1 = 0.f, v2 = 0.f, v3 = 0.f;
#pragma unroll
    for (int p = 0; p < 8; ++p) {
        float d0 = h[4 * p] - mu, d1 = h[4 * p + 1] - mu;
        float d2 = h[4 * p + 2] - mu, d3 = h[4 * p + 3] - mu;
        v0 = fmaf(d0, d0, v0); v1 = fmaf(d1, d1, v1);
        v2 = fmaf(d2, d2, v2); v3 = fmaf(d3, d3, v3);
    }
    float var = ((v0 + v1) + (v2 + v3)) * 0.03125f;
    float rs = rsqrtf(var + 1e-5f);
#pragma unroll
    for (int j = 0; j < 32; ++j)
        h[j] = fmaxf((h[j] - mu) * rs * rw.g1[j] + rw.gb1[j], 0.f);

    hv2 hp[16];
#pragma unroll
    for (int p = 0; p < 16; ++p) hp[p] = f2hv(h[2 * p], h[2 * p + 1]);

    float h2[32];
#pragma unroll
    for (int j = 0; j < 32; ++j) {
        float acc = rw.b2[j];
        const unsigned* __restrict__ wj = rw.W2q + j * 16;   // uniform -> s_load
#pragma unroll
        for (int kp = 0; kp < 16; ++kp)
            acc = FDOT2(hp[kp], u2hv(wj[kp]), acc);
        h2[j] = acc;
    }
    s0 = s1 = s2 = s3 = 0.f;
#pragma unroll
    for (int p = 0; p < 8; ++p) {
        s0 += h2[4 * p]; s1 += h2[4 * p + 1]; s2 += h2[4 * p + 2]; s3 += h2[4 * p + 3];
    }
    mu = ((s0 + s1) + (s2 + s3)) * 0.03125f;
    v0 = v1 = v2 = v3 = 0.f;
#pragma unroll
    for (int p = 0; p < 8; ++p) {
        float d0 = h2[4 * p] - mu, d1 = h2[4 * p + 1] - mu;
        float d2 = h2[4 * p + 2] - mu, d3 = h2[4 * p + 3] - mu;
        v0 = fmaf(d0, d0, v0); v1 = fmaf(d1, d1, v1);
        v2 = fmaf(d2, d2, v2); v3 = fmaf(d3, d3, v3);
    }
    var = ((v0 + v1) + (v2 + v3)) * 0.03125f;
    rs = rsqrtf(var + 1e-5f);
    float y[32];
#pragma unroll
    for (int j = 0; j < 32; ++j)
        y[j] = fmaxf((h2[j] - mu) * rs * rw.g2[j] + rw.gb2[j], 0.f);
#pragma unroll
    for (int p = 0; p < 16; ++p) hvpk[p] = f2hv(y[2 * p], y[2 * p + 1]);
}

// v[o] = Ut[o] + sum_p dot2(hvpk[p], Um[o][p])   (fdot2, f32 accumulate)
__device__ __forceinline__ void contract_dot(const hv2* hvpk,
                                             const uint4* __restrict__ Um,
                                             const float* __restrict__ Ut,
                                             float* v /*[16]*/) {
    float4 t0 = ((const float4*)Ut)[0];
    float4 t1 = ((const float4*)Ut)[1];
    float4 t2 = ((const float4*)Ut)[2];
    float4 t3 = ((const float4*)Ut)[3];
    float tail[16] = {t0.x, t0.y, t0.z, t0.w, t1.x, t1.y, t1.z, t1.w,
                      t2.x, t2.y, t2.z, t2.w, t3.x, t3.y, t3.z, t3.w};
#pragma unroll
    for (int o = 0; o < 16; ++o) {
        uint4 q0 = Um[o * 4];
        uint4 q1 = Um[o * 4 + 1];
        uint4 q2 = Um[o * 4 + 2];
        uint4 q3 = Um[o * 4 + 3];
        float acc = tail[o];
        acc = FDOT2(hvpk[0],  u2hv(q0.x), acc);
        acc = FDOT2(hvpk[1],  u2hv(q0.y), acc);
        acc = FDOT2(hvpk[2],  u2hv(q0.z), acc);
        acc = FDOT2(hvpk[3],  u2hv(q0.w), acc);
        acc = FDOT2(hvpk[4],  u2hv(q1.x), acc);
        acc = FDOT2(hvpk[5],  u2hv(q1.y), acc);
        acc = FDOT2(hvpk[6],  u2hv(q1.z), acc);
        acc = FDOT2(hvpk[7],  u2hv(q1.w), acc);
        acc = FDOT2(hvpk[8],  u2hv(q2.x), acc);
        acc = FDOT2(hvpk[9],  u2hv(q2.y), acc);
        acc = FDOT2(hvpk[10], u2hv(q2.z), acc);
        acc = FDOT2(hvpk[11], u2hv(q2.w), acc);
        acc = FDOT2(hvpk[12], u2hv(q3.x), acc);
        acc = FDOT2(hvpk[13], u2hv(q3.y), acc);
        acc = FDOT2(hvpk[14], u2hv(q3.z), acc);
        acc = FDOT2(hvpk[15], u2hv(q3.w), acc);
        v[o] = acc;
    }
}

// ---- embed stage 1 (+ weight pre-pack on trailing blocks) -----------------
// t = ELU(x@W1+b1), thread per (n,j); 4 partial accumulators.
__global__ __launch_bounds__(256) void k_embed1(
    const float* __restrict__ nf, const float* __restrict__ W1,
    const float* __restrict__ b1, float* __restrict__ t, int N, int nbEmb,
    const float* __restrict__ rW3, const float* __restrict__ rW2,
    unsigned* __restrict__ Wp, unsigned* __restrict__ Wq) {
    if (blockIdx.x >= (unsigned)nbEmb) {
        int tt = (blockIdx.x - nbEmb) * 256 + threadIdx.x;
        if (tt < 3 * 256) {
            int ni = tt >> 8;
            int net = (ni == 0) ? 0 : ni + 1;
            int r = tt & 255;
            int i = r >> 4, o = r & 15;
            const float* __restrict__ W3n = rW3 + (size_t)net * 8192;
            unsigned* __restrict__ dp = Wp + (size_t)ni * 4608 + (size_t)(i * 16 + o) * 18;
#pragma unroll
            for (int kp = 0; kp < 16; ++kp) {
                float a = W3n[(2 * kp) * 256 + o * 16 + i];
                float b = W3n[(2 * kp + 1) * 256 + o * 16 + i];
                dp[kp] = h2u(__floats2half2_rn(a, b));
            }
        } else if (tt < 3 * 256 + 3 * 512) {
            int r = tt - 3 * 256;
            int ni = r / 512;
            int net = (ni == 0) ? 0 : ni + 1;
            int jk = r - ni * 512;
            int j = jk >> 4, kp = jk & 15;
            const float* __restrict__ W2n = rW2 + (size_t)net * 1024;
            Wq[ni * 512 + j * 16 + kp] =
                h2u(__floats2half2_rn(W2n[(2 * kp) * 32 + j],
                                      W2n[(2 * kp + 1) * 32 + j]));
        }
        return;
    }
    int idx = blockIdx.x * 256 + threadIdx.x;
    if (idx >= N * 67) return;
    int n = idx / 67, j = idx - n * 67;
    const float* __restrict__ x = nf + (size_t)n * 67;
    const float* __restrict__ w = W1 + j;
    float a0 = b1[j], a1 = 0.f, a2 = 0.f, a3 = 0.f;
#pragma unroll
    for (int i = 0; i < 64; i += 4) {
        a0 = fmaf(x[i],     w[(size_t)i * 67],       a0);
        a1 = fmaf(x[i + 1], w[(size_t)(i + 1) * 67], a1);
        a2 = fmaf(x[i + 2], w[(size_t)(i + 2) * 67], a2);
        a3 = fmaf(x[i + 3], w[(size_t)(i + 3) * 67], a3);
    }
    a0 = fmaf(x[64], w[64 * 67], a0);
    a1 = fmaf(x[65], w[65 * 67], a1);
    a2 = fmaf(x[66], w[66 * 67], a2);
    float s = (a0 + a1) + (a2 + a3);
    t[idx] = (s > 0.f) ? s : expm1f(s);   // ELU(alpha=1)
}

// ---- embed stage 2: h0 = t@W2+b2, thread per (n,c) ------------------------
__global__ __launch_bounds__(256) void k_embed2(
    const float* __restrict__ t, const float* __restrict__ W2,
    const float* __restrict__ b2, float* __restrict__ h0, int N) {
    int idx = blockIdx.x * 256 + threadIdx.x;
    if (idx >= N * 16) return;
    int n = idx >> 4, c = idx & 15;
    const float* __restrict__ x = t + (size_t)n * 67;
    const float* __restrict__ w = W2 + c;
    float a0 = b2[c], a1 = 0.f, a2 = 0.f, a3 = 0.f;
#pragma unroll
    for (int i = 0; i < 64; i += 4) {
        a0 = fmaf(x[i],     w[(size_t)i * 16],       a0);
        a1 = fmaf(x[i + 1], w[(size_t)(i + 1) * 16], a1);
        a2 = fmaf(x[i + 2], w[(size_t)(i + 2) * 16], a2);
        a3 = fmaf(x[i + 3], w[(size_t)(i + 3) * 16], a3);
    }
    a0 = fmaf(x[64], w[64 * 16], a0);
    a1 = fmaf(x[65], w[65 * 16], a1);
    a2 = fmaf(x[66], w[66 * 16], a2);
    h0[idx] = (a0 + a1) + (a2 + a3);
}

// ---- counting sorts -------------------------------------------------------
__global__ void k_count2(const int* __restrict__ src, const int* __restrict__ dst,
                         int* __restrict__ cntd, int* __restrict__ cnts,
                         int* __restrict__ posd, int* __restrict__ poss, int E) {
    int e = blockIdx.x * blockDim.x + threadIdx.x;
    if (e >= E) return;
    posd[e] = atomicAdd(cntd + dst[e], 1);
    poss[e] = atomicAdd(cnts + src[e], 1);
}

// grid=2: block 0 scans cntd->rsd, block 1 scans cnts->rss
__global__ __launch_bounds__(1024) void k_scan2(const int* __restrict__ cntd,
                                                int* __restrict__ rsd,
                                                const int* __restrict__ cnts,
                                                int* __restrict__ rss, int N) {
    const int* __restrict__ c = (blockIdx.x == 0) ? cntd : cnts;
    int* __restrict__ rs      = (blockIdx.x == 0) ? rsd  : rss;
    int chunk = (N + 1023) >> 10;
    int lo = (int)threadIdx.x * chunk;
    int sum = 0;
    for (int j = 0; j < chunk; ++j) { int i = lo + j; sum += (i < N) ? c[i] : 0; }
    __shared__ int ps[1024];
    ps[threadIdx.x] = sum;
    __syncthreads();
    for (int off = 1; off < 1024; off <<= 1) {
        int t = (threadIdx.x >= (unsigned)off) ? ps[threadIdx.x - off] : 0;
        __syncthreads();
        ps[threadIdx.x] += t;
        __syncthreads();
    }
    int run = threadIdx.x ? ps[threadIdx.x - 1] : 0;
    if (threadIdx.x == 0) rs[0] = 0;
    for (int j = 0; j < chunk; ++j) {
        int i = lo + j;
        if (i < N) { run += c[i]; rs[i + 1] = run; }
    }
}

// ---- prep: geometry; edgeS (src-sorted), y1d (dst-sorted, f16), s2d map ---
__global__ void k_prep(const float* __restrict__ pos, const float* __restrict__ ew,
                       const int* __restrict__ src, const int* __restrict__ dst,
                       const int* __restrict__ rsd, const int* __restrict__ rss,
                       const int* __restrict__ posd, const int* __restrict__ poss,
                       float4* __restrict__ edgeS, uint2* __restrict__ y1d,
                       int* __restrict__ s2d, int E) {
    int e = blockIdx.x * blockDim.x + threadIdx.x;
    if (e >= E) return;
    int s = src[e], d = dst[e];
    float dx = pos[3 * d]     - pos[3 * s];
    float dy = pos[3 * d + 1] - pos[3 * s + 1];
    float dz = pos[3 * d + 2] - pos[3 * s + 2];
    float r = sqrtf(dx * dx + dy * dy + dz * dz);
    float im = 1.f / fmaxf(r, 1e-8f);
    int ts = rss[s] + poss[e];
    int td = rsd[d] + posd[e];
    s2d[ts] = td;
    edgeS[ts] = make_float4(ew[2 * e], ew[2 * e + 1], r, __int_as_float(s));
    y1d[td] = make_uint2(h2u(__floats2half2_rn(C1C * dy * im, C1C * dz * im)),
                         h2u(__floats2half2_rn(C1C * dx * im, 0.f)));
}

// ---- U precompute: LDS-staged packed weights, 2 nodes/thread --------------
__global__ __launch_bounds__(256) void k_u2(
    const float* __restrict__ h, const unsigned* __restrict__ Wp,
    const float* __restrict__ b3A, const float* __restrict__ b3B,
    unsigned* __restrict__ Um0, float* __restrict__ Ut0,
    unsigned* __restrict__ Um1, float* __restrict__ Ut1,
    int wpA, int nbPerNet, int N) {
    __shared__ unsigned WL[4608];
    int netSel = blockIdx.x / nbPerNet;
    int nbase = (blockIdx.x - netSel * nbPerNet) * 32;
    const unsigned* __restrict__ g = Wp + (size_t)(wpA + netSel) * 4608;
    for (int j = threadIdx.x; j < 4608; j += 256) WL[j] = g[j];
    __syncthreads();

    const float* __restrict__ b3 = netSel ? b3B : b3A;
    unsigned* __restrict__ Um = netSel ? Um1 : Um0;
    float*    __restrict__ Ut = netSel ? Ut1 : Ut0;

    int o = threadIdx.x & 15;
    int pr = threadIdx.x >> 4;
    int n0 = nbase + pr * 2;
    int n1 = n0 + 1;
    bool ok0 = n0 < N, ok1 = n1 < N;
    int m0 = ok0 ? n0 : 0, m1 = ok1 ? n1 : 0;

    const float* __restrict__ bo = b3 + o * 16;
    float tA = 0.f, tB = 0.f;
    __half2 hhA[16], hhB[16];
    {
        const float4* hp = (const float4*)(h + (size_t)m0 * 16);
#pragma unroll
        for (int q = 0; q < 4; ++q) {
            float4 hv = hp[q];
            tA += hv.x * bo[4 * q] + hv.y * bo[4 * q + 1]
                + hv.z * bo[4 * q + 2] + hv.w * bo[4 * q + 3];
            hhA[4 * q]     = __floats2half2_rn(hv.x, hv.x);
            hhA[4 * q + 1] = __floats2half2_rn(hv.y, hv.y);
            hhA[4 * q + 2] = __floats2half2_rn(hv.z, hv.z);
            hhA[4 * q + 3] = __floats2half2_rn(hv.w, hv.w);
        }
    }
    {
        const float4* hp = (const float4*)(h + (size_t)m1 * 16);
#pragma unroll
        for (int q = 0; q < 4; ++q) {
            float4 hv = hp[q];
            tB += hv.x * bo[4 * q] + hv.y * bo[4 * q + 1]
                + hv.z * bo[4 * q + 2] + hv.w * bo[4 * q + 3];
            hhB[4 * q]     = __floats2half2_rn(hv.x, hv.x);
            hhB[4 * q + 1] = __floats2half2_rn(hv.y, hv.y);
            hhB[4 * q + 2] = __floats2half2_rn(hv.z, hv.z);
            hhB[4 * q + 3] = __floats2half2_rn(hv.w, hv.w);
        }
    }

    __half2 accA[16], accB[16];
#pragma unroll
    for (int p = 0; p < 16; ++p) {
        accA[p] = __floats2half2_rn(0.f, 0.f);
        accB[p] = __floats2half2_rn(0.f, 0.f);
    }

#pragma unroll
    for (int i = 0; i < 16; ++i) {
        const uint2* __restrict__ row = (const uint2*)(WL + i * 288 + o * 18);
        __half2 ha = hhA[i], hb = hhB[i];
#pragma unroll
        for (int q = 0; q < 8; ++q) {
            uint2 w = row[q];
            accA[2 * q]     = __hfma2(ha, u2h(w.x), accA[2 * q]);
            accA[2 * q + 1] = __hfma2(ha, u2h(w.y), accA[2 * q + 1]);
            accB[2 * q]     = __hfma2(hb, u2h(w.x), accB[2 * q]);
            accB[2 * q + 1] = __hfma2(hb, u2h(w.y), accB[2 * q + 1]);
        }
    }

    if (ok0) {
        uint4* du = (uint4*)(Um + ((size_t)(n0 * 16 + o)) * 16);
#pragma unroll
        for (int q = 0; q < 4; ++q)
            du[q] = make_uint4(h2u(accA[4 * q]), h2u(accA[4 * q + 1]),
                               h2u(accA[4 * q + 2]), h2u(accA[4 * q + 3]));
        Ut[n0 * 16 + o] = tA;
    }
    if (ok1) {
        uint4* du = (uint4*)(Um + ((size_t)(n1 * 16 + o)) * 16);
#pragma unroll
        for (int q = 0; q < 4; ++q)
            du[q] = make_uint4(h2u(accB[4 * q]), h2u(accB[4 * q + 1]),
                               h2u(accB[4 * q + 2]), h2u(accB[4 * q + 3]));
        Ut[n1 * 16 + o] = tB;
    }
}

// ---- edge kernels (src-sorted traversal, scatter-write to dst slot) -------
__global__ __launch_bounds__(256) void k_edgeL0(
    const float4* __restrict__ edgeS, const int* __restrict__ s2d, RadialW ra,
    const uint4* __restrict__ UmA, const float* __restrict__ UtA,
    unsigned short* __restrict__ msg /*stride 16*/, int E) {
    int t = blockIdx.x * blockDim.x + threadIdx.x;
    if (t >= E) return;
    float4 a = edgeS[t];
    int sn = __float_as_int(a.w);
    hv2 hv[16];
    float v[16];
    radial_net_pk(a.x, a.y, a.z, ra, hv);
    contract_dot(hv, UmA + (size_t)sn * 64, UtA + (size_t)sn * 16, v);
    int td = s2d[t];
    uint4* m = (uint4*)(msg + (size_t)td * 16);
    m[0] = make_uint4(hv2u(f2hv(v[0], v[1])),  hv2u(f2hv(v[2], v[3])),
                      hv2u(f2hv(v[4], v[5])),  hv2u(f2hv(v[6], v[7])));
    m[1] = make_uint4(hv2u(f2hv(v[8], v[9])),  hv2u(f2hv(v[10], v[11])),
                      hv2u(f2hv(v[12], v[13])), hv2u(f2hv(v[14], v[15])));
}

__global__ __launch_bounds__(256) void k_edgeL1(
    const float4* __restrict__ edgeS, const int* __restrict__ s2d,
    RadialW ra, RadialW rb,
    const uint4* __restrict__ UmA, const float* __restrict__ UtA,
    const uint4* __restrict__ UmB, const float* __restrict__ UtB,
    unsigned short* __restrict__ msg /*stride 32*/, int nbE, int E) {
    int half = (blockIdx.x >= (unsigned)nbE) ? 1 : 0;
    int t = (blockIdx.x - half * nbE) * blockDim.x + threadIdx.x;
    if (t >= E) return;
    float4 a = edgeS[t];
    int sn = __float_as_int(a.w);
    RadialW rw = half ? rb : ra;
    const uint4* __restrict__ Um = half ? UmB : UmA;
    const float* __restrict__ Ut = half ? UtB : UtA;
    hv2 hv[16];
    float v[16];
    radial_net_pk(a.x, a.y, a.z, rw, hv);
    contract_dot(hv, Um + (size_t)sn * 64, Ut + (size_t)sn * 16, v);
    int td = s2d[t];
    uint4* m = (uint4*)(msg + (size_t)td * 32 + half * 16);
    m[0] = make_uint4(hv2u(f2hv(v[0], v[1])),  hv2u(f2hv(v[2], v[3])),
                      hv2u(f2hv(v[4], v[5])),  hv2u(f2hv(v[6], v[7])));
    m[1] = make_uint4(hv2u(f2hv(v[8], v[9])),  hv2u(f2hv(v[10], v[11])),
                      hv2u(f2hv(v[12], v[13])), hv2u(f2hv(v[14], v[15])));
}

// ---- segment reduces (contiguous, dst-sorted; x2 unrolled) ----------------
__global__ void k_reduce0(const unsigned short* __restrict__ msg,
                          const int* __restrict__ rowstart,
                          const float* __restrict__ h, const float* __restrict__ Wself,
                          float* __restrict__ out, int N) {
    int idx = blockIdx.x * blockDim.x + threadIdx.x;
    if (idx >= N * 16) return;
    int n = idx >> 4, o = idx & 15;
    int s = rowstart[n], t1 = rowstart[n + 1];
    float acc0 = 0.f, acc1 = 0.f;
    int t = s;
    for (; t + 1 < t1; t += 2) {
        acc0 += hbits2f(msg[(size_t)t * 16 + o]);
        acc1 += hbits2f(msg[(size_t)(t + 1) * 16 + o]);
    }
    if (t < t1) acc0 += hbits2f(msg[(size_t)t * 16 + o]);
    float acc = acc0 + acc1;
    int d = t1 - s;
    float invd = (d > 0) ? 1.f / (float)d : 0.f;
    float hi   = (d > 0) ? 1.f : 0.f;
    const float* __restrict__ hn = h + (size_t)n * 16;
    const float* __restrict__ w  = Wself + o * 16;
    float self = 0.f;
#pragma unroll
    for (int c = 0; c < 16; ++c) self += hn[c] * w[c];
    out[idx] = Y0C * acc * invd + hi * self;
}

__global__ void k_reduce1(const unsigned short* __restrict__ msg,  // stride 32
                          const uint2* __restrict__ y1d,
                          const int* __restrict__ rowstart,
                          const float* __restrict__ h, const float* __restrict__ Wself,
                          float* __restrict__ out0, float* __restrict__ out1, int N) {
    int idx = blockIdx.x * blockDim.x + threadIdx.x;
    if (idx >= N * 16) return;
    int n = idx >> 4, o = idx & 15;
    int s = rowstart[n], t1 = rowstart[n + 1];
    float a0 = 0.f, ax = 0.f, ay = 0.f, az = 0.f;
    float b0 = 0.f, bx = 0.f, by = 0.f, bz = 0.f;
    int t = s;
    for (; t + 1 < t1; t += 2) {
        const unsigned short* rowA = msg + (size_t)t * 32;
        const unsigned short* rowB = msg + (size_t)(t + 1) * 32;
        uint2 yva = y1d[t];
        uint2 yvb = y1d[t + 1];
        a0 += hbits2f(rowA[o]);
        b0 += hbits2f(rowB[o]);
        float pa = hbits2f(rowA[16 + o]);
        float pb = hbits2f(rowB[16 + o]);
        ax = fmaf(pa, hbits2f((unsigned short)yva.x), ax);
        ay = fmaf(pa, hbits2f((unsigned short)(yva.x >> 16)), ay);
        az = fmaf(pa, hbits2f((unsigned short)yva.y), az);
        bx = fmaf(pb, hbits2f((unsigned short)yvb.x), bx);
        by = fmaf(pb, hbits2f((unsigned short)(yvb.x >> 16)), by);
        bz = fmaf(pb, hbits2f((unsigned short)yvb.y), bz);
    }
    if (t < t1) {
        const unsigned short* rowA = msg + (size_t)t * 32;
        uint2 yva = y1d[t];
        a0 += hbits2f(rowA[o]);
        float pa = hbits2f(rowA[16 + o]);
        ax = fmaf(pa, hbits2f((unsigned short)yva.x), ax);
        ay = fmaf(pa, hbits2f((unsigned short)(yva.x >> 16)), ay);
        az = fmaf(pa, hbits2f((unsigned short)yva.y), az);
    }
    a0 += b0; ax += bx; ay += by; az += bz;
    int d = t1 - s;
    float invd = (d > 0) ? 1.f / (float)d : 0.f;
    float hi   = (d > 0) ? 1.f : 0.f;
    const float* __restrict__ hn = h + (size_t)n * 16;
    const float* __restrict__ w  = Wself + o * 16;
    float self = 0.f;
#pragma unroll
    for (int c = 0; c < 16; ++c) self += hn[c] * w[c];
    out0[idx] = Y0C * a0 * invd + hi * self;
    out1[(size_t)idx * 3]     = ax * invd;
    out1[(size_t)idx * 3 + 1] = ay * invd;
    out1[(size_t)idx * 3 + 2] = az * invd;
}

// ---------------------------------------------------------------------------
extern "C" void kernel_launch(void* const* d_in, const int* in_sizes, int n_in,
                              void* d_out, int out_size, void* d_ws, size_t ws_size,
                              hipStream_t stream) {
    (void)n_in; (void)out_size; (void)ws_size;
    const float* node_feats = (const float*)d_in[0];
    const float* pos    = (const float*)d_in[1];
    const float* edge_w = (const float*)d_in[2];
    const float* lin1_W = (const float*)d_in[3];
    const float* lin1_b = (const float*)d_in[4];
    const float* lin2_W = (const float*)d_in[5];
    const float* lin2_b = (const float*)d_in[6];
    const float* rW1    = (const float*)d_in[7];
    const float* rb1    = (const float*)d_in[8];
    const float* ln1_g  = (const float*)d_in[9];
    const float* ln1_b  = (const float*)d_in[10];
    const float* rW2    = (const float*)d_in[11];
    const float* rb2    = (const float*)d_in[12];
    const float* ln2_g  = (const float*)d_in[13];
    const float* ln2_b  = (const float*)d_in[14];
    const float* rW3    = (const float*)d_in[15];
    const float* rb3    = (const float*)d_in[16];
    const float* Wself  = (const float*)d_in[17];
    const int*   src    = (const int*)d_in[18];
    const int*   dst    = (const int*)d_in[19];

    const int N = in_sizes[1] / 3;     // pos is [N,3]
    const int E = in_sizes[18];        // src is [E]

    char* ws = (char*)d_ws;
    size_t off = 0;
    auto carve = [&](size_t bytes) -> char* {
        char* p = ws + off;
        off = (off + bytes + 255) & ~(size_t)255;
        return p;
    };
    float* h0   = (float*)carve((size_t)N * 16 * 4);
    float* h1   = (float*)carve((size_t)N * 16 * 4);
    int*   cntd = (int*)carve((size_t)N * 4);
    int*   cnts = (int*)carve((size_t)N * 4);
    int*   rsd  = (int*)carve((size_t)(N + 1) * 4);
    int*   rss  = (int*)carve((size_t)(N + 1) * 4);
    int*   s2d  = (int*)carve((size_t)E * 4);
    float4* edgeS = (float4*)carve((size_t)E * 16);
    uint2*  y1d   = (uint2*)carve((size_t)E * 8);
    unsigned* UaM = (unsigned*)carve((size_t)N * 16 * 64);
    float*    UaT = (float*)carve((size_t)N * 16 * 4);
    unsigned* UbM = (unsigned*)carve((size_t)N * 16 * 64);
    float*    UbT = (float*)carve((size_t)N * 16 * 4);
    unsigned* Wp  = (unsigned*)carve((size_t)3 * 4608 * 4);
    unsigned* Wq  = (unsigned*)carve((size_t)3 * 512 * 4);
    unsigned short* msg = (unsigned short*)carve((size_t)E * 32 * 2);
    // disjoint-lifetime overlays inside msg (dead before edge kernels run):
    float* tmb = (float*)msg;                          // [N,67] embed temp (<8MB)
    int* posd = (int*)((char*)msg + (8u << 20));       // [E]
    int* poss = (int*)((char*)msg + (14u << 20));      // [E]

    auto nb = [](int n) { return (n + 255) / 256; };
    const int nbE = nb(E);
    const int nbU = (N + 31) / 32;
    const int nbE1 = nb(N * 67);

    // single fused memset (cntd and cnts are adjacent carves)
    hipMemsetAsync(cntd, 0, (size_t)((char*)cnts - (char*)cntd) + (size_t)N * 4, stream);

    k_embed1<<<nbE1 + 9, 256, 0, stream>>>(node_feats, lin1_W, lin1_b, tmb, N,
                                           nbE1, rW3, rW2, Wp, Wq);
    k_embed2<<<nb(N * 16), 256, 0, stream>>>(tmb, lin2_W, lin2_b, h0, N);

    k_count2<<<nbE, 256, 0, stream>>>(src, dst, cntd, cnts, posd, poss, E);
    k_scan2<<<2, 1024, 0, stream>>>(cntd, rsd, cnts, rss, N);
    k_prep<<<nbE, 256, 0, stream>>>(pos, edge_w, src, dst, rsd, rss, posd, poss,
                                    edgeS, y1d, s2d, E);

    auto rnet = [&](int net, int ni) -> RadialW {
        RadialW r;
        r.W1 = rW1 + net * 96;   r.b1 = rb1 + net * 32;
        r.g1 = ln1_g + net * 32; r.gb1 = ln1_b + net * 32;
        r.b2 = rb2 + net * 32;
        r.g2 = ln2_g + net * 32; r.gb2 = ln2_b + net * 32;
        r.W2q = Wq + ni * 512;
        return r;
    };

    // ---- layer 0 (degree-1 branch dead: only net 0) ----
    k_u2<<<nbU, 256, 0, stream>>>(h0, Wp, rb3, rb3, UaM, UaT, UbM, UbT,
                                  /*wpA=*/0, nbU, N);
    k_edgeL0<<<nbE, 256, 0, stream>>>(edgeS, s2d, rnet(0, 0), (const uint4*)UaM, UaT,
                                      msg, E);
    k_reduce0<<<nb(N * 16), 256, 0, stream>>>(msg, rsd, h0, Wself, h1, N);

    // ---- layer 1 (nets 2,3) ----
    k_u2<<<2 * nbU, 256, 0, stream>>>(h1, Wp, rb3 + 2 * 256, rb3 + 3 * 256,
                                      UaM, UaT, UbM, UbT, /*wpA=*/1, nbU, N);
    k_edgeL1<<<2 * nbE, 256, 0, stream>>>(edgeS, s2d, rnet(2, 1), rnet(3, 2),
                                          (const uint4*)UaM, UaT,
                                          (const uint4*)UbM, UbT, msg, nbE, E);
    float* out0 = (float*)d_out;
    float* out1 = (float*)d_out + (size_t)N * 16;
    k_reduce1<<<nb(N * 16), 256, 0, stream>>>(msg, y1d, rsd, h1, Wself + 256,
                                              out0, out1, N);
}